// Round 4
// baseline (761.748 us; speedup 1.0000x reference)
//
#include <hip/hip_runtime.h>
#include <cstdint>

// ---------------------------------------------------------------------------
// GCN pipeline:
//  packed-u64 deg/cnt atomic -> dinv -> 3-phase scan (rowptr+fill) ->
//  CSR scatter (int2 interleaved) -> GEMM1(bf16 out) -> AGG1(bf16 gather) ->
//  GEMM2(bf16 out) -> AGG2 -> mean-pool -> fused head
// ---------------------------------------------------------------------------

#define SCAN_CHUNK 512  // elements per scan block (multiple of 256)
#define FIXSCALE 16777216.0f  // 2^24

// f32 -> bf16 round-to-nearest-even
static __device__ __forceinline__ unsigned int f2bf(float f) {
    unsigned int u = __float_as_uint(f);
    return (u + 0x7fffu + ((u >> 16) & 1u)) >> 16;
}
static __device__ __forceinline__ unsigned int packbf2(float a, float b) {
    return f2bf(a) | (f2bf(b) << 16);
}
static __device__ __forceinline__ float bf_lo(unsigned int v) {
    return __uint_as_float(v << 16);
}
static __device__ __forceinline__ float bf_hi(unsigned int v) {
    return __uint_as_float(v & 0xffff0000u);
}

__global__ void k_init_small(int* gstart, int* gcnt, int G) {
    int g = blockIdx.x * blockDim.x + threadIdx.x;
    if (g < G) { gstart[g] = 0x7fffffff; gcnt[g] = 0; }
}

__global__ void k_init_nodes(const int* __restrict__ batch,
                             unsigned long long* __restrict__ packed,
                             int* gstart, int* gcnt, int N) {
    int i = blockIdx.x * blockDim.x + threadIdx.x;
    if (i >= N) return;
    packed[i] = 0ull;
    int b = batch[i];
    if (i == 0 || batch[i - 1] != b) gstart[b] = i;  // batch sorted -> unique writer
    atomicAdd(&gcnt[b], 1);
}

// one u64 atomic per edge: low32 = edge count, high32 = sum(ew) in 2^-24 fixed pt
__global__ void k_edge1(const int* __restrict__ dst, const float* __restrict__ ew,
                        unsigned long long* __restrict__ packed, int E) {
    int e = blockIdx.x * blockDim.x + threadIdx.x;
    if (e >= E) return;
    int d = dst[e];
    unsigned int fx = (unsigned int)__float2uint_rn(ew[e] * FIXSCALE);
    atomicAdd(&packed[d], ((unsigned long long)fx << 32) | 1ull);
}

__global__ void k_dinv(const unsigned long long* __restrict__ packed,
                       float* __restrict__ dinv, int* __restrict__ cnt, int N) {
    int i = blockIdx.x * blockDim.x + threadIdx.x;
    if (i >= N) return;
    unsigned long long v = packed[i];
    cnt[i] = (int)(v & 0xffffffffull);
    float deg = 1.0f + (float)(v >> 32) * (1.0f / FIXSCALE);  // self-loop +1
    dinv[i] = rsqrtf(deg);
}

// ---- 3-phase exclusive scan of cnt[N] -> rowptr[N+1] (+ fill seed) --------
__global__ __launch_bounds__(256) void k_scan_a(const int* __restrict__ cnt,
                                                int* __restrict__ bsum, int N) {
    __shared__ int sm[256];
    int base = blockIdx.x * SCAN_CHUNK;
    int end = min(base + SCAN_CHUNK, N);
    int s = 0;
    for (int i = base + threadIdx.x; i < end; i += 256) s += cnt[i];
    sm[threadIdx.x] = s;
    __syncthreads();
    for (int d = 128; d > 0; d >>= 1) {
        if (threadIdx.x < d) sm[threadIdx.x] += sm[threadIdx.x + d];
        __syncthreads();
    }
    if (threadIdx.x == 0) bsum[blockIdx.x] = sm[0];
}

__global__ __launch_bounds__(1024) void k_scan_b(const int* __restrict__ bsum,
                                                 int* __restrict__ boff,
                                                 int* __restrict__ rowptr,
                                                 int NB, int N) {
    __shared__ int sm[1024];
    int tid = threadIdx.x;
    int v = (tid < NB) ? bsum[tid] : 0;
    sm[tid] = v;
    __syncthreads();
    for (int d = 1; d < 1024; d <<= 1) {
        int t = (tid >= d) ? sm[tid - d] : 0;
        __syncthreads();
        sm[tid] += t;
        __syncthreads();
    }
    if (tid < NB) boff[tid] = sm[tid] - v;   // exclusive
    if (tid == NB - 1) rowptr[N] = sm[tid];  // total
}

__global__ __launch_bounds__(256) void k_scan_c(const int* __restrict__ cnt,
                                                const int* __restrict__ boff,
                                                int* __restrict__ rowptr,
                                                int* __restrict__ fill, int N) {
    __shared__ int sm[256];
    int base = blockIdx.x * SCAN_CHUNK;
    int end = min(base + SCAN_CHUNK, N);
    int running = boff[blockIdx.x];
    for (int t0 = base; t0 < end; t0 += 256) {
        int i = t0 + threadIdx.x;
        int v = (i < end) ? cnt[i] : 0;
        sm[threadIdx.x] = v;
        __syncthreads();
        for (int d = 1; d < 256; d <<= 1) {
            int t = (threadIdx.x >= d) ? sm[threadIdx.x - d] : 0;
            __syncthreads();
            sm[threadIdx.x] += t;
            __syncthreads();
        }
        if (i < end) {
            int rp = running + sm[threadIdx.x] - v;
            rowptr[i] = rp;
            fill[i] = rp;  // seed: edge2's atomicAdd returns position directly
        }
        running += sm[255];
        __syncthreads();
    }
}
// ---------------------------------------------------------------------------

__global__ void k_edge2(const int* __restrict__ src, const int* __restrict__ dst,
                        const float* __restrict__ ew, const float* __restrict__ dinv,
                        int* fill, int2* __restrict__ cvb, int E) {
    int e = blockIdx.x * blockDim.x + threadIdx.x;
    if (e >= E) return;
    int s = src[e], d = dst[e];
    int pos = atomicAdd(&fill[d], 1);
    float val = dinv[s] * ew[e] * dinv[d];
    cvb[pos] = make_int2(s, __float_as_int(val));
}

// Y[M,128](bf16) = X[M,128](f32) @ W[128,128]  (W via wave-uniform scalar loads)
// block: 256 thr = 4 waves; wave w -> cols [32w,32w+32); lane -> one row.
__global__ __launch_bounds__(256) void k_gemm(const float* __restrict__ X,
                                              const float* __restrict__ W,
                                              unsigned short* __restrict__ Y, int M) {
    int tid = threadIdx.x;
    int wid = tid >> 6, lane = tid & 63;
    int row = blockIdx.x * 64 + lane;
    int c0 = __builtin_amdgcn_readfirstlane(wid * 32);  // wave-uniform col base
    if (row >= M) return;
    float acc[32];
#pragma unroll
    for (int c = 0; c < 32; ++c) acc[c] = 0.f;
    const float4* __restrict__ xrow = reinterpret_cast<const float4*>(X + (size_t)row * 128);
#pragma unroll 8
    for (int k4 = 0; k4 < 32; ++k4) {
        float4 xv = xrow[k4];
#pragma unroll
        for (int j = 0; j < 4; ++j) {
            float xk = (j == 0) ? xv.x : (j == 1) ? xv.y : (j == 2) ? xv.z : xv.w;
            const float* __restrict__ wrow = W + (size_t)(k4 * 4 + j) * 128 + c0;
#pragma unroll
            for (int c = 0; c < 32; ++c) acc[c] = fmaf(xk, wrow[c], acc[c]);
        }
    }
    // 32 accs -> 64 B of bf16 (aligned: row*256 + c0*2 is 16B-aligned)
    uint4* y4 = reinterpret_cast<uint4*>(Y + (size_t)row * 128 + c0);
#pragma unroll
    for (int q = 0; q < 4; ++q) {
        uint4 v;
        v.x = packbf2(acc[8 * q + 0], acc[8 * q + 1]);
        v.y = packbf2(acc[8 * q + 2], acc[8 * q + 3]);
        v.z = packbf2(acc[8 * q + 4], acc[8 * q + 5]);
        v.w = packbf2(acc[8 * q + 6], acc[8 * q + 7]);
        y4[q] = v;
    }
}

// Out[d] = relu( sum_e val[e]*Hin[col[e]] + dinv[d]^2*Hin[d] + bias )
// Hin is bf16; one wave per node; lane holds 2 features (one u32 = 2 bf16).
__global__ __launch_bounds__(256) void k_agg(const unsigned int* __restrict__ Hb,
                                             const int* __restrict__ rowptr,
                                             const int2* __restrict__ cvb,
                                             const float* __restrict__ dinv,
                                             const float* __restrict__ bias,
                                             float* __restrict__ Out, int N) {
    int lane = threadIdx.x & 63;
    int node = blockIdx.x * 4 + (threadIdx.x >> 6);
    if (node >= N) return;
    int beg = rowptr[node], end = rowptr[node + 1];
    float di = dinv[node];
    unsigned int hv = Hb[(size_t)node * 64 + lane];
    float sn = di * di;
    float a0 = sn * bf_lo(hv), a1 = sn * bf_hi(hv);
    int n = end - beg;
    for (int base = 0; base < n; base += 64) {
        int m = min(64, n - base);
        int cl = 0; float vl = 0.f;
        if (base + lane < n) {
            int2 cv = cvb[beg + base + lane];
            cl = cv.x;
            vl = __int_as_float(cv.y);
        }
        for (int j0 = 0; j0 < m; j0 += 4) {
#pragma unroll
            for (int jj = 0; jj < 4; ++jj) {
                int j = j0 + jj;
                if (j < m) {
                    int sIdx = __shfl(cl, j);
                    float v = __shfl(vl, j);
                    unsigned int h = Hb[(size_t)sIdx * 64 + lane];
                    a0 = fmaf(v, bf_lo(h), a0);
                    a1 = fmaf(v, bf_hi(h), a1);
                }
            }
        }
    }
    float2 bv = reinterpret_cast<const float2*>(bias)[lane];
    a0 = fmaxf(a0 + bv.x, 0.f);
    a1 = fmaxf(a1 + bv.y, 0.f);
    reinterpret_cast<float2*>(Out)[(size_t)node * 64 + lane] = make_float2(a0, a1);
}

// mean pool: batch sorted -> graph g is rows [gstart[g], gstart[g]+gcnt[g])
__global__ __launch_bounds__(256) void k_pool(const float* __restrict__ Hfin,
                                              const int* __restrict__ gstart,
                                              const int* __restrict__ gcnt,
                                              float* __restrict__ gmean) {
    int g = blockIdx.x;
    int tid = threadIdx.x;
    int c = tid & 127, half = tid >> 7;
    __shared__ float red[256];
    int cntg = gcnt[g];
    int b = gstart[g];
    float s = 0.f;
    for (int i = half; i < cntg; i += 2) s += Hfin[(size_t)(b + i) * 128 + c];
    red[tid] = s;
    __syncthreads();
    if (half == 0) {
        float tot = red[c] + red[c + 128];
        gmean[g * 128 + c] = tot / fmaxf((float)cntg, 1.f);
    }
}

// head: md = relu(metadata[first%G] @ Wm + bm); out = [pooled, md] @ Wf + bf
__global__ __launch_bounds__(128) void k_final(const float* __restrict__ gmean,
                                               const int* __restrict__ gstart,
                                               const float* __restrict__ meta,
                                               const float* __restrict__ Wm,
                                               const float* __restrict__ bm,
                                               const float* __restrict__ Wf,
                                               const float* __restrict__ bf,
                                               float* __restrict__ out, int G) {
    int g = blockIdx.x;
    int c = threadIdx.x;  // 128 threads
    __shared__ float red[128];
    float pooled = gmean[g * 128 + c];
    int fn = gstart[g];          // INT_MAX for empty graph (matches segment_min identity)
    int idx = fn % G;            // metadata.shape[0] == G
    float m = bm[c];
#pragma unroll
    for (int k = 0; k < 30; ++k) m = fmaf(meta[idx * 30 + k], Wm[k * 128 + c], m);
    m = fmaxf(m, 0.f);
    float part = pooled * Wf[c] + m * Wf[128 + c];
    red[c] = part;
    __syncthreads();
    for (int st = 64; st > 0; st >>= 1) {
        if (c < st) red[c] += red[c + st];
        __syncthreads();
    }
    if (c == 0) out[g] = red[0] + bf[0];
}

extern "C" void kernel_launch(void* const* d_in, const int* in_sizes, int n_in,
                              void* d_out, int out_size, void* d_ws, size_t ws_size,
                              hipStream_t stream) {
    const float* x     = (const float*)d_in[0];
    const int*   ei    = (const int*)d_in[1];
    const float* ew    = (const float*)d_in[2];
    const int*   batch = (const int*)d_in[3];
    const float* meta  = (const float*)d_in[4];
    const float* W1    = (const float*)d_in[5];
    const float* b1    = (const float*)d_in[6];
    const float* W2    = (const float*)d_in[7];
    const float* b2    = (const float*)d_in[8];
    const float* Wm    = (const float*)d_in[9];
    const float* bm    = (const float*)d_in[10];
    const float* Wf    = (const float*)d_in[11];
    const float* bf    = (const float*)d_in[12];

    int N = in_sizes[0] / 128;
    int E = in_sizes[2];
    int G = in_sizes[4] / 30;
    const int* srcp = ei;
    const int* dstp = ei + E;

    char* p = (char*)d_ws;
    auto alloc = [&](size_t bytes) -> void* {
        void* r = p;
        p += (bytes + 255) & ~(size_t)255;
        return r;
    };
    unsigned long long* packed = (unsigned long long*)alloc((size_t)N * 8);
    float* dinv   = (float*)alloc((size_t)N * 4);
    int*   cnt    = (int*)alloc((size_t)N * 4);
    int*   fill   = (int*)alloc((size_t)N * 4);
    int*   rowptr = (int*)alloc((size_t)(N + 1) * 4);
    int2*  cvb    = (int2*)alloc((size_t)E * 8);
    unsigned short* bufH = (unsigned short*)alloc((size_t)N * 128 * 2);  // bf16 h
    float* bufF   = (float*)alloc((size_t)N * 128 * 4);                  // f32 agg out
    float* gmean  = (float*)alloc((size_t)G * 128 * 4);
    int*   gstart = (int*)alloc((size_t)G * 4);
    int*   gcnt   = (int*)alloc((size_t)G * 4);
    int NB = (N + SCAN_CHUNK - 1) / SCAN_CHUNK;
    int*   bsum   = (int*)alloc((size_t)NB * 4);
    int*   boff   = (int*)alloc((size_t)NB * 4);

    k_init_small<<<(G + 255) / 256, 256, 0, stream>>>(gstart, gcnt, G);
    k_init_nodes<<<(N + 255) / 256, 256, 0, stream>>>(batch, packed, gstart, gcnt, N);
    k_edge1<<<(E + 255) / 256, 256, 0, stream>>>(dstp, ew, packed, E);
    k_dinv<<<(N + 255) / 256, 256, 0, stream>>>(packed, dinv, cnt, N);
    k_scan_a<<<NB, 256, 0, stream>>>(cnt, bsum, N);
    k_scan_b<<<1, 1024, 0, stream>>>(bsum, boff, rowptr, NB, N);
    k_scan_c<<<NB, 256, 0, stream>>>(cnt, boff, rowptr, fill, N);
    k_edge2<<<(E + 255) / 256, 256, 0, stream>>>(srcp, dstp, ew, dinv, fill, cvb, E);

    k_gemm<<<(N + 63) / 64, 256, 0, stream>>>(x, W1, bufH, N);
    k_agg<<<(N + 3) / 4, 256, 0, stream>>>((const unsigned int*)bufH, rowptr, cvb, dinv, b1, bufF, N);
    k_gemm<<<(N + 63) / 64, 256, 0, stream>>>(bufF, W2, bufH, N);
    k_agg<<<(N + 3) / 4, 256, 0, stream>>>((const unsigned int*)bufH, rowptr, cvb, dinv, b2, bufF, N);

    k_pool<<<G, 256, 0, stream>>>(bufF, gstart, gcnt, gmean);
    k_final<<<G, 128, 0, stream>>>(gmean, gstart, meta, Wm, bm, Wf, bf, (float*)d_out, G);
}

// Round 5
// 577.040 us; speedup vs baseline: 1.3201x; 1.3201x over previous
//
#include <hip/hip_runtime.h>
#include <cstdint>

// ---------------------------------------------------------------------------
// GCN pipeline (bf16 MFMA GEMMs):
//  packed-u64 deg/cnt atomic -> dinv -> 3-phase scan (rowptr+fill) ->
//  CSR scatter (int2) -> xcast(bf16) -> MFMA GEMM1 -> AGG1(bf16 out) ->
//  MFMA GEMM2 -> AGG2(bf16 out) -> mean-pool(bf16 in) -> fused head
// ---------------------------------------------------------------------------

#define SCAN_CHUNK 512
#define FIXSCALE 16777216.0f  // 2^24

typedef short bf16x8 __attribute__((ext_vector_type(8)));
typedef float f32x4 __attribute__((ext_vector_type(4)));

// f32 -> bf16 round-to-nearest-even
static __device__ __forceinline__ unsigned int f2bf(float f) {
    unsigned int u = __float_as_uint(f);
    return (u + 0x7fffu + ((u >> 16) & 1u)) >> 16;
}
static __device__ __forceinline__ unsigned int packbf2(float a, float b) {
    return f2bf(a) | (f2bf(b) << 16);
}
static __device__ __forceinline__ float bf_lo(unsigned int v) {
    return __uint_as_float(v << 16);
}
static __device__ __forceinline__ float bf_hi(unsigned int v) {
    return __uint_as_float(v & 0xffff0000u);
}

__global__ void k_init_small(int* gstart, int* gcnt, int G) {
    int g = blockIdx.x * blockDim.x + threadIdx.x;
    if (g < G) { gstart[g] = 0x7fffffff; gcnt[g] = 0; }
}

__global__ void k_init_nodes(const int* __restrict__ batch,
                             unsigned long long* __restrict__ packed,
                             int* gstart, int* gcnt, int N) {
    int i = blockIdx.x * blockDim.x + threadIdx.x;
    if (i >= N) return;
    packed[i] = 0ull;
    int b = batch[i];
    if (i == 0 || batch[i - 1] != b) gstart[b] = i;  // batch sorted -> unique writer
    atomicAdd(&gcnt[b], 1);
}

// one u64 atomic per edge: low32 = edge count, high32 = sum(ew) in 2^-24 fixed pt
__global__ void k_edge1(const int* __restrict__ dst, const float* __restrict__ ew,
                        unsigned long long* __restrict__ packed, int E) {
    int e = blockIdx.x * blockDim.x + threadIdx.x;
    if (e >= E) return;
    int d = dst[e];
    unsigned int fx = (unsigned int)__float2uint_rn(ew[e] * FIXSCALE);
    atomicAdd(&packed[d], ((unsigned long long)fx << 32) | 1ull);
}

__global__ void k_dinv(const unsigned long long* __restrict__ packed,
                       float* __restrict__ dinv, int* __restrict__ cnt, int N) {
    int i = blockIdx.x * blockDim.x + threadIdx.x;
    if (i >= N) return;
    unsigned long long v = packed[i];
    cnt[i] = (int)(v & 0xffffffffull);
    float deg = 1.0f + (float)(v >> 32) * (1.0f / FIXSCALE);  // self-loop +1
    dinv[i] = rsqrtf(deg);
}

// ---- 3-phase exclusive scan of cnt[N] -> rowptr[N+1] (+ fill seed) --------
__global__ __launch_bounds__(256) void k_scan_a(const int* __restrict__ cnt,
                                                int* __restrict__ bsum, int N) {
    __shared__ int sm[256];
    int base = blockIdx.x * SCAN_CHUNK;
    int end = min(base + SCAN_CHUNK, N);
    int s = 0;
    for (int i = base + threadIdx.x; i < end; i += 256) s += cnt[i];
    sm[threadIdx.x] = s;
    __syncthreads();
    for (int d = 128; d > 0; d >>= 1) {
        if (threadIdx.x < d) sm[threadIdx.x] += sm[threadIdx.x + d];
        __syncthreads();
    }
    if (threadIdx.x == 0) bsum[blockIdx.x] = sm[0];
}

__global__ __launch_bounds__(1024) void k_scan_b(const int* __restrict__ bsum,
                                                 int* __restrict__ boff,
                                                 int* __restrict__ rowptr,
                                                 int NB, int N) {
    __shared__ int sm[1024];
    int tid = threadIdx.x;
    int v = (tid < NB) ? bsum[tid] : 0;
    sm[tid] = v;
    __syncthreads();
    for (int d = 1; d < 1024; d <<= 1) {
        int t = (tid >= d) ? sm[tid - d] : 0;
        __syncthreads();
        sm[tid] += t;
        __syncthreads();
    }
    if (tid < NB) boff[tid] = sm[tid] - v;   // exclusive
    if (tid == NB - 1) rowptr[N] = sm[tid];  // total
}

__global__ __launch_bounds__(256) void k_scan_c(const int* __restrict__ cnt,
                                                const int* __restrict__ boff,
                                                int* __restrict__ rowptr,
                                                int* __restrict__ fill, int N) {
    __shared__ int sm[256];
    int base = blockIdx.x * SCAN_CHUNK;
    int end = min(base + SCAN_CHUNK, N);
    int running = boff[blockIdx.x];
    for (int t0 = base; t0 < end; t0 += 256) {
        int i = t0 + threadIdx.x;
        int v = (i < end) ? cnt[i] : 0;
        sm[threadIdx.x] = v;
        __syncthreads();
        for (int d = 1; d < 256; d <<= 1) {
            int t = (threadIdx.x >= d) ? sm[threadIdx.x - d] : 0;
            __syncthreads();
            sm[threadIdx.x] += t;
            __syncthreads();
        }
        if (i < end) {
            int rp = running + sm[threadIdx.x] - v;
            rowptr[i] = rp;
            fill[i] = rp;  // seed: edge2's atomicAdd returns position directly
        }
        running += sm[255];
        __syncthreads();
    }
}
// ---------------------------------------------------------------------------

__global__ void k_edge2(const int* __restrict__ src, const int* __restrict__ dst,
                        const float* __restrict__ ew, const float* __restrict__ dinv,
                        int* fill, int2* __restrict__ cvb, int E) {
    int e = blockIdx.x * blockDim.x + threadIdx.x;
    if (e >= E) return;
    int s = src[e], d = dst[e];
    int pos = atomicAdd(&fill[d], 1);
    float val = dinv[s] * ew[e] * dinv[d];
    cvb[pos] = make_int2(s, __float_as_int(val));
}

// x (f32) -> Xb (bf16), 8 elems/thread
__global__ __launch_bounds__(256) void k_xcast(const float* __restrict__ x,
                                               unsigned int* __restrict__ Xb, int n8) {
    int i = blockIdx.x * blockDim.x + threadIdx.x;
    if (i >= n8) return;
    const float4* xp = reinterpret_cast<const float4*>(x) + (size_t)i * 2;
    float4 v0 = xp[0], v1 = xp[1];
    uint4 o;
    o.x = packbf2(v0.x, v0.y);
    o.y = packbf2(v0.z, v0.w);
    o.z = packbf2(v1.x, v1.y);
    o.w = packbf2(v1.z, v1.w);
    reinterpret_cast<uint4*>(Xb)[i] = o;
}

// W[k][n] f32 -> WT[n][k] bf16  (16384 elems, 64 blocks x 256)
__global__ __launch_bounds__(256) void k_wt(const float* __restrict__ W,
                                            unsigned short* __restrict__ WT) {
    int idx = blockIdx.x * 256 + threadIdx.x;
    int n = idx >> 7, k = idx & 127;
    WT[idx] = (unsigned short)f2bf(W[(size_t)k * 128 + n]);
}

// Y[M,128](bf16) = Xb[M,128](bf16) @ W (via WT[n][k] bf16), MFMA 16x16x32.
// 256 thr = 4 waves; wave computes 16 rows x 128 cols; K=128 -> 4 chunks.
// A frag: lane l holds Xb[rowb+(l&15)][kc*32+(l>>4)*8 ..+8]
// B frag: lane l holds WT[nt*16+(l&15)][kc*32+(l>>4)*8 ..+8]
// D: col=lane&15, row=(lane>>4)*4+reg (verified layout)
__global__ __launch_bounds__(256) void k_gemm(const unsigned short* __restrict__ Xb,
                                              const unsigned short* __restrict__ WT,
                                              unsigned short* __restrict__ Y, int M) {
    int tid = threadIdx.x;
    int wid = tid >> 6, lane = tid & 63;
    int rowb = blockIdx.x * 64 + wid * 16;
    int r16 = lane & 15, kg = lane >> 4;
    const bf16x8* Ap = reinterpret_cast<const bf16x8*>(Xb + (size_t)(rowb + r16) * 128 + kg * 8);
    bf16x8 a0 = Ap[0], a1 = Ap[4], a2 = Ap[8], a3 = Ap[12];  // kc stride 32 elem = 4 frags
    const bf16x8* Bp = reinterpret_cast<const bf16x8*>(WT + (size_t)r16 * 128 + kg * 8);
#pragma unroll
    for (int nt = 0; nt < 8; ++nt) {
        const bf16x8* B = Bp + (size_t)nt * 256;  // nt*16 rows * 16 frags/row
        f32x4 acc = {0.f, 0.f, 0.f, 0.f};
        acc = __builtin_amdgcn_mfma_f32_16x16x32_bf16(a0, B[0], acc, 0, 0, 0);
        acc = __builtin_amdgcn_mfma_f32_16x16x32_bf16(a1, B[4], acc, 0, 0, 0);
        acc = __builtin_amdgcn_mfma_f32_16x16x32_bf16(a2, B[8], acc, 0, 0, 0);
        acc = __builtin_amdgcn_mfma_f32_16x16x32_bf16(a3, B[12], acc, 0, 0, 0);
        int colo = nt * 16 + r16;
#pragma unroll
        for (int r = 0; r < 4; ++r) {
            int ro = rowb + kg * 4 + r;
            if (ro < M) Y[(size_t)ro * 128 + colo] = (unsigned short)f2bf(acc[r]);
        }
    }
}

// Out[d] = relu( sum_e val[e]*H[col[e]] + dinv[d]^2*H[d] + bias ), bf16 in/out
// one wave per node; lane holds 2 features (one u32 = 2 bf16).
__global__ __launch_bounds__(256) void k_agg(const unsigned int* __restrict__ Hb,
                                             const int* __restrict__ rowptr,
                                             const int2* __restrict__ cvb,
                                             const float* __restrict__ dinv,
                                             const float* __restrict__ bias,
                                             unsigned int* __restrict__ OutB, int N) {
    int lane = threadIdx.x & 63;
    int node = blockIdx.x * 4 + (threadIdx.x >> 6);
    if (node >= N) return;
    int beg = rowptr[node], end = rowptr[node + 1];
    float di = dinv[node];
    unsigned int hv = Hb[(size_t)node * 64 + lane];
    float sn = di * di;
    float a0 = sn * bf_lo(hv), a1 = sn * bf_hi(hv);
    int n = end - beg;
    for (int base = 0; base < n; base += 64) {
        int m = min(64, n - base);
        int cl = 0; float vl = 0.f;
        if (base + lane < n) {
            int2 cv = cvb[beg + base + lane];
            cl = cv.x;
            vl = __int_as_float(cv.y);
        }
        for (int j0 = 0; j0 < m; j0 += 4) {
#pragma unroll
            for (int jj = 0; jj < 4; ++jj) {
                int j = j0 + jj;
                if (j < m) {
                    int sIdx = __shfl(cl, j);
                    float v = __shfl(vl, j);
                    unsigned int h = Hb[(size_t)sIdx * 64 + lane];
                    a0 = fmaf(v, bf_lo(h), a0);
                    a1 = fmaf(v, bf_hi(h), a1);
                }
            }
        }
    }
    float2 bv = reinterpret_cast<const float2*>(bias)[lane];
    a0 = fmaxf(a0 + bv.x, 0.f);
    a1 = fmaxf(a1 + bv.y, 0.f);
    OutB[(size_t)node * 64 + lane] = packbf2(a0, a1);
}

// mean pool over bf16 rows: graph g = rows [gstart[g], gstart[g]+gcnt[g])
__global__ __launch_bounds__(256) void k_pool(const unsigned int* __restrict__ H2u,
                                              const int* __restrict__ gstart,
                                              const int* __restrict__ gcnt,
                                              float* __restrict__ gmean) {
    int g = blockIdx.x;
    int tid = threadIdx.x;
    int cu = tid & 63, q = tid >> 6;  // cu: u32 col (2 feats), q: row stride phase
    __shared__ float r0[256], r1[256];
    int cntg = gcnt[g];
    int b = gstart[g];
    float s0 = 0.f, s1 = 0.f;
    for (int i = q; i < cntg; i += 4) {
        unsigned int v = H2u[(size_t)(b + i) * 64 + cu];
        s0 += bf_lo(v);
        s1 += bf_hi(v);
    }
    r0[tid] = s0; r1[tid] = s1;
    __syncthreads();
    if (tid < 64) {
        float t0 = r0[cu] + r0[cu + 64] + r0[cu + 128] + r0[cu + 192];
        float t1 = r1[cu] + r1[cu + 64] + r1[cu + 128] + r1[cu + 192];
        float inv = 1.f / fmaxf((float)cntg, 1.f);
        gmean[g * 128 + 2 * cu] = t0 * inv;
        gmean[g * 128 + 2 * cu + 1] = t1 * inv;
    }
}

// head: md = relu(metadata[first%G] @ Wm + bm); out = [pooled, md] @ Wf + bf
__global__ __launch_bounds__(128) void k_final(const float* __restrict__ gmean,
                                               const int* __restrict__ gstart,
                                               const float* __restrict__ meta,
                                               const float* __restrict__ Wm,
                                               const float* __restrict__ bm,
                                               const float* __restrict__ Wf,
                                               const float* __restrict__ bf,
                                               float* __restrict__ out, int G) {
    int g = blockIdx.x;
    int c = threadIdx.x;  // 128 threads
    __shared__ float red[128];
    float pooled = gmean[g * 128 + c];
    int fn = gstart[g];          // INT_MAX for empty graph (matches segment_min identity)
    int idx = fn % G;            // metadata.shape[0] == G
    float m = bm[c];
#pragma unroll
    for (int k = 0; k < 30; ++k) m = fmaf(meta[idx * 30 + k], Wm[k * 128 + c], m);
    m = fmaxf(m, 0.f);
    float part = pooled * Wf[c] + m * Wf[128 + c];
    red[c] = part;
    __syncthreads();
    for (int st = 64; st > 0; st >>= 1) {
        if (c < st) red[c] += red[c + st];
        __syncthreads();
    }
    if (c == 0) out[g] = red[0] + bf[0];
}

extern "C" void kernel_launch(void* const* d_in, const int* in_sizes, int n_in,
                              void* d_out, int out_size, void* d_ws, size_t ws_size,
                              hipStream_t stream) {
    const float* x     = (const float*)d_in[0];
    const int*   ei    = (const int*)d_in[1];
    const float* ew    = (const float*)d_in[2];
    const int*   batch = (const int*)d_in[3];
    const float* meta  = (const float*)d_in[4];
    const float* W1    = (const float*)d_in[5];
    const float* b1    = (const float*)d_in[6];
    const float* W2    = (const float*)d_in[7];
    const float* b2    = (const float*)d_in[8];
    const float* Wm    = (const float*)d_in[9];
    const float* bm    = (const float*)d_in[10];
    const float* Wf    = (const float*)d_in[11];
    const float* bf    = (const float*)d_in[12];

    int N = in_sizes[0] / 128;
    int E = in_sizes[2];
    int G = in_sizes[4] / 30;
    int Mpad = (N + 63) & ~63;
    const int* srcp = ei;
    const int* dstp = ei + E;

    char* p = (char*)d_ws;
    auto alloc = [&](size_t bytes) -> void* {
        void* r = p;
        p += (bytes + 255) & ~(size_t)255;
        return r;
    };
    unsigned long long* packed = (unsigned long long*)alloc((size_t)N * 8);
    float* dinv   = (float*)alloc((size_t)N * 4);
    int*   cnt    = (int*)alloc((size_t)N * 4);
    int*   fill   = (int*)alloc((size_t)N * 4);
    int*   rowptr = (int*)alloc((size_t)(N + 1) * 4);
    int2*  cvb    = (int2*)alloc((size_t)E * 8);
    unsigned short* Xb  = (unsigned short*)alloc((size_t)Mpad * 128 * 2);
    unsigned short* H   = (unsigned short*)alloc((size_t)Mpad * 128 * 2);
    unsigned short* H2  = (unsigned short*)alloc((size_t)Mpad * 128 * 2);
    unsigned short* WT1 = (unsigned short*)alloc(128 * 128 * 2);
    unsigned short* WT2 = (unsigned short*)alloc(128 * 128 * 2);
    float* gmean  = (float*)alloc((size_t)G * 128 * 4);
    int*   gstart = (int*)alloc((size_t)G * 4);
    int*   gcnt   = (int*)alloc((size_t)G * 4);
    int NB = (N + SCAN_CHUNK - 1) / SCAN_CHUNK;
    int*   bsum   = (int*)alloc((size_t)NB * 4);
    int*   boff   = (int*)alloc((size_t)NB * 4);

    k_init_small<<<(G + 255) / 256, 256, 0, stream>>>(gstart, gcnt, G);
    k_init_nodes<<<(N + 255) / 256, 256, 0, stream>>>(batch, packed, gstart, gcnt, N);
    k_edge1<<<(E + 255) / 256, 256, 0, stream>>>(dstp, ew, packed, E);
    k_dinv<<<(N + 255) / 256, 256, 0, stream>>>(packed, dinv, cnt, N);
    k_scan_a<<<NB, 256, 0, stream>>>(cnt, bsum, N);
    k_scan_b<<<1, 1024, 0, stream>>>(bsum, boff, rowptr, NB, N);
    k_scan_c<<<NB, 256, 0, stream>>>(cnt, boff, rowptr, fill, N);
    k_edge2<<<(E + 255) / 256, 256, 0, stream>>>(srcp, dstp, ew, dinv, fill, cvb, E);

    int n8 = N * 128 / 8;
    k_xcast<<<(n8 + 255) / 256, 256, 0, stream>>>(x, (unsigned int*)Xb, n8);
    k_wt<<<64, 256, 0, stream>>>(W1, WT1);
    k_wt<<<64, 256, 0, stream>>>(W2, WT2);

    k_gemm<<<Mpad / 64, 256, 0, stream>>>(Xb, WT1, H, N);
    k_agg<<<(N + 3) / 4, 256, 0, stream>>>((const unsigned int*)H, rowptr, cvb, dinv, b1,
                                           (unsigned int*)H2, N);
    k_gemm<<<Mpad / 64, 256, 0, stream>>>(H2, WT2, H, N);
    k_agg<<<(N + 3) / 4, 256, 0, stream>>>((const unsigned int*)H, rowptr, cvb, dinv, b2,
                                           (unsigned int*)H2, N);

    k_pool<<<G, 256, 0, stream>>>((const unsigned int*)H2, gstart, gcnt, gmean);
    k_final<<<G, 128, 0, stream>>>(gmean, gstart, meta, Wm, bm, Wf, bf, (float*)d_out, G);
}

// Round 6
// 555.635 us; speedup vs baseline: 1.3710x; 1.0385x over previous
//
#include <hip/hip_runtime.h>
#include <cstdint>

// ---------------------------------------------------------------------------
// GCN pipeline (bf16 MFMA GEMMs, dinv folded into GEMM epilogue):
//  cnt atomic -> 3-phase scan (rowptr+fill) -> CSR scatter (src,ew) ->
//  k_deg (segmented sum -> dinv) -> xcast -> GEMM1(xW*dinv) -> AGG1 ->
//  GEMM2(*dinv) -> AGG2 -> mean-pool -> fused head
// ---------------------------------------------------------------------------

#define SCAN_CHUNK 512

typedef short bf16x8 __attribute__((ext_vector_type(8)));
typedef float f32x4 __attribute__((ext_vector_type(4)));

// f32 -> bf16 round-to-nearest-even
static __device__ __forceinline__ unsigned int f2bf(float f) {
    unsigned int u = __float_as_uint(f);
    return (u + 0x7fffu + ((u >> 16) & 1u)) >> 16;
}
static __device__ __forceinline__ unsigned int packbf2(float a, float b) {
    return f2bf(a) | (f2bf(b) << 16);
}
static __device__ __forceinline__ float bf_lo(unsigned int v) {
    return __uint_as_float(v << 16);
}
static __device__ __forceinline__ float bf_hi(unsigned int v) {
    return __uint_as_float(v & 0xffff0000u);
}

__global__ void k_init_small(int* gstart, int* gcnt, int G) {
    int g = blockIdx.x * blockDim.x + threadIdx.x;
    if (g < G) { gstart[g] = 0x7fffffff; gcnt[g] = 0; }
}

__global__ void k_init_nodes(const int* __restrict__ batch, int* __restrict__ cnt,
                             int* gstart, int* gcnt, int N) {
    int i = blockIdx.x * blockDim.x + threadIdx.x;
    if (i >= N) return;
    cnt[i] = 0;
    int b = batch[i];
    if (i == 0 || batch[i - 1] != b) gstart[b] = i;  // batch sorted -> unique writer
    atomicAdd(&gcnt[b], 1);
}

// count edges per dst (single u32 atomic per edge)
__global__ void k_edge1(const int* __restrict__ dst, int* __restrict__ cnt, int E) {
    int e = blockIdx.x * blockDim.x + threadIdx.x;
    if (e >= E) return;
    atomicAdd(&cnt[dst[e]], 1);
}

// ---- 3-phase exclusive scan of cnt[N] -> rowptr[N+1] (+ fill seed) --------
__global__ __launch_bounds__(256) void k_scan_a(const int* __restrict__ cnt,
                                                int* __restrict__ bsum, int N) {
    __shared__ int sm[256];
    int base = blockIdx.x * SCAN_CHUNK;
    int end = min(base + SCAN_CHUNK, N);
    int s = 0;
    for (int i = base + threadIdx.x; i < end; i += 256) s += cnt[i];
    sm[threadIdx.x] = s;
    __syncthreads();
    for (int d = 128; d > 0; d >>= 1) {
        if (threadIdx.x < d) sm[threadIdx.x] += sm[threadIdx.x + d];
        __syncthreads();
    }
    if (threadIdx.x == 0) bsum[blockIdx.x] = sm[0];
}

__global__ __launch_bounds__(1024) void k_scan_b(const int* __restrict__ bsum,
                                                 int* __restrict__ boff,
                                                 int* __restrict__ rowptr,
                                                 int NB, int N) {
    __shared__ int sm[1024];
    int tid = threadIdx.x;
    int v = (tid < NB) ? bsum[tid] : 0;
    sm[tid] = v;
    __syncthreads();
    for (int d = 1; d < 1024; d <<= 1) {
        int t = (tid >= d) ? sm[tid - d] : 0;
        __syncthreads();
        sm[tid] += t;
        __syncthreads();
    }
    if (tid < NB) boff[tid] = sm[tid] - v;   // exclusive
    if (tid == NB - 1) rowptr[N] = sm[tid];  // total
}

__global__ __launch_bounds__(256) void k_scan_c(const int* __restrict__ cnt,
                                                const int* __restrict__ boff,
                                                int* __restrict__ rowptr,
                                                int* __restrict__ fill, int N) {
    __shared__ int sm[256];
    int base = blockIdx.x * SCAN_CHUNK;
    int end = min(base + SCAN_CHUNK, N);
    int running = boff[blockIdx.x];
    for (int t0 = base; t0 < end; t0 += 256) {
        int i = t0 + threadIdx.x;
        int v = (i < end) ? cnt[i] : 0;
        sm[threadIdx.x] = v;
        __syncthreads();
        for (int d = 1; d < 256; d <<= 1) {
            int t = (threadIdx.x >= d) ? sm[threadIdx.x - d] : 0;
            __syncthreads();
            sm[threadIdx.x] += t;
            __syncthreads();
        }
        if (i < end) {
            int rp = running + sm[threadIdx.x] - v;
            rowptr[i] = rp;
            fill[i] = rp;  // seed: edge2's atomicAdd returns position directly
        }
        running += sm[255];
        __syncthreads();
    }
}
// ---------------------------------------------------------------------------

// scatter (src, ew) into CSR order — no dinv dependency
__global__ void k_edge2(const int* __restrict__ src, const int* __restrict__ dst,
                        const float* __restrict__ ew,
                        int* fill, int2* __restrict__ cvb, int E) {
    int e = blockIdx.x * blockDim.x + threadIdx.x;
    if (e >= E) return;
    int s = src[e], d = dst[e];
    int pos = atomicAdd(&fill[d], 1);
    cvb[pos] = make_int2(s, __float_as_int(ew[e]));
}

// deg[d] = 1 + sum of ew over row d -> dinv = rsqrt ; one wave per node
__global__ __launch_bounds__(256) void k_deg(const int2* __restrict__ cvb,
                                             const int* __restrict__ rowptr,
                                             float* __restrict__ dinv, int N) {
    int lane = threadIdx.x & 63;
    int node = blockIdx.x * 4 + (threadIdx.x >> 6);
    if (node >= N) return;
    int beg = rowptr[node], end = rowptr[node + 1];
    float s = 0.f;
    for (int i = beg + lane; i < end; i += 64) s += __int_as_float(cvb[i].y);
#pragma unroll
    for (int off = 32; off > 0; off >>= 1) s += __shfl_xor(s, off);
    if (lane == 0) dinv[node] = rsqrtf(1.0f + s);
}

// x (f32) -> Xb (bf16), 8 elems/thread
__global__ __launch_bounds__(256) void k_xcast(const float* __restrict__ x,
                                               unsigned int* __restrict__ Xb, int n8) {
    int i = blockIdx.x * blockDim.x + threadIdx.x;
    if (i >= n8) return;
    const float4* xp = reinterpret_cast<const float4*>(x) + (size_t)i * 2;
    float4 v0 = xp[0], v1 = xp[1];
    uint4 o;
    o.x = packbf2(v0.x, v0.y);
    o.y = packbf2(v0.z, v0.w);
    o.z = packbf2(v1.x, v1.y);
    o.w = packbf2(v1.z, v1.w);
    reinterpret_cast<uint4*>(Xb)[i] = o;
}

// W[k][n] f32 -> WT[n][k] bf16  (16384 elems, 64 blocks x 256)
__global__ __launch_bounds__(256) void k_wt(const float* __restrict__ W,
                                            unsigned short* __restrict__ WT) {
    int idx = blockIdx.x * 256 + threadIdx.x;
    int n = idx >> 7, k = idx & 127;
    WT[idx] = (unsigned short)f2bf(W[(size_t)k * 128 + n]);
}

// Y[M,128](bf16) = dinv[row] * (Xb[M,128] @ W) via MFMA 16x16x32.
// 256 thr = 4 waves; wave computes 16 rows x 128 cols; K=128 -> 4 chunks.
__global__ __launch_bounds__(256) void k_gemm(const unsigned short* __restrict__ Xb,
                                              const unsigned short* __restrict__ WT,
                                              const float* __restrict__ dinv,
                                              unsigned short* __restrict__ Y, int M) {
    int tid = threadIdx.x;
    int wid = tid >> 6, lane = tid & 63;
    int rowb = blockIdx.x * 64 + wid * 16;
    int r16 = lane & 15, kg = lane >> 4;
    const bf16x8* Ap = reinterpret_cast<const bf16x8*>(Xb + (size_t)(rowb + r16) * 128 + kg * 8);
    bf16x8 a0 = Ap[0], a1 = Ap[4], a2 = Ap[8], a3 = Ap[12];  // kc stride 32 elem
    float dv[4];
#pragma unroll
    for (int r = 0; r < 4; ++r) {
        int ro = rowb + kg * 4 + r;
        dv[r] = (ro < M) ? dinv[ro] : 0.f;
    }
    const bf16x8* Bp = reinterpret_cast<const bf16x8*>(WT + (size_t)r16 * 128 + kg * 8);
#pragma unroll
    for (int nt = 0; nt < 8; ++nt) {
        const bf16x8* B = Bp + (size_t)nt * 256;  // nt*16 rows * 16 frags/row
        f32x4 acc = {0.f, 0.f, 0.f, 0.f};
        acc = __builtin_amdgcn_mfma_f32_16x16x32_bf16(a0, B[0], acc, 0, 0, 0);
        acc = __builtin_amdgcn_mfma_f32_16x16x32_bf16(a1, B[4], acc, 0, 0, 0);
        acc = __builtin_amdgcn_mfma_f32_16x16x32_bf16(a2, B[8], acc, 0, 0, 0);
        acc = __builtin_amdgcn_mfma_f32_16x16x32_bf16(a3, B[12], acc, 0, 0, 0);
        int colo = nt * 16 + r16;
#pragma unroll
        for (int r = 0; r < 4; ++r) {
            int ro = rowb + kg * 4 + r;
            if (ro < M) Y[(size_t)ro * 128 + colo] = (unsigned short)f2bf(acc[r] * dv[r]);
        }
    }
}

// Out[d] = relu( dinv[d]*( sum_e ew_e*H'[s_e] + H'[d] ) + bias ), bf16 in/out
// H' rows are pre-scaled by dinv. TWO nodes per wave (double gather MLP).
__global__ __launch_bounds__(256) void k_agg(const unsigned int* __restrict__ Hb,
                                             const int* __restrict__ rowptr,
                                             const int2* __restrict__ cvb,
                                             const float* __restrict__ dinv,
                                             const float* __restrict__ bias,
                                             unsigned int* __restrict__ OutB, int N) {
    int lane = threadIdx.x & 63;
    int pair = blockIdx.x * 4 + (threadIdx.x >> 6);
    int n0 = pair * 2, n1 = n0 + 1;
    if (n0 >= N) return;
    bool has1 = (n1 < N);
    int beg0 = rowptr[n0], end0 = rowptr[n0 + 1];
    int beg1 = has1 ? rowptr[n1] : 0;
    int end1 = has1 ? rowptr[n1 + 1] : 0;
    unsigned int hv0 = Hb[(size_t)n0 * 64 + lane];
    unsigned int hv1 = has1 ? Hb[(size_t)n1 * 64 + lane] : 0u;
    float a00 = bf_lo(hv0), a01 = bf_hi(hv0);  // self term (H' already scaled)
    float a10 = bf_lo(hv1), a11 = bf_hi(hv1);
    int c0n = end0 - beg0, c1n = end1 - beg1;
    int nmax = max(c0n, c1n);
    for (int base = 0; base < nmax; base += 64) {
        int cl0 = 0, cl1 = 0;
        float vl0 = 0.f, vl1 = 0.f;
        if (base + lane < c0n) {
            int2 cv = cvb[beg0 + base + lane];
            cl0 = cv.x; vl0 = __int_as_float(cv.y);
        }
        if (base + lane < c1n) {
            int2 cv = cvb[beg1 + base + lane];
            cl1 = cv.x; vl1 = __int_as_float(cv.y);
        }
        int m = min(64, nmax - base);
        for (int j0 = 0; j0 < m; j0 += 4) {
#pragma unroll
            for (int jj = 0; jj < 4; ++jj) {
                int j = j0 + jj;
                if (j < m) {
                    int s0 = __shfl(cl0, j);
                    float v0 = __shfl(vl0, j);
                    int s1 = __shfl(cl1, j);
                    float v1 = __shfl(vl1, j);
                    unsigned int h0 = Hb[(size_t)s0 * 64 + lane];
                    unsigned int h1 = Hb[(size_t)s1 * 64 + lane];
                    a00 = fmaf(v0, bf_lo(h0), a00);
                    a01 = fmaf(v0, bf_hi(h0), a01);
                    a10 = fmaf(v1, bf_lo(h1), a10);
                    a11 = fmaf(v1, bf_hi(h1), a11);
                }
            }
        }
    }
    float2 bv = reinterpret_cast<const float2*>(bias)[lane];
    float d0 = dinv[n0];
    a00 = fmaxf(fmaf(a00, d0, bv.x), 0.f);
    a01 = fmaxf(fmaf(a01, d0, bv.y), 0.f);
    OutB[(size_t)n0 * 64 + lane] = packbf2(a00, a01);
    if (has1) {
        float d1 = dinv[n1];
        a10 = fmaxf(fmaf(a10, d1, bv.x), 0.f);
        a11 = fmaxf(fmaf(a11, d1, bv.y), 0.f);
        OutB[(size_t)n1 * 64 + lane] = packbf2(a10, a11);
    }
}

// mean pool over bf16 rows: graph g = rows [gstart[g], gstart[g]+gcnt[g])
__global__ __launch_bounds__(256) void k_pool(const unsigned int* __restrict__ H2u,
                                              const int* __restrict__ gstart,
                                              const int* __restrict__ gcnt,
                                              float* __restrict__ gmean) {
    int g = blockIdx.x;
    int tid = threadIdx.x;
    int cu = tid & 63, q = tid >> 6;
    __shared__ float r0[256], r1[256];
    int cntg = gcnt[g];
    int b = gstart[g];
    float s0 = 0.f, s1 = 0.f;
    for (int i = q; i < cntg; i += 4) {
        unsigned int v = H2u[(size_t)(b + i) * 64 + cu];
        s0 += bf_lo(v);
        s1 += bf_hi(v);
    }
    r0[tid] = s0; r1[tid] = s1;
    __syncthreads();
    if (tid < 64) {
        float t0 = r0[cu] + r0[cu + 64] + r0[cu + 128] + r0[cu + 192];
        float t1 = r1[cu] + r1[cu + 64] + r1[cu + 128] + r1[cu + 192];
        float inv = 1.f / fmaxf((float)cntg, 1.f);
        gmean[g * 128 + 2 * cu] = t0 * inv;
        gmean[g * 128 + 2 * cu + 1] = t1 * inv;
    }
}

// head: md = relu(metadata[first%G] @ Wm + bm); out = [pooled, md] @ Wf + bf
__global__ __launch_bounds__(128) void k_final(const float* __restrict__ gmean,
                                               const int* __restrict__ gstart,
                                               const float* __restrict__ meta,
                                               const float* __restrict__ Wm,
                                               const float* __restrict__ bm,
                                               const float* __restrict__ Wf,
                                               const float* __restrict__ bf,
                                               float* __restrict__ out, int G) {
    int g = blockIdx.x;
    int c = threadIdx.x;  // 128 threads
    __shared__ float red[128];
    float pooled = gmean[g * 128 + c];
    int fn = gstart[g];          // INT_MAX for empty graph (matches segment_min identity)
    int idx = fn % G;            // metadata.shape[0] == G
    float m = bm[c];
#pragma unroll
    for (int k = 0; k < 30; ++k) m = fmaf(meta[idx * 30 + k], Wm[k * 128 + c], m);
    m = fmaxf(m, 0.f);
    float part = pooled * Wf[c] + m * Wf[128 + c];
    red[c] = part;
    __syncthreads();
    for (int st = 64; st > 0; st >>= 1) {
        if (c < st) red[c] += red[c + st];
        __syncthreads();
    }
    if (c == 0) out[g] = red[0] + bf[0];
}

extern "C" void kernel_launch(void* const* d_in, const int* in_sizes, int n_in,
                              void* d_out, int out_size, void* d_ws, size_t ws_size,
                              hipStream_t stream) {
    const float* x     = (const float*)d_in[0];
    const int*   ei    = (const int*)d_in[1];
    const float* ew    = (const float*)d_in[2];
    const int*   batch = (const int*)d_in[3];
    const float* meta  = (const float*)d_in[4];
    const float* W1    = (const float*)d_in[5];
    const float* b1    = (const float*)d_in[6];
    const float* W2    = (const float*)d_in[7];
    const float* b2    = (const float*)d_in[8];
    const float* Wm    = (const float*)d_in[9];
    const float* bm    = (const float*)d_in[10];
    const float* Wf    = (const float*)d_in[11];
    const float* bf    = (const float*)d_in[12];

    int N = in_sizes[0] / 128;
    int E = in_sizes[2];
    int G = in_sizes[4] / 30;
    int Mpad = (N + 63) & ~63;
    const int* srcp = ei;
    const int* dstp = ei + E;

    char* p = (char*)d_ws;
    auto alloc = [&](size_t bytes) -> void* {
        void* r = p;
        p += (bytes + 255) & ~(size_t)255;
        return r;
    };
    float* dinv   = (float*)alloc((size_t)N * 4);
    int*   cnt    = (int*)alloc((size_t)N * 4);
    int*   fill   = (int*)alloc((size_t)N * 4);
    int*   rowptr = (int*)alloc((size_t)(N + 1) * 4);
    int2*  cvb    = (int2*)alloc((size_t)E * 8);
    unsigned short* Xb  = (unsigned short*)alloc((size_t)Mpad * 128 * 2);
    unsigned short* H   = (unsigned short*)alloc((size_t)Mpad * 128 * 2);
    unsigned short* H2  = (unsigned short*)alloc((size_t)Mpad * 128 * 2);
    unsigned short* WT1 = (unsigned short*)alloc(128 * 128 * 2);
    unsigned short* WT2 = (unsigned short*)alloc(128 * 128 * 2);
    float* gmean  = (float*)alloc((size_t)G * 128 * 4);
    int*   gstart = (int*)alloc((size_t)G * 4);
    int*   gcnt   = (int*)alloc((size_t)G * 4);
    int NB = (N + SCAN_CHUNK - 1) / SCAN_CHUNK;
    int*   bsum   = (int*)alloc((size_t)NB * 4);
    int*   boff   = (int*)alloc((size_t)NB * 4);

    k_init_small<<<(G + 255) / 256, 256, 0, stream>>>(gstart, gcnt, G);
    k_init_nodes<<<(N + 255) / 256, 256, 0, stream>>>(batch, cnt, gstart, gcnt, N);
    k_edge1<<<(E + 255) / 256, 256, 0, stream>>>(dstp, cnt, E);
    k_scan_a<<<NB, 256, 0, stream>>>(cnt, bsum, N);
    k_scan_b<<<1, 1024, 0, stream>>>(bsum, boff, rowptr, NB, N);
    k_scan_c<<<NB, 256, 0, stream>>>(cnt, boff, rowptr, fill, N);
    k_edge2<<<(E + 255) / 256, 256, 0, stream>>>(srcp, dstp, ew, fill, cvb, E);
    k_deg<<<(N + 3) / 4, 256, 0, stream>>>(cvb, rowptr, dinv, N);

    int n8 = N * 128 / 8;
    k_xcast<<<(n8 + 255) / 256, 256, 0, stream>>>(x, (unsigned int*)Xb, n8);
    k_wt<<<64, 256, 0, stream>>>(W1, WT1);
    k_wt<<<64, 256, 0, stream>>>(W2, WT2);

    k_gemm<<<Mpad / 64, 256, 0, stream>>>(Xb, WT1, dinv, H, N);
    k_agg<<<(N + 7) / 8, 256, 0, stream>>>((const unsigned int*)H, rowptr, cvb, dinv, b1,
                                           (unsigned int*)H2, N);
    k_gemm<<<Mpad / 64, 256, 0, stream>>>(H2, WT2, dinv, H, N);
    k_agg<<<(N + 7) / 8, 256, 0, stream>>>((const unsigned int*)H, rowptr, cvb, dinv, b2,
                                           (unsigned int*)H2, N);

    k_pool<<<G, 256, 0, stream>>>((const unsigned int*)H2, gstart, gcnt, gmean);
    k_final<<<G, 128, 0, stream>>>(gmean, gstart, meta, Wm, bm, Wf, bf, (float*)d_out, G);
}

// Round 7
// 394.653 us; speedup vs baseline: 1.9302x; 1.4079x over previous
//
#include <hip/hip_runtime.h>
#include <cstdint>

// ---------------------------------------------------------------------------
// GCN pipeline (bf16 MFMA GEMMs, binned CSR build):
//  binhist -> binscan -> binscatter (bucket-major, LDS counting sort) ->
//  k_csr (per-bucket local CSR + rowptr + dinv) -> xcast -> GEMM1(xW*dinv)
//  -> AGG1 -> GEMM2(*dinv) -> AGG2 -> mean-pool -> fused head
// ---------------------------------------------------------------------------

#define BK_SHIFT 9
#define BK_NODES 512            // 1 << BK_SHIFT
#define CH 4096                 // edges per binscatter chunk
#define NODE_BITS 17            // N=100000 < 2^17
#define NODE_MASK ((1 << NODE_BITS) - 1)

typedef short bf16x8 __attribute__((ext_vector_type(8)));
typedef float f32x4 __attribute__((ext_vector_type(4)));

// f32 -> bf16 round-to-nearest-even
static __device__ __forceinline__ unsigned int f2bf(float f) {
    unsigned int u = __float_as_uint(f);
    return (u + 0x7fffu + ((u >> 16) & 1u)) >> 16;
}
static __device__ __forceinline__ unsigned int packbf2(float a, float b) {
    return f2bf(a) | (f2bf(b) << 16);
}
static __device__ __forceinline__ float bf_lo(unsigned int v) {
    return __uint_as_float(v << 16);
}
static __device__ __forceinline__ float bf_hi(unsigned int v) {
    return __uint_as_float(v & 0xffff0000u);
}

// gstart/gcnt init + zero bucket counters
__global__ void k_init_small(int* gstart, int* gcnt, int G, int* bcnt, int NBK) {
    int g = blockIdx.x * blockDim.x + threadIdx.x;
    if (g < G) { gstart[g] = 0x7fffffff; gcnt[g] = 0; }
    if (g < NBK) bcnt[g] = 0;
}

__global__ void k_init_nodes(const int* __restrict__ batch,
                             int* gstart, int* gcnt, int N) {
    int i = blockIdx.x * blockDim.x + threadIdx.x;
    if (i >= N) return;
    int b = batch[i];
    if (i == 0 || batch[i - 1] != b) gstart[b] = i;  // batch sorted -> unique writer
    atomicAdd(&gcnt[b], 1);
}

// ---- Pass A1: per-bucket edge counts ---------------------------------------
__global__ __launch_bounds__(256) void k_binhist(const int* __restrict__ dst, int E,
                                                 int* __restrict__ bcnt, int NBK) {
    __shared__ int h[256];
    int tid = threadIdx.x;
    h[tid] = 0;
    __syncthreads();
    int base = blockIdx.x * CH;
    int nend = min(base + CH, E);
    for (int i = base + tid; i < nend; i += 256) atomicAdd(&h[dst[i] >> BK_SHIFT], 1);
    __syncthreads();
    if (tid < NBK && h[tid]) atomicAdd(&bcnt[tid], h[tid]);
}

// ---- Pass A2: scan bucket counts -> bbase[NBK+1], bfill cursors ------------
__global__ __launch_bounds__(256) void k_binscan(const int* __restrict__ bcnt,
                                                 int* __restrict__ bbase,
                                                 int* __restrict__ bfill, int NBK) {
    __shared__ int sc[256];
    int tid = threadIdx.x;
    int v = (tid < NBK) ? bcnt[tid] : 0;
    sc[tid] = v;
    __syncthreads();
    for (int d = 1; d < 256; d <<= 1) {
        int t = (tid >= d) ? sc[tid - d] : 0;
        __syncthreads();
        sc[tid] += t;
        __syncthreads();
    }
    int excl = sc[tid] - v;
    if (tid < NBK) { bbase[tid] = excl; bfill[tid] = excl; }
    if (tid == 255) bbase[NBK] = sc[255];  // total = E
}

// ---- Pass A3: counting-sort each 4096-edge chunk into bucket-major order ---
__global__ __launch_bounds__(256) void k_binscatter(const int* __restrict__ src,
                                                    const int* __restrict__ dst,
                                                    const float* __restrict__ ew,
                                                    int* __restrict__ bfill,
                                                    int2* __restrict__ binned, int E) {
    __shared__ int2 stage2[CH];          // 32 KB
    __shared__ unsigned char bkt2[CH];   // 4 KB
    __shared__ int hist[256], sc[256], lofs[256], cnt2[256], gbase[256];
    int tid = threadIdx.x;
    int base = blockIdx.x * CH;
    int n = min(CH, E - base);
    hist[tid] = 0;
    cnt2[tid] = 0;
    __syncthreads();
    int2 ev[CH / 256];
    int bk[CH / 256];
#pragma unroll
    for (int j = 0; j < CH / 256; ++j) {
        int i = base + tid + j * 256;
        bk[j] = -1;
        if (i < base + n) {
            int s = src[i], d = dst[i];
            float w = ew[i];
            int b = d >> BK_SHIFT;
            ev[j] = make_int2(s | ((d & (BK_NODES - 1)) << NODE_BITS), __float_as_int(w));
            bk[j] = b;
            atomicAdd(&hist[b], 1);
        }
    }
    __syncthreads();
    int hv = hist[tid];
    sc[tid] = hv;
    __syncthreads();
    for (int d = 1; d < 256; d <<= 1) {
        int t = (tid >= d) ? sc[tid - d] : 0;
        __syncthreads();
        sc[tid] += t;
        __syncthreads();
    }
    lofs[tid] = sc[tid] - hv;
    gbase[tid] = hv ? atomicAdd(&bfill[tid], hv) : 0;
    __syncthreads();
#pragma unroll
    for (int j = 0; j < CH / 256; ++j) {
        if (bk[j] >= 0) {
            int r = atomicAdd(&cnt2[bk[j]], 1);
            int p = lofs[bk[j]] + r;
            stage2[p] = ev[j];
            bkt2[p] = (unsigned char)bk[j];
        }
    }
    __syncthreads();
    for (int i = tid; i < n; i += 256) {
        int b = bkt2[i];
        binned[gbase[b] + (i - lofs[b])] = stage2[i];
    }
}

// ---- Pass B: per-bucket local CSR + rowptr + dinv --------------------------
__global__ __launch_bounds__(256) void k_csr(const int2* __restrict__ binned,
                                             const int* __restrict__ bbase,
                                             int2* __restrict__ cvb,
                                             int* __restrict__ rowptr,
                                             float* __restrict__ dinv, int N, int E) {
    __shared__ int lh[BK_NODES];
    __shared__ float ls[BK_NODES];
    __shared__ int lofs[BK_NODES];
    __shared__ int s2[256];
    int tid = threadIdx.x;
    int b = blockIdx.x;
    int nbase = b << BK_SHIFT;
    int nend = min(nbase + BK_NODES, N);
    int ebase = bbase[b], eend = bbase[b + 1];
    for (int i = tid; i < BK_NODES; i += 256) { lh[i] = 0; ls[i] = 0.f; }
    __syncthreads();
    for (int e = ebase + tid; e < eend; e += 256) {
        int2 v = binned[e];
        int local = (v.x >> NODE_BITS) & (BK_NODES - 1);
        atomicAdd(&lh[local], 1);
        atomicAdd(&ls[local], __int_as_float(v.y));
    }
    __syncthreads();
    // exclusive scan of lh[512] via pairwise + 256-scan
    int p0 = lh[2 * tid], p1 = lh[2 * tid + 1];
    int pv = p0 + p1;
    s2[tid] = pv;
    __syncthreads();
    for (int d = 1; d < 256; d <<= 1) {
        int t = (tid >= d) ? s2[tid - d] : 0;
        __syncthreads();
        s2[tid] += t;
        __syncthreads();
    }
    int e2 = s2[tid] - pv;  // exclusive over pairs
    lofs[2 * tid] = e2;
    lofs[2 * tid + 1] = e2 + p0;
    __syncthreads();
    for (int i = nbase + tid; i < nend; i += 256) {
        int local = i - nbase;
        rowptr[i] = ebase + lofs[local];
        dinv[i] = rsqrtf(1.0f + ls[local]);
    }
    if (b == 0 && tid == 0) rowptr[N] = E;
    __syncthreads();
    for (int e = ebase + tid; e < eend; e += 256) {
        int2 v = binned[e];
        int local = (v.x >> NODE_BITS) & (BK_NODES - 1);
        int r = atomicAdd(&lofs[local], 1);
        cvb[ebase + r] = make_int2(v.x & NODE_MASK, v.y);
    }
}

// x (f32) -> Xb (bf16), 8 elems/thread
__global__ __launch_bounds__(256) void k_xcast(const float* __restrict__ x,
                                               unsigned int* __restrict__ Xb, int n8) {
    int i = blockIdx.x * blockDim.x + threadIdx.x;
    if (i >= n8) return;
    const float4* xp = reinterpret_cast<const float4*>(x) + (size_t)i * 2;
    float4 v0 = xp[0], v1 = xp[1];
    uint4 o;
    o.x = packbf2(v0.x, v0.y);
    o.y = packbf2(v0.z, v0.w);
    o.z = packbf2(v1.x, v1.y);
    o.w = packbf2(v1.z, v1.w);
    reinterpret_cast<uint4*>(Xb)[i] = o;
}

// W[k][n] f32 -> WT[n][k] bf16
__global__ __launch_bounds__(256) void k_wt(const float* __restrict__ W,
                                            unsigned short* __restrict__ WT) {
    int idx = blockIdx.x * 256 + threadIdx.x;
    int n = idx >> 7, k = idx & 127;
    WT[idx] = (unsigned short)f2bf(W[(size_t)k * 128 + n]);
}

// Y[M,128](bf16) = dinv[row] * (Xb[M,128] @ W) via MFMA 16x16x32.
__global__ __launch_bounds__(256) void k_gemm(const unsigned short* __restrict__ Xb,
                                              const unsigned short* __restrict__ WT,
                                              const float* __restrict__ dinv,
                                              unsigned short* __restrict__ Y, int M) {
    int tid = threadIdx.x;
    int wid = tid >> 6, lane = tid & 63;
    int rowb = blockIdx.x * 64 + wid * 16;
    int r16 = lane & 15, kg = lane >> 4;
    const bf16x8* Ap = reinterpret_cast<const bf16x8*>(Xb + (size_t)(rowb + r16) * 128 + kg * 8);
    bf16x8 a0 = Ap[0], a1 = Ap[4], a2 = Ap[8], a3 = Ap[12];
    float dv[4];
#pragma unroll
    for (int r = 0; r < 4; ++r) {
        int ro = rowb + kg * 4 + r;
        dv[r] = (ro < M) ? dinv[ro] : 0.f;
    }
    const bf16x8* Bp = reinterpret_cast<const bf16x8*>(WT + (size_t)r16 * 128 + kg * 8);
#pragma unroll
    for (int nt = 0; nt < 8; ++nt) {
        const bf16x8* B = Bp + (size_t)nt * 256;
        f32x4 acc = {0.f, 0.f, 0.f, 0.f};
        acc = __builtin_amdgcn_mfma_f32_16x16x32_bf16(a0, B[0], acc, 0, 0, 0);
        acc = __builtin_amdgcn_mfma_f32_16x16x32_bf16(a1, B[4], acc, 0, 0, 0);
        acc = __builtin_amdgcn_mfma_f32_16x16x32_bf16(a2, B[8], acc, 0, 0, 0);
        acc = __builtin_amdgcn_mfma_f32_16x16x32_bf16(a3, B[12], acc, 0, 0, 0);
        int colo = nt * 16 + r16;
#pragma unroll
        for (int r = 0; r < 4; ++r) {
            int ro = rowb + kg * 4 + r;
            if (ro < M) Y[(size_t)ro * 128 + colo] = (unsigned short)f2bf(acc[r] * dv[r]);
        }
    }
}

// Out[d] = relu( dinv[d]*( sum_e ew_e*H'[s_e] + H'[d] ) + bias ), bf16 in/out
// H' rows pre-scaled by dinv. TWO nodes per wave.
__global__ __launch_bounds__(256) void k_agg(const unsigned int* __restrict__ Hb,
                                             const int* __restrict__ rowptr,
                                             const int2* __restrict__ cvb,
                                             const float* __restrict__ dinv,
                                             const float* __restrict__ bias,
                                             unsigned int* __restrict__ OutB, int N) {
    int lane = threadIdx.x & 63;
    int pair = blockIdx.x * 4 + (threadIdx.x >> 6);
    int n0 = pair * 2, n1 = n0 + 1;
    if (n0 >= N) return;
    bool has1 = (n1 < N);
    int beg0 = rowptr[n0], end0 = rowptr[n0 + 1];
    int beg1 = has1 ? rowptr[n1] : 0;
    int end1 = has1 ? rowptr[n1 + 1] : 0;
    unsigned int hv0 = Hb[(size_t)n0 * 64 + lane];
    unsigned int hv1 = has1 ? Hb[(size_t)n1 * 64 + lane] : 0u;
    float a00 = bf_lo(hv0), a01 = bf_hi(hv0);
    float a10 = bf_lo(hv1), a11 = bf_hi(hv1);
    int c0n = end0 - beg0, c1n = end1 - beg1;
    int nmax = max(c0n, c1n);
    for (int base = 0; base < nmax; base += 64) {
        int cl0 = 0, cl1 = 0;
        float vl0 = 0.f, vl1 = 0.f;
        if (base + lane < c0n) {
            int2 cv = cvb[beg0 + base + lane];
            cl0 = cv.x; vl0 = __int_as_float(cv.y);
        }
        if (base + lane < c1n) {
            int2 cv = cvb[beg1 + base + lane];
            cl1 = cv.x; vl1 = __int_as_float(cv.y);
        }
        int m = min(64, nmax - base);
        for (int j0 = 0; j0 < m; j0 += 4) {
#pragma unroll
            for (int jj = 0; jj < 4; ++jj) {
                int j = j0 + jj;
                if (j < m) {
                    int s0 = __shfl(cl0, j);
                    float v0 = __shfl(vl0, j);
                    int s1 = __shfl(cl1, j);
                    float v1 = __shfl(vl1, j);
                    unsigned int h0 = Hb[(size_t)s0 * 64 + lane];
                    unsigned int h1 = Hb[(size_t)s1 * 64 + lane];
                    a00 = fmaf(v0, bf_lo(h0), a00);
                    a01 = fmaf(v0, bf_hi(h0), a01);
                    a10 = fmaf(v1, bf_lo(h1), a10);
                    a11 = fmaf(v1, bf_hi(h1), a11);
                }
            }
        }
    }
    float2 bv = reinterpret_cast<const float2*>(bias)[lane];
    float d0 = dinv[n0];
    a00 = fmaxf(fmaf(a00, d0, bv.x), 0.f);
    a01 = fmaxf(fmaf(a01, d0, bv.y), 0.f);
    OutB[(size_t)n0 * 64 + lane] = packbf2(a00, a01);
    if (has1) {
        float d1 = dinv[n1];
        a10 = fmaxf(fmaf(a10, d1, bv.x), 0.f);
        a11 = fmaxf(fmaf(a11, d1, bv.y), 0.f);
        OutB[(size_t)n1 * 64 + lane] = packbf2(a10, a11);
    }
}

// mean pool over bf16 rows
__global__ __launch_bounds__(256) void k_pool(const unsigned int* __restrict__ H2u,
                                              const int* __restrict__ gstart,
                                              const int* __restrict__ gcnt,
                                              float* __restrict__ gmean) {
    int g = blockIdx.x;
    int tid = threadIdx.x;
    int cu = tid & 63, q = tid >> 6;
    __shared__ float r0[256], r1[256];
    int cntg = gcnt[g];
    int b = gstart[g];
    float s0 = 0.f, s1 = 0.f;
    for (int i = q; i < cntg; i += 4) {
        unsigned int v = H2u[(size_t)(b + i) * 64 + cu];
        s0 += bf_lo(v);
        s1 += bf_hi(v);
    }
    r0[tid] = s0; r1[tid] = s1;
    __syncthreads();
    if (tid < 64) {
        float t0 = r0[cu] + r0[cu + 64] + r0[cu + 128] + r0[cu + 192];
        float t1 = r1[cu] + r1[cu + 64] + r1[cu + 128] + r1[cu + 192];
        float inv = 1.f / fmaxf((float)cntg, 1.f);
        gmean[g * 128 + 2 * cu] = t0 * inv;
        gmean[g * 128 + 2 * cu + 1] = t1 * inv;
    }
}

// head: md = relu(metadata[first%G] @ Wm + bm); out = [pooled, md] @ Wf + bf
__global__ __launch_bounds__(128) void k_final(const float* __restrict__ gmean,
                                               const int* __restrict__ gstart,
                                               const float* __restrict__ meta,
                                               const float* __restrict__ Wm,
                                               const float* __restrict__ bm,
                                               const float* __restrict__ Wf,
                                               const float* __restrict__ bf,
                                               float* __restrict__ out, int G) {
    int g = blockIdx.x;
    int c = threadIdx.x;
    __shared__ float red[128];
    float pooled = gmean[g * 128 + c];
    int fn = gstart[g];
    int idx = fn % G;
    float m = bm[c];
#pragma unroll
    for (int k = 0; k < 30; ++k) m = fmaf(meta[idx * 30 + k], Wm[k * 128 + c], m);
    m = fmaxf(m, 0.f);
    float part = pooled * Wf[c] + m * Wf[128 + c];
    red[c] = part;
    __syncthreads();
    for (int st = 64; st > 0; st >>= 1) {
        if (c < st) red[c] += red[c + st];
        __syncthreads();
    }
    if (c == 0) out[g] = red[0] + bf[0];
}

extern "C" void kernel_launch(void* const* d_in, const int* in_sizes, int n_in,
                              void* d_out, int out_size, void* d_ws, size_t ws_size,
                              hipStream_t stream) {
    const float* x     = (const float*)d_in[0];
    const int*   ei    = (const int*)d_in[1];
    const float* ew    = (const float*)d_in[2];
    const int*   batch = (const int*)d_in[3];
    const float* meta  = (const float*)d_in[4];
    const float* W1    = (const float*)d_in[5];
    const float* b1    = (const float*)d_in[6];
    const float* W2    = (const float*)d_in[7];
    const float* b2    = (const float*)d_in[8];
    const float* Wm    = (const float*)d_in[9];
    const float* bm    = (const float*)d_in[10];
    const float* Wf    = (const float*)d_in[11];
    const float* bf    = (const float*)d_in[12];

    int N = in_sizes[0] / 128;
    int E = in_sizes[2];
    int G = in_sizes[4] / 30;
    int Mpad = (N + 63) & ~63;
    int NBK = (N + BK_NODES - 1) >> BK_SHIFT;  // 196 for N=100000 (<=256)
    const int* srcp = ei;
    const int* dstp = ei + E;

    char* p = (char*)d_ws;
    auto alloc = [&](size_t bytes) -> void* {
        void* r = p;
        p += (bytes + 255) & ~(size_t)255;
        return r;
    };
    float* dinv   = (float*)alloc((size_t)N * 4);
    int*   rowptr = (int*)alloc((size_t)(N + 1) * 4);
    int2*  binned = (int2*)alloc((size_t)E * 8);
    int2*  cvb    = (int2*)alloc((size_t)E * 8);
    int*   bcnt   = (int*)alloc((size_t)NBK * 4);
    int*   bbase  = (int*)alloc((size_t)(NBK + 1) * 4);
    int*   bfillp = (int*)alloc((size_t)NBK * 4);
    unsigned short* Xb  = (unsigned short*)alloc((size_t)Mpad * 128 * 2);
    unsigned short* H   = (unsigned short*)alloc((size_t)Mpad * 128 * 2);
    unsigned short* H2  = (unsigned short*)alloc((size_t)Mpad * 128 * 2);
    unsigned short* WT1 = (unsigned short*)alloc(128 * 128 * 2);
    unsigned short* WT2 = (unsigned short*)alloc(128 * 128 * 2);
    float* gmean  = (float*)alloc((size_t)G * 128 * 4);
    int*   gstart = (int*)alloc((size_t)G * 4);
    int*   gcnt   = (int*)alloc((size_t)G * 4);

    int EB = (E + CH - 1) / CH;
    k_init_small<<<(max(G, NBK) + 255) / 256, 256, 0, stream>>>(gstart, gcnt, G, bcnt, NBK);
    k_init_nodes<<<(N + 255) / 256, 256, 0, stream>>>(batch, gstart, gcnt, N);
    k_binhist<<<EB, 256, 0, stream>>>(dstp, E, bcnt, NBK);
    k_binscan<<<1, 256, 0, stream>>>(bcnt, bbase, bfillp, NBK);
    k_binscatter<<<EB, 256, 0, stream>>>(srcp, dstp, ew, bfillp, binned, E);
    k_csr<<<NBK, 256, 0, stream>>>(binned, bbase, cvb, rowptr, dinv, N, E);

    int n8 = N * 128 / 8;
    k_xcast<<<(n8 + 255) / 256, 256, 0, stream>>>(x, (unsigned int*)Xb, n8);
    k_wt<<<64, 256, 0, stream>>>(W1, WT1);
    k_wt<<<64, 256, 0, stream>>>(W2, WT2);

    k_gemm<<<Mpad / 64, 256, 0, stream>>>(Xb, WT1, dinv, H, N);
    k_agg<<<(N + 7) / 8, 256, 0, stream>>>((const unsigned int*)H, rowptr, cvb, dinv, b1,
                                           (unsigned int*)H2, N);
    k_gemm<<<Mpad / 64, 256, 0, stream>>>(H2, WT2, dinv, H, N);
    k_agg<<<(N + 7) / 8, 256, 0, stream>>>((const unsigned int*)H, rowptr, cvb, dinv, b2,
                                           (unsigned int*)H2, N);

    k_pool<<<G, 256, 0, stream>>>((const unsigned int*)H2, gstart, gcnt, gmean);
    k_final<<<G, 128, 0, stream>>>(gmean, gstart, meta, Wm, bm, Wf, bf, (float*)d_out, G);
}

// Round 8
// 375.788 us; speedup vs baseline: 2.0271x; 1.0502x over previous
//
#include <hip/hip_runtime.h>
#include <cstdint>

// ---------------------------------------------------------------------------
// GCN pipeline (bf16 MFMA GEMMs, binned CSR build):
//  binhist -> binscan -> binscatter (bucket-major, LDS counting sort) ->
//  k_csr (per-bucket local CSR + rowptr + dinv) -> xcast -> GEMM1(xW*dinv)
//  -> AGG1 (4 gather streams/wave) -> GEMM2(*dinv) -> AGG2 -> pool -> head
// ---------------------------------------------------------------------------

#define BK_SHIFT 9
#define BK_NODES 512            // 1 << BK_SHIFT
#define CH 4096                 // edges per binscatter chunk
#define NODE_BITS 17            // N=100000 < 2^17
#define NODE_MASK ((1 << NODE_BITS) - 1)

typedef short bf16x8 __attribute__((ext_vector_type(8)));
typedef float f32x4 __attribute__((ext_vector_type(4)));

// f32 -> bf16 round-to-nearest-even
static __device__ __forceinline__ unsigned int f2bf(float f) {
    unsigned int u = __float_as_uint(f);
    return (u + 0x7fffu + ((u >> 16) & 1u)) >> 16;
}
static __device__ __forceinline__ unsigned int packbf2(float a, float b) {
    return f2bf(a) | (f2bf(b) << 16);
}
static __device__ __forceinline__ float bf_lo(unsigned int v) {
    return __uint_as_float(v << 16);
}
static __device__ __forceinline__ float bf_hi(unsigned int v) {
    return __uint_as_float(v & 0xffff0000u);
}

// gstart/gcnt init + zero bucket counters
__global__ void k_init_small(int* gstart, int* gcnt, int G, int* bcnt, int NBK) {
    int g = blockIdx.x * blockDim.x + threadIdx.x;
    if (g < G) { gstart[g] = 0x7fffffff; gcnt[g] = 0; }
    if (g < NBK) bcnt[g] = 0;
}

__global__ void k_init_nodes(const int* __restrict__ batch,
                             int* gstart, int* gcnt, int N) {
    int i = blockIdx.x * blockDim.x + threadIdx.x;
    if (i >= N) return;
    int b = batch[i];
    if (i == 0 || batch[i - 1] != b) gstart[b] = i;  // batch sorted -> unique writer
    atomicAdd(&gcnt[b], 1);
}

// ---- Pass A1: per-bucket edge counts ---------------------------------------
__global__ __launch_bounds__(256) void k_binhist(const int* __restrict__ dst, int E,
                                                 int* __restrict__ bcnt, int NBK) {
    __shared__ int h[256];
    int tid = threadIdx.x;
    h[tid] = 0;
    __syncthreads();
    int base = blockIdx.x * CH;
    int nend = min(base + CH, E);
    for (int i = base + tid; i < nend; i += 256) atomicAdd(&h[dst[i] >> BK_SHIFT], 1);
    __syncthreads();
    if (tid < NBK && h[tid]) atomicAdd(&bcnt[tid], h[tid]);
}

// ---- Pass A2: scan bucket counts -> bbase[NBK+1], bfill cursors ------------
__global__ __launch_bounds__(256) void k_binscan(const int* __restrict__ bcnt,
                                                 int* __restrict__ bbase,
                                                 int* __restrict__ bfill, int NBK) {
    __shared__ int sc[256];
    int tid = threadIdx.x;
    int v = (tid < NBK) ? bcnt[tid] : 0;
    sc[tid] = v;
    __syncthreads();
    for (int d = 1; d < 256; d <<= 1) {
        int t = (tid >= d) ? sc[tid - d] : 0;
        __syncthreads();
        sc[tid] += t;
        __syncthreads();
    }
    int excl = sc[tid] - v;
    if (tid < NBK) { bbase[tid] = excl; bfill[tid] = excl; }
    if (tid == 255) bbase[NBK] = sc[255];  // total = E
}

// ---- Pass A3: counting-sort each 4096-edge chunk into bucket-major order ---
__global__ __launch_bounds__(256) void k_binscatter(const int* __restrict__ src,
                                                    const int* __restrict__ dst,
                                                    const float* __restrict__ ew,
                                                    int* __restrict__ bfill,
                                                    int2* __restrict__ binned, int E) {
    __shared__ int2 stage2[CH];          // 32 KB
    __shared__ unsigned char bkt2[CH];   // 4 KB
    __shared__ int hist[256], sc[256], lofs[256], cnt2[256], gbase[256];
    int tid = threadIdx.x;
    int base = blockIdx.x * CH;
    int n = min(CH, E - base);
    hist[tid] = 0;
    cnt2[tid] = 0;
    __syncthreads();
    int2 ev[CH / 256];
    int bk[CH / 256];
#pragma unroll
    for (int j = 0; j < CH / 256; ++j) {
        int i = base + tid + j * 256;
        bk[j] = -1;
        if (i < base + n) {
            int s = src[i], d = dst[i];
            float w = ew[i];
            int b = d >> BK_SHIFT;
            ev[j] = make_int2(s | ((d & (BK_NODES - 1)) << NODE_BITS), __float_as_int(w));
            bk[j] = b;
            atomicAdd(&hist[b], 1);
        }
    }
    __syncthreads();
    int hv = hist[tid];
    sc[tid] = hv;
    __syncthreads();
    for (int d = 1; d < 256; d <<= 1) {
        int t = (tid >= d) ? sc[tid - d] : 0;
        __syncthreads();
        sc[tid] += t;
        __syncthreads();
    }
    lofs[tid] = sc[tid] - hv;
    gbase[tid] = hv ? atomicAdd(&bfill[tid], hv) : 0;
    __syncthreads();
#pragma unroll
    for (int j = 0; j < CH / 256; ++j) {
        if (bk[j] >= 0) {
            int r = atomicAdd(&cnt2[bk[j]], 1);
            int p = lofs[bk[j]] + r;
            stage2[p] = ev[j];
            bkt2[p] = (unsigned char)bk[j];
        }
    }
    __syncthreads();
    for (int i = tid; i < n; i += 256) {
        int b = bkt2[i];
        binned[gbase[b] + (i - lofs[b])] = stage2[i];
    }
}

// ---- Pass B: per-bucket local CSR + rowptr + dinv --------------------------
__global__ __launch_bounds__(256) void k_csr(const int2* __restrict__ binned,
                                             const int* __restrict__ bbase,
                                             int2* __restrict__ cvb,
                                             int* __restrict__ rowptr,
                                             float* __restrict__ dinv, int N, int E) {
    __shared__ int lh[BK_NODES];
    __shared__ float ls[BK_NODES];
    __shared__ int lofs[BK_NODES];
    __shared__ int s2[256];
    int tid = threadIdx.x;
    int b = blockIdx.x;
    int nbase = b << BK_SHIFT;
    int nend = min(nbase + BK_NODES, N);
    int ebase = bbase[b], eend = bbase[b + 1];
    for (int i = tid; i < BK_NODES; i += 256) { lh[i] = 0; ls[i] = 0.f; }
    __syncthreads();
    for (int e = ebase + tid; e < eend; e += 256) {
        int2 v = binned[e];
        int local = (v.x >> NODE_BITS) & (BK_NODES - 1);
        atomicAdd(&lh[local], 1);
        atomicAdd(&ls[local], __int_as_float(v.y));
    }
    __syncthreads();
    // exclusive scan of lh[512] via pairwise + 256-scan
    int p0 = lh[2 * tid], p1 = lh[2 * tid + 1];
    int pv = p0 + p1;
    s2[tid] = pv;
    __syncthreads();
    for (int d = 1; d < 256; d <<= 1) {
        int t = (tid >= d) ? s2[tid - d] : 0;
        __syncthreads();
        s2[tid] += t;
        __syncthreads();
    }
    int e2 = s2[tid] - pv;  // exclusive over pairs
    lofs[2 * tid] = e2;
    lofs[2 * tid + 1] = e2 + p0;
    __syncthreads();
    for (int i = nbase + tid; i < nend; i += 256) {
        int local = i - nbase;
        rowptr[i] = ebase + lofs[local];
        dinv[i] = rsqrtf(1.0f + ls[local]);
    }
    if (b == 0 && tid == 0) rowptr[N] = E;
    __syncthreads();
    for (int e = ebase + tid; e < eend; e += 256) {
        int2 v = binned[e];
        int local = (v.x >> NODE_BITS) & (BK_NODES - 1);
        int r = atomicAdd(&lofs[local], 1);
        cvb[ebase + r] = make_int2(v.x & NODE_MASK, v.y);
    }
}

// x (f32) -> Xb (bf16), 8 elems/thread
__global__ __launch_bounds__(256) void k_xcast(const float* __restrict__ x,
                                               unsigned int* __restrict__ Xb, int n8) {
    int i = blockIdx.x * blockDim.x + threadIdx.x;
    if (i >= n8) return;
    const float4* xp = reinterpret_cast<const float4*>(x) + (size_t)i * 2;
    float4 v0 = xp[0], v1 = xp[1];
    uint4 o;
    o.x = packbf2(v0.x, v0.y);
    o.y = packbf2(v0.z, v0.w);
    o.z = packbf2(v1.x, v1.y);
    o.w = packbf2(v1.z, v1.w);
    reinterpret_cast<uint4*>(Xb)[i] = o;
}

// W[k][n] f32 -> WT[n][k] bf16
__global__ __launch_bounds__(256) void k_wt(const float* __restrict__ W,
                                            unsigned short* __restrict__ WT) {
    int idx = blockIdx.x * 256 + threadIdx.x;
    int n = idx >> 7, k = idx & 127;
    WT[idx] = (unsigned short)f2bf(W[(size_t)k * 128 + n]);
}

// Y[M,128](bf16) = dinv[row] * (Xb[M,128] @ W) via MFMA 16x16x32.
__global__ __launch_bounds__(256) void k_gemm(const unsigned short* __restrict__ Xb,
                                              const unsigned short* __restrict__ WT,
                                              const float* __restrict__ dinv,
                                              unsigned short* __restrict__ Y, int M) {
    int tid = threadIdx.x;
    int wid = tid >> 6, lane = tid & 63;
    int rowb = blockIdx.x * 64 + wid * 16;
    int r16 = lane & 15, kg = lane >> 4;
    const bf16x8* Ap = reinterpret_cast<const bf16x8*>(Xb + (size_t)(rowb + r16) * 128 + kg * 8);
    bf16x8 a0 = Ap[0], a1 = Ap[4], a2 = Ap[8], a3 = Ap[12];
    float dv[4];
#pragma unroll
    for (int r = 0; r < 4; ++r) {
        int ro = rowb + kg * 4 + r;
        dv[r] = (ro < M) ? dinv[ro] : 0.f;
    }
    const bf16x8* Bp = reinterpret_cast<const bf16x8*>(WT + (size_t)r16 * 128 + kg * 8);
#pragma unroll
    for (int nt = 0; nt < 8; ++nt) {
        const bf16x8* B = Bp + (size_t)nt * 256;
        f32x4 acc = {0.f, 0.f, 0.f, 0.f};
        acc = __builtin_amdgcn_mfma_f32_16x16x32_bf16(a0, B[0], acc, 0, 0, 0);
        acc = __builtin_amdgcn_mfma_f32_16x16x32_bf16(a1, B[4], acc, 0, 0, 0);
        acc = __builtin_amdgcn_mfma_f32_16x16x32_bf16(a2, B[8], acc, 0, 0, 0);
        acc = __builtin_amdgcn_mfma_f32_16x16x32_bf16(a3, B[12], acc, 0, 0, 0);
        int colo = nt * 16 + r16;
#pragma unroll
        for (int r = 0; r < 4; ++r) {
            int ro = rowb + kg * 4 + r;
            if (ro < M) Y[(size_t)ro * 128 + colo] = (unsigned short)f2bf(acc[r] * dv[r]);
        }
    }
}

// Out[d] = relu( dinv[d]*( sum_e ew_e*H'[s_e] + H'[d] ) + bias ), bf16 in/out
// H' rows pre-scaled by dinv. FOUR nodes (gather streams) per wave.
// Out-of-range j broadcasts (cl=0, vl=0) cost only a cached row-0 load.
__global__ __launch_bounds__(256) void k_agg(const unsigned int* __restrict__ Hb,
                                             const int* __restrict__ rowptr,
                                             const int2* __restrict__ cvb,
                                             const float* __restrict__ dinv,
                                             const float* __restrict__ bias,
                                             unsigned int* __restrict__ OutB, int N) {
    int lane = threadIdx.x & 63;
    int grp = blockIdx.x * 4 + (threadIdx.x >> 6);
    int n0 = grp * 4;
    if (n0 >= N) return;
    int r0 = rowptr[n0];
    int r1 = rowptr[min(n0 + 1, N)];
    int r2 = rowptr[min(n0 + 2, N)];
    int r3 = rowptr[min(n0 + 3, N)];
    int r4 = rowptr[min(n0 + 4, N)];
    int c0 = r1 - r0, c1 = r2 - r1, c2 = r3 - r2, c3 = r4 - r3;
    bool v1n = n0 + 1 < N, v2n = n0 + 2 < N, v3n = n0 + 3 < N;
    // self terms (H' already dinv-scaled)
    unsigned int hv0 = Hb[(size_t)n0 * 64 + lane];
    unsigned int hv1 = v1n ? Hb[(size_t)(n0 + 1) * 64 + lane] : 0u;
    unsigned int hv2 = v2n ? Hb[(size_t)(n0 + 2) * 64 + lane] : 0u;
    unsigned int hv3 = v3n ? Hb[(size_t)(n0 + 3) * 64 + lane] : 0u;
    float a00 = bf_lo(hv0), a01 = bf_hi(hv0);
    float a10 = bf_lo(hv1), a11 = bf_hi(hv1);
    float a20 = bf_lo(hv2), a21 = bf_hi(hv2);
    float a30 = bf_lo(hv3), a31 = bf_hi(hv3);
    int nmax = max(max(c0, c1), max(c2, c3));
    for (int base = 0; base < nmax; base += 64) {
        int2 cv0 = make_int2(0, 0), cv1 = make_int2(0, 0);
        int2 cv2 = make_int2(0, 0), cv3 = make_int2(0, 0);
        int bl = base + lane;
        if (bl < c0) cv0 = cvb[r0 + bl];
        if (bl < c1) cv1 = cvb[r1 + bl];
        if (bl < c2) cv2 = cvb[r2 + bl];
        if (bl < c3) cv3 = cvb[r3 + bl];
        int m = min(64, nmax - base);
        for (int j0 = 0; j0 < m; j0 += 4) {
#pragma unroll
            for (int jj = 0; jj < 4; ++jj) {
                int j = j0 + jj;
                if (j < m) {
                    int s0 = __shfl(cv0.x, j);
                    float w0 = __uint_as_float((unsigned)__shfl(cv0.y, j));
                    int s1 = __shfl(cv1.x, j);
                    float w1 = __uint_as_float((unsigned)__shfl(cv1.y, j));
                    int s2 = __shfl(cv2.x, j);
                    float w2 = __uint_as_float((unsigned)__shfl(cv2.y, j));
                    int s3 = __shfl(cv3.x, j);
                    float w3 = __uint_as_float((unsigned)__shfl(cv3.y, j));
                    unsigned int h0 = Hb[(size_t)s0 * 64 + lane];
                    unsigned int h1 = Hb[(size_t)s1 * 64 + lane];
                    unsigned int h2 = Hb[(size_t)s2 * 64 + lane];
                    unsigned int h3 = Hb[(size_t)s3 * 64 + lane];
                    a00 = fmaf(w0, bf_lo(h0), a00);
                    a01 = fmaf(w0, bf_hi(h0), a01);
                    a10 = fmaf(w1, bf_lo(h1), a10);
                    a11 = fmaf(w1, bf_hi(h1), a11);
                    a20 = fmaf(w2, bf_lo(h2), a20);
                    a21 = fmaf(w2, bf_hi(h2), a21);
                    a30 = fmaf(w3, bf_lo(h3), a30);
                    a31 = fmaf(w3, bf_hi(h3), a31);
                }
            }
        }
    }
    float2 bv = reinterpret_cast<const float2*>(bias)[lane];
    float d0 = dinv[n0];
    a00 = fmaxf(fmaf(a00, d0, bv.x), 0.f);
    a01 = fmaxf(fmaf(a01, d0, bv.y), 0.f);
    OutB[(size_t)n0 * 64 + lane] = packbf2(a00, a01);
    if (v1n) {
        float d1 = dinv[n0 + 1];
        a10 = fmaxf(fmaf(a10, d1, bv.x), 0.f);
        a11 = fmaxf(fmaf(a11, d1, bv.y), 0.f);
        OutB[(size_t)(n0 + 1) * 64 + lane] = packbf2(a10, a11);
    }
    if (v2n) {
        float d2 = dinv[n0 + 2];
        a20 = fmaxf(fmaf(a20, d2, bv.x), 0.f);
        a21 = fmaxf(fmaf(a21, d2, bv.y), 0.f);
        OutB[(size_t)(n0 + 2) * 64 + lane] = packbf2(a20, a21);
    }
    if (v3n) {
        float d3 = dinv[n0 + 3];
        a30 = fmaxf(fmaf(a30, d3, bv.x), 0.f);
        a31 = fmaxf(fmaf(a31, d3, bv.y), 0.f);
        OutB[(size_t)(n0 + 3) * 64 + lane] = packbf2(a30, a31);
    }
}

// mean pool over bf16 rows
__global__ __launch_bounds__(256) void k_pool(const unsigned int* __restrict__ H2u,
                                              const int* __restrict__ gstart,
                                              const int* __restrict__ gcnt,
                                              float* __restrict__ gmean) {
    int g = blockIdx.x;
    int tid = threadIdx.x;
    int cu = tid & 63, q = tid >> 6;
    __shared__ float r0[256], r1[256];
    int cntg = gcnt[g];
    int b = gstart[g];
    float s0 = 0.f, s1 = 0.f;
    for (int i = q; i < cntg; i += 4) {
        unsigned int v = H2u[(size_t)(b + i) * 64 + cu];
        s0 += bf_lo(v);
        s1 += bf_hi(v);
    }
    r0[tid] = s0; r1[tid] = s1;
    __syncthreads();
    if (tid < 64) {
        float t0 = r0[cu] + r0[cu + 64] + r0[cu + 128] + r0[cu + 192];
        float t1 = r1[cu] + r1[cu + 64] + r1[cu + 128] + r1[cu + 192];
        float inv = 1.f / fmaxf((float)cntg, 1.f);
        gmean[g * 128 + 2 * cu] = t0 * inv;
        gmean[g * 128 + 2 * cu + 1] = t1 * inv;
    }
}

// head: md = relu(metadata[first%G] @ Wm + bm); out = [pooled, md] @ Wf + bf
__global__ __launch_bounds__(128) void k_final(const float* __restrict__ gmean,
                                               const int* __restrict__ gstart,
                                               const float* __restrict__ meta,
                                               const float* __restrict__ Wm,
                                               const float* __restrict__ bm,
                                               const float* __restrict__ Wf,
                                               const float* __restrict__ bf,
                                               float* __restrict__ out, int G) {
    int g = blockIdx.x;
    int c = threadIdx.x;
    __shared__ float red[128];
    float pooled = gmean[g * 128 + c];
    int fn = gstart[g];
    int idx = fn % G;
    float m = bm[c];
#pragma unroll
    for (int k = 0; k < 30; ++k) m = fmaf(meta[idx * 30 + k], Wm[k * 128 + c], m);
    m = fmaxf(m, 0.f);
    float part = pooled * Wf[c] + m * Wf[128 + c];
    red[c] = part;
    __syncthreads();
    for (int st = 64; st > 0; st >>= 1) {
        if (c < st) red[c] += red[c + st];
        __syncthreads();
    }
    if (c == 0) out[g] = red[0] + bf[0];
}

extern "C" void kernel_launch(void* const* d_in, const int* in_sizes, int n_in,
                              void* d_out, int out_size, void* d_ws, size_t ws_size,
                              hipStream_t stream) {
    const float* x     = (const float*)d_in[0];
    const int*   ei    = (const int*)d_in[1];
    const float* ew    = (const float*)d_in[2];
    const int*   batch = (const int*)d_in[3];
    const float* meta  = (const float*)d_in[4];
    const float* W1    = (const float*)d_in[5];
    const float* b1    = (const float*)d_in[6];
    const float* W2    = (const float*)d_in[7];
    const float* b2    = (const float*)d_in[8];
    const float* Wm    = (const float*)d_in[9];
    const float* bm    = (const float*)d_in[10];
    const float* Wf    = (const float*)d_in[11];
    const float* bf    = (const float*)d_in[12];

    int N = in_sizes[0] / 128;
    int E = in_sizes[2];
    int G = in_sizes[4] / 30;
    int Mpad = (N + 63) & ~63;
    int NBK = (N + BK_NODES - 1) >> BK_SHIFT;  // 196 for N=100000 (<=256)
    const int* srcp = ei;
    const int* dstp = ei + E;

    char* p = (char*)d_ws;
    auto alloc = [&](size_t bytes) -> void* {
        void* r = p;
        p += (bytes + 255) & ~(size_t)255;
        return r;
    };
    float* dinv   = (float*)alloc((size_t)N * 4);
    int*   rowptr = (int*)alloc((size_t)(N + 1) * 4);
    int2*  binned = (int2*)alloc((size_t)E * 8);
    int2*  cvb    = (int2*)alloc((size_t)E * 8);
    int*   bcnt   = (int*)alloc((size_t)NBK * 4);
    int*   bbase  = (int*)alloc((size_t)(NBK + 1) * 4);
    int*   bfillp = (int*)alloc((size_t)NBK * 4);
    unsigned short* Xb  = (unsigned short*)alloc((size_t)Mpad * 128 * 2);
    unsigned short* H   = (unsigned short*)alloc((size_t)Mpad * 128 * 2);
    unsigned short* H2  = (unsigned short*)alloc((size_t)Mpad * 128 * 2);
    unsigned short* WT1 = (unsigned short*)alloc(128 * 128 * 2);
    unsigned short* WT2 = (unsigned short*)alloc(128 * 128 * 2);
    float* gmean  = (float*)alloc((size_t)G * 128 * 4);
    int*   gstart = (int*)alloc((size_t)G * 4);
    int*   gcnt   = (int*)alloc((size_t)G * 4);

    int EB = (E + CH - 1) / CH;
    k_init_small<<<(max(G, NBK) + 255) / 256, 256, 0, stream>>>(gstart, gcnt, G, bcnt, NBK);
    k_init_nodes<<<(N + 255) / 256, 256, 0, stream>>>(batch, gstart, gcnt, N);
    k_binhist<<<EB, 256, 0, stream>>>(dstp, E, bcnt, NBK);
    k_binscan<<<1, 256, 0, stream>>>(bcnt, bbase, bfillp, NBK);
    k_binscatter<<<EB, 256, 0, stream>>>(srcp, dstp, ew, bfillp, binned, E);
    k_csr<<<NBK, 256, 0, stream>>>(binned, bbase, cvb, rowptr, dinv, N, E);

    int n8 = N * 128 / 8;
    k_xcast<<<(n8 + 255) / 256, 256, 0, stream>>>(x, (unsigned int*)Xb, n8);
    k_wt<<<64, 256, 0, stream>>>(W1, WT1);
    k_wt<<<64, 256, 0, stream>>>(W2, WT2);

    k_gemm<<<Mpad / 64, 256, 0, stream>>>(Xb, WT1, dinv, H, N);
    k_agg<<<(N + 15) / 16, 256, 0, stream>>>((const unsigned int*)H, rowptr, cvb, dinv, b1,
                                             (unsigned int*)H2, N);
    k_gemm<<<Mpad / 64, 256, 0, stream>>>(H2, WT2, dinv, H, N);
    k_agg<<<(N + 15) / 16, 256, 0, stream>>>((const unsigned int*)H, rowptr, cvb, dinv, b2,
                                             (unsigned int*)H2, N);

    k_pool<<<G, 256, 0, stream>>>((const unsigned int*)H2, gstart, gcnt, gmean);
    k_final<<<G, 128, 0, stream>>>(gmean, gstart, meta, Wm, bm, Wf, bf, (float*)d_out, G);
}

// Round 9
// 307.728 us; speedup vs baseline: 2.4754x; 1.2212x over previous
//
#include <hip/hip_runtime.h>
#include <cstdint>

// ---------------------------------------------------------------------------
// GCN pipeline (bf16 MFMA GEMMs, binned CSR build):
//  binhist -> binscan -> binscatter (bucket-major, LDS counting sort) ->
//  k_csr (per-bucket local CSR + rowptr + dinv) -> xcast -> GEMM1(xW*dinv)
//  -> AGG1 (4 gather streams/wave) -> GEMM2(*dinv) -> AGG2 -> pool -> head
//  Graph ranges via sorted-batch boundary detection (NO atomics).
// ---------------------------------------------------------------------------

#define BK_SHIFT 9
#define BK_NODES 512            // 1 << BK_SHIFT
#define CH 4096                 // edges per binscatter chunk
#define NODE_BITS 17            // N=100000 < 2^17
#define NODE_MASK ((1 << NODE_BITS) - 1)

typedef short bf16x8 __attribute__((ext_vector_type(8)));
typedef float f32x4 __attribute__((ext_vector_type(4)));

// f32 -> bf16 round-to-nearest-even
static __device__ __forceinline__ unsigned int f2bf(float f) {
    unsigned int u = __float_as_uint(f);
    return (u + 0x7fffu + ((u >> 16) & 1u)) >> 16;
}
static __device__ __forceinline__ unsigned int packbf2(float a, float b) {
    return f2bf(a) | (f2bf(b) << 16);
}
static __device__ __forceinline__ float bf_lo(unsigned int v) {
    return __uint_as_float(v << 16);
}
static __device__ __forceinline__ float bf_hi(unsigned int v) {
    return __uint_as_float(v & 0xffff0000u);
}

// gstart/gend init + zero bucket counters
__global__ void k_init_small(int* gstart, int* gend, int G, int* bcnt, int NBK) {
    int g = blockIdx.x * blockDim.x + threadIdx.x;
    if (g < G) { gstart[g] = 0x7fffffff; gend[g] = 0; }
    if (g < NBK) bcnt[g] = 0;
}

// sorted batch -> contiguous runs; boundary threads are unique writers
__global__ void k_init_nodes(const int* __restrict__ batch,
                             int* __restrict__ gstart, int* __restrict__ gend, int N) {
    int i = blockIdx.x * blockDim.x + threadIdx.x;
    if (i >= N) return;
    int b = batch[i];
    if (i == 0 || batch[i - 1] != b) gstart[b] = i;
    if (i == N - 1 || batch[i + 1] != b) gend[b] = i + 1;
}

// ---- Pass A1: per-bucket edge counts ---------------------------------------
__global__ __launch_bounds__(256) void k_binhist(const int* __restrict__ dst, int E,
                                                 int* __restrict__ bcnt, int NBK) {
    __shared__ int h[256];
    int tid = threadIdx.x;
    h[tid] = 0;
    __syncthreads();
    int base = blockIdx.x * CH;
    int nend = min(base + CH, E);
    for (int i = base + tid; i < nend; i += 256) atomicAdd(&h[dst[i] >> BK_SHIFT], 1);
    __syncthreads();
    if (tid < NBK && h[tid]) atomicAdd(&bcnt[tid], h[tid]);
}

// ---- Pass A2: scan bucket counts -> bbase[NBK+1], bfill cursors ------------
__global__ __launch_bounds__(256) void k_binscan(const int* __restrict__ bcnt,
                                                 int* __restrict__ bbase,
                                                 int* __restrict__ bfill, int NBK) {
    __shared__ int sc[256];
    int tid = threadIdx.x;
    int v = (tid < NBK) ? bcnt[tid] : 0;
    sc[tid] = v;
    __syncthreads();
    for (int d = 1; d < 256; d <<= 1) {
        int t = (tid >= d) ? sc[tid - d] : 0;
        __syncthreads();
        sc[tid] += t;
        __syncthreads();
    }
    int excl = sc[tid] - v;
    if (tid < NBK) { bbase[tid] = excl; bfill[tid] = excl; }
    if (tid == 255) bbase[NBK] = sc[255];  // total = E
}

// ---- Pass A3: counting-sort each 4096-edge chunk into bucket-major order ---
__global__ __launch_bounds__(256) void k_binscatter(const int* __restrict__ src,
                                                    const int* __restrict__ dst,
                                                    const float* __restrict__ ew,
                                                    int* __restrict__ bfill,
                                                    int2* __restrict__ binned, int E) {
    __shared__ int2 stage2[CH];          // 32 KB
    __shared__ unsigned char bkt2[CH];   // 4 KB
    __shared__ int hist[256], sc[256], lofs[256], cnt2[256], gbase[256];
    int tid = threadIdx.x;
    int base = blockIdx.x * CH;
    int n = min(CH, E - base);
    hist[tid] = 0;
    cnt2[tid] = 0;
    __syncthreads();
    int2 ev[CH / 256];
    int bk[CH / 256];
#pragma unroll
    for (int j = 0; j < CH / 256; ++j) {
        int i = base + tid + j * 256;
        bk[j] = -1;
        if (i < base + n) {
            int s = src[i], d = dst[i];
            float w = ew[i];
            int b = d >> BK_SHIFT;
            ev[j] = make_int2(s | ((d & (BK_NODES - 1)) << NODE_BITS), __float_as_int(w));
            bk[j] = b;
            atomicAdd(&hist[b], 1);
        }
    }
    __syncthreads();
    int hv = hist[tid];
    sc[tid] = hv;
    __syncthreads();
    for (int d = 1; d < 256; d <<= 1) {
        int t = (tid >= d) ? sc[tid - d] : 0;
        __syncthreads();
        sc[tid] += t;
        __syncthreads();
    }
    lofs[tid] = sc[tid] - hv;
    gbase[tid] = hv ? atomicAdd(&bfill[tid], hv) : 0;
    __syncthreads();
#pragma unroll
    for (int j = 0; j < CH / 256; ++j) {
        if (bk[j] >= 0) {
            int r = atomicAdd(&cnt2[bk[j]], 1);
            int p = lofs[bk[j]] + r;
            stage2[p] = ev[j];
            bkt2[p] = (unsigned char)bk[j];
        }
    }
    __syncthreads();
    for (int i = tid; i < n; i += 256) {
        int b = bkt2[i];
        binned[gbase[b] + (i - lofs[b])] = stage2[i];
    }
}

// ---- Pass B: per-bucket local CSR + rowptr + dinv --------------------------
__global__ __launch_bounds__(256) void k_csr(const int2* __restrict__ binned,
                                             const int* __restrict__ bbase,
                                             int2* __restrict__ cvb,
                                             int* __restrict__ rowptr,
                                             float* __restrict__ dinv, int N, int E) {
    __shared__ int lh[BK_NODES];
    __shared__ float ls[BK_NODES];
    __shared__ int lofs[BK_NODES];
    __shared__ int s2[256];
    int tid = threadIdx.x;
    int b = blockIdx.x;
    int nbase = b << BK_SHIFT;
    int nend = min(nbase + BK_NODES, N);
    int ebase = bbase[b], eend = bbase[b + 1];
    for (int i = tid; i < BK_NODES; i += 256) { lh[i] = 0; ls[i] = 0.f; }
    __syncthreads();
    for (int e = ebase + tid; e < eend; e += 256) {
        int2 v = binned[e];
        int local = (v.x >> NODE_BITS) & (BK_NODES - 1);
        atomicAdd(&lh[local], 1);
        atomicAdd(&ls[local], __int_as_float(v.y));
    }
    __syncthreads();
    // exclusive scan of lh[512] via pairwise + 256-scan
    int p0 = lh[2 * tid], p1 = lh[2 * tid + 1];
    int pv = p0 + p1;
    s2[tid] = pv;
    __syncthreads();
    for (int d = 1; d < 256; d <<= 1) {
        int t = (tid >= d) ? s2[tid - d] : 0;
        __syncthreads();
        s2[tid] += t;
        __syncthreads();
    }
    int e2 = s2[tid] - pv;  // exclusive over pairs
    lofs[2 * tid] = e2;
    lofs[2 * tid + 1] = e2 + p0;
    __syncthreads();
    for (int i = nbase + tid; i < nend; i += 256) {
        int local = i - nbase;
        rowptr[i] = ebase + lofs[local];
        dinv[i] = rsqrtf(1.0f + ls[local]);
    }
    if (b == 0 && tid == 0) rowptr[N] = E;
    __syncthreads();
    for (int e = ebase + tid; e < eend; e += 256) {
        int2 v = binned[e];
        int local = (v.x >> NODE_BITS) & (BK_NODES - 1);
        int r = atomicAdd(&lofs[local], 1);
        cvb[ebase + r] = make_int2(v.x & NODE_MASK, v.y);
    }
}

// x (f32) -> Xb (bf16), 8 elems/thread
__global__ __launch_bounds__(256) void k_xcast(const float* __restrict__ x,
                                               unsigned int* __restrict__ Xb, int n8) {
    int i = blockIdx.x * blockDim.x + threadIdx.x;
    if (i >= n8) return;
    const float4* xp = reinterpret_cast<const float4*>(x) + (size_t)i * 2;
    float4 v0 = xp[0], v1 = xp[1];
    uint4 o;
    o.x = packbf2(v0.x, v0.y);
    o.y = packbf2(v0.z, v0.w);
    o.z = packbf2(v1.x, v1.y);
    o.w = packbf2(v1.z, v1.w);
    reinterpret_cast<uint4*>(Xb)[i] = o;
}

// W[k][n] f32 -> WT[n][k] bf16
__global__ __launch_bounds__(256) void k_wt(const float* __restrict__ W,
                                            unsigned short* __restrict__ WT) {
    int idx = blockIdx.x * 256 + threadIdx.x;
    int n = idx >> 7, k = idx & 127;
    WT[idx] = (unsigned short)f2bf(W[(size_t)k * 128 + n]);
}

// Y[M,128](bf16) = dinv[row] * (Xb[M,128] @ W) via MFMA 16x16x32.
__global__ __launch_bounds__(256) void k_gemm(const unsigned short* __restrict__ Xb,
                                              const unsigned short* __restrict__ WT,
                                              const float* __restrict__ dinv,
                                              unsigned short* __restrict__ Y, int M) {
    int tid = threadIdx.x;
    int wid = tid >> 6, lane = tid & 63;
    int rowb = blockIdx.x * 64 + wid * 16;
    int r16 = lane & 15, kg = lane >> 4;
    const bf16x8* Ap = reinterpret_cast<const bf16x8*>(Xb + (size_t)(rowb + r16) * 128 + kg * 8);
    bf16x8 a0 = Ap[0], a1 = Ap[4], a2 = Ap[8], a3 = Ap[12];
    float dv[4];
#pragma unroll
    for (int r = 0; r < 4; ++r) {
        int ro = rowb + kg * 4 + r;
        dv[r] = (ro < M) ? dinv[ro] : 0.f;
    }
    const bf16x8* Bp = reinterpret_cast<const bf16x8*>(WT + (size_t)r16 * 128 + kg * 8);
#pragma unroll
    for (int nt = 0; nt < 8; ++nt) {
        const bf16x8* B = Bp + (size_t)nt * 256;
        f32x4 acc = {0.f, 0.f, 0.f, 0.f};
        acc = __builtin_amdgcn_mfma_f32_16x16x32_bf16(a0, B[0], acc, 0, 0, 0);
        acc = __builtin_amdgcn_mfma_f32_16x16x32_bf16(a1, B[4], acc, 0, 0, 0);
        acc = __builtin_amdgcn_mfma_f32_16x16x32_bf16(a2, B[8], acc, 0, 0, 0);
        acc = __builtin_amdgcn_mfma_f32_16x16x32_bf16(a3, B[12], acc, 0, 0, 0);
        int colo = nt * 16 + r16;
#pragma unroll
        for (int r = 0; r < 4; ++r) {
            int ro = rowb + kg * 4 + r;
            if (ro < M) Y[(size_t)ro * 128 + colo] = (unsigned short)f2bf(acc[r] * dv[r]);
        }
    }
}

// Out[d] = relu( dinv[d]*( sum_e ew_e*H'[s_e] + H'[d] ) + bias ), bf16 in/out
// H' rows pre-scaled by dinv. FOUR nodes (gather streams) per wave.
__global__ __launch_bounds__(256) void k_agg(const unsigned int* __restrict__ Hb,
                                             const int* __restrict__ rowptr,
                                             const int2* __restrict__ cvb,
                                             const float* __restrict__ dinv,
                                             const float* __restrict__ bias,
                                             unsigned int* __restrict__ OutB, int N) {
    int lane = threadIdx.x & 63;
    int grp = blockIdx.x * 4 + (threadIdx.x >> 6);
    int n0 = grp * 4;
    if (n0 >= N) return;
    int r0 = rowptr[n0];
    int r1 = rowptr[min(n0 + 1, N)];
    int r2 = rowptr[min(n0 + 2, N)];
    int r3 = rowptr[min(n0 + 3, N)];
    int r4 = rowptr[min(n0 + 4, N)];
    int c0 = r1 - r0, c1 = r2 - r1, c2 = r3 - r2, c3 = r4 - r3;
    bool v1n = n0 + 1 < N, v2n = n0 + 2 < N, v3n = n0 + 3 < N;
    unsigned int hv0 = Hb[(size_t)n0 * 64 + lane];
    unsigned int hv1 = v1n ? Hb[(size_t)(n0 + 1) * 64 + lane] : 0u;
    unsigned int hv2 = v2n ? Hb[(size_t)(n0 + 2) * 64 + lane] : 0u;
    unsigned int hv3 = v3n ? Hb[(size_t)(n0 + 3) * 64 + lane] : 0u;
    float a00 = bf_lo(hv0), a01 = bf_hi(hv0);
    float a10 = bf_lo(hv1), a11 = bf_hi(hv1);
    float a20 = bf_lo(hv2), a21 = bf_hi(hv2);
    float a30 = bf_lo(hv3), a31 = bf_hi(hv3);
    int nmax = max(max(c0, c1), max(c2, c3));
    for (int base = 0; base < nmax; base += 64) {
        int2 cv0 = make_int2(0, 0), cv1 = make_int2(0, 0);
        int2 cv2 = make_int2(0, 0), cv3 = make_int2(0, 0);
        int bl = base + lane;
        if (bl < c0) cv0 = cvb[r0 + bl];
        if (bl < c1) cv1 = cvb[r1 + bl];
        if (bl < c2) cv2 = cvb[r2 + bl];
        if (bl < c3) cv3 = cvb[r3 + bl];
        int m = min(64, nmax - base);
        for (int j0 = 0; j0 < m; j0 += 4) {
#pragma unroll
            for (int jj = 0; jj < 4; ++jj) {
                int j = j0 + jj;
                if (j < m) {
                    int s0 = __shfl(cv0.x, j);
                    float w0 = __uint_as_float((unsigned)__shfl(cv0.y, j));
                    int s1 = __shfl(cv1.x, j);
                    float w1 = __uint_as_float((unsigned)__shfl(cv1.y, j));
                    int s2 = __shfl(cv2.x, j);
                    float w2 = __uint_as_float((unsigned)__shfl(cv2.y, j));
                    int s3 = __shfl(cv3.x, j);
                    float w3 = __uint_as_float((unsigned)__shfl(cv3.y, j));
                    unsigned int h0 = Hb[(size_t)s0 * 64 + lane];
                    unsigned int h1 = Hb[(size_t)s1 * 64 + lane];
                    unsigned int h2 = Hb[(size_t)s2 * 64 + lane];
                    unsigned int h3 = Hb[(size_t)s3 * 64 + lane];
                    a00 = fmaf(w0, bf_lo(h0), a00);
                    a01 = fmaf(w0, bf_hi(h0), a01);
                    a10 = fmaf(w1, bf_lo(h1), a10);
                    a11 = fmaf(w1, bf_hi(h1), a11);
                    a20 = fmaf(w2, bf_lo(h2), a20);
                    a21 = fmaf(w2, bf_hi(h2), a21);
                    a30 = fmaf(w3, bf_lo(h3), a30);
                    a31 = fmaf(w3, bf_hi(h3), a31);
                }
            }
        }
    }
    float2 bv = reinterpret_cast<const float2*>(bias)[lane];
    float d0 = dinv[n0];
    a00 = fmaxf(fmaf(a00, d0, bv.x), 0.f);
    a01 = fmaxf(fmaf(a01, d0, bv.y), 0.f);
    OutB[(size_t)n0 * 64 + lane] = packbf2(a00, a01);
    if (v1n) {
        float d1 = dinv[n0 + 1];
        a10 = fmaxf(fmaf(a10, d1, bv.x), 0.f);
        a11 = fmaxf(fmaf(a11, d1, bv.y), 0.f);
        OutB[(size_t)(n0 + 1) * 64 + lane] = packbf2(a10, a11);
    }
    if (v2n) {
        float d2 = dinv[n0 + 2];
        a20 = fmaxf(fmaf(a20, d2, bv.x), 0.f);
        a21 = fmaxf(fmaf(a21, d2, bv.y), 0.f);
        OutB[(size_t)(n0 + 2) * 64 + lane] = packbf2(a20, a21);
    }
    if (v3n) {
        float d3 = dinv[n0 + 3];
        a30 = fmaxf(fmaf(a30, d3, bv.x), 0.f);
        a31 = fmaxf(fmaf(a31, d3, bv.y), 0.f);
        OutB[(size_t)(n0 + 3) * 64 + lane] = packbf2(a30, a31);
    }
}

// mean pool over bf16 rows; graph g = rows [gstart[g], gend[g])
__global__ __launch_bounds__(256) void k_pool(const unsigned int* __restrict__ H2u,
                                              const int* __restrict__ gstart,
                                              const int* __restrict__ gend,
                                              float* __restrict__ gmean) {
    int g = blockIdx.x;
    int tid = threadIdx.x;
    int cu = tid & 63, q = tid >> 6;
    __shared__ float r0[256], r1[256];
    int b = gstart[g];
    int e = gend[g];
    int cntg = e - b;  // negative/0 for empty graph (gstart=INT_MAX, gend=0)
    float s0 = 0.f, s1 = 0.f;
    for (int i = q; i < cntg; i += 4) {
        unsigned int v = H2u[(size_t)(b + i) * 64 + cu];
        s0 += bf_lo(v);
        s1 += bf_hi(v);
    }
    r0[tid] = s0; r1[tid] = s1;
    __syncthreads();
    if (tid < 64) {
        float t0 = r0[cu] + r0[cu + 64] + r0[cu + 128] + r0[cu + 192];
        float t1 = r1[cu] + r1[cu + 64] + r1[cu + 128] + r1[cu + 192];
        float inv = 1.f / fmaxf((float)cntg, 1.f);
        gmean[g * 128 + 2 * cu] = t0 * inv;
        gmean[g * 128 + 2 * cu + 1] = t1 * inv;
    }
}

// head: md = relu(metadata[first%G] @ Wm + bm); out = [pooled, md] @ Wf + bf
__global__ __launch_bounds__(128) void k_final(const float* __restrict__ gmean,
                                               const int* __restrict__ gstart,
                                               const float* __restrict__ meta,
                                               const float* __restrict__ Wm,
                                               const float* __restrict__ bm,
                                               const float* __restrict__ Wf,
                                               const float* __restrict__ bf,
                                               float* __restrict__ out, int G) {
    int g = blockIdx.x;
    int c = threadIdx.x;
    __shared__ float red[128];
    float pooled = gmean[g * 128 + c];
    int fn = gstart[g];          // INT_MAX for empty graph (segment_min identity)
    int idx = fn % G;
    float m = bm[c];
#pragma unroll
    for (int k = 0; k < 30; ++k) m = fmaf(meta[idx * 30 + k], Wm[k * 128 + c], m);
    m = fmaxf(m, 0.f);
    float part = pooled * Wf[c] + m * Wf[128 + c];
    red[c] = part;
    __syncthreads();
    for (int st = 64; st > 0; st >>= 1) {
        if (c < st) red[c] += red[c + st];
        __syncthreads();
    }
    if (c == 0) out[g] = red[0] + bf[0];
}

extern "C" void kernel_launch(void* const* d_in, const int* in_sizes, int n_in,
                              void* d_out, int out_size, void* d_ws, size_t ws_size,
                              hipStream_t stream) {
    const float* x     = (const float*)d_in[0];
    const int*   ei    = (const int*)d_in[1];
    const float* ew    = (const float*)d_in[2];
    const int*   batch = (const int*)d_in[3];
    const float* meta  = (const float*)d_in[4];
    const float* W1    = (const float*)d_in[5];
    const float* b1    = (const float*)d_in[6];
    const float* W2    = (const float*)d_in[7];
    const float* b2    = (const float*)d_in[8];
    const float* Wm    = (const float*)d_in[9];
    const float* bm    = (const float*)d_in[10];
    const float* Wf    = (const float*)d_in[11];
    const float* bf    = (const float*)d_in[12];

    int N = in_sizes[0] / 128;
    int E = in_sizes[2];
    int G = in_sizes[4] / 30;
    int Mpad = (N + 63) & ~63;
    int NBK = (N + BK_NODES - 1) >> BK_SHIFT;  // 196 for N=100000 (<=256)
    const int* srcp = ei;
    const int* dstp = ei + E;

    char* p = (char*)d_ws;
    auto alloc = [&](size_t bytes) -> void* {
        void* r = p;
        p += (bytes + 255) & ~(size_t)255;
        return r;
    };
    float* dinv   = (float*)alloc((size_t)N * 4);
    int*   rowptr = (int*)alloc((size_t)(N + 1) * 4);
    int2*  binned = (int2*)alloc((size_t)E * 8);
    int2*  cvb    = (int2*)alloc((size_t)E * 8);
    int*   bcnt   = (int*)alloc((size_t)NBK * 4);
    int*   bbase  = (int*)alloc((size_t)(NBK + 1) * 4);
    int*   bfillp = (int*)alloc((size_t)NBK * 4);
    unsigned short* Xb  = (unsigned short*)alloc((size_t)Mpad * 128 * 2);
    unsigned short* H   = (unsigned short*)alloc((size_t)Mpad * 128 * 2);
    unsigned short* H2  = (unsigned short*)alloc((size_t)Mpad * 128 * 2);
    unsigned short* WT1 = (unsigned short*)alloc(128 * 128 * 2);
    unsigned short* WT2 = (unsigned short*)alloc(128 * 128 * 2);
    float* gmean  = (float*)alloc((size_t)G * 128 * 4);
    int*   gstart = (int*)alloc((size_t)G * 4);
    int*   gend   = (int*)alloc((size_t)G * 4);

    int EB = (E + CH - 1) / CH;
    k_init_small<<<(max(G, NBK) + 255) / 256, 256, 0, stream>>>(gstart, gend, G, bcnt, NBK);
    k_init_nodes<<<(N + 255) / 256, 256, 0, stream>>>(batch, gstart, gend, N);
    k_binhist<<<EB, 256, 0, stream>>>(dstp, E, bcnt, NBK);
    k_binscan<<<1, 256, 0, stream>>>(bcnt, bbase, bfillp, NBK);
    k_binscatter<<<EB, 256, 0, stream>>>(srcp, dstp, ew, bfillp, binned, E);
    k_csr<<<NBK, 256, 0, stream>>>(binned, bbase, cvb, rowptr, dinv, N, E);

    int n8 = N * 128 / 8;
    k_xcast<<<(n8 + 255) / 256, 256, 0, stream>>>(x, (unsigned int*)Xb, n8);
    k_wt<<<64, 256, 0, stream>>>(W1, WT1);
    k_wt<<<64, 256, 0, stream>>>(W2, WT2);

    k_gemm<<<Mpad / 64, 256, 0, stream>>>(Xb, WT1, dinv, H, N);
    k_agg<<<(N + 15) / 16, 256, 0, stream>>>((const unsigned int*)H, rowptr, cvb, dinv, b1,
                                             (unsigned int*)H2, N);
    k_gemm<<<Mpad / 64, 256, 0, stream>>>(H2, WT2, dinv, H, N);
    k_agg<<<(N + 15) / 16, 256, 0, stream>>>((const unsigned int*)H, rowptr, cvb, dinv, b2,
                                             (unsigned int*)H2, N);

    k_pool<<<G, 256, 0, stream>>>((const unsigned int*)H2, gstart, gend, gmean);
    k_final<<<G, 128, 0, stream>>>(gmean, gstart, meta, Wm, bm, Wf, bf, (float*)d_out, G);
}

// Round 10
// 299.913 us; speedup vs baseline: 2.5399x; 1.0261x over previous
//
#include <hip/hip_runtime.h>
#include <cstdint>

// ---------------------------------------------------------------------------
// GCN pipeline (bf16 MFMA GEMMs, binned CSR build):
//  binhist -> binscan -> binscatter (bucket-major, LDS counting sort) ->
//  k_csr (per-bucket local CSR + rowptr + dinv) -> GEMM1(f32 in, fused cast,
//  xW*dinv) -> AGG1 (4 streams/wave, LDS broadcast) -> GEMM2(*dinv) -> AGG2
//  -> fused pool+head.  Graph ranges via sorted-batch boundaries (no atomics).
// ---------------------------------------------------------------------------

#define BK_SHIFT 9
#define BK_NODES 512            // 1 << BK_SHIFT
#define CH 4096                 // edges per binscatter chunk
#define NODE_BITS 17            // N=100000 < 2^17
#define NODE_MASK ((1 << NODE_BITS) - 1)

typedef short bf16x8 __attribute__((ext_vector_type(8)));
typedef float f32x4 __attribute__((ext_vector_type(4)));

union bfpack {
    uint4 u;
    bf16x8 b;
};

// f32 -> bf16 round-to-nearest-even
static __device__ __forceinline__ unsigned int f2bf(float f) {
    unsigned int u = __float_as_uint(f);
    return (u + 0x7fffu + ((u >> 16) & 1u)) >> 16;
}
static __device__ __forceinline__ unsigned int packbf2(float a, float b) {
    return f2bf(a) | (f2bf(b) << 16);
}
static __device__ __forceinline__ float bf_lo(unsigned int v) {
    return __uint_as_float(v << 16);
}
static __device__ __forceinline__ float bf_hi(unsigned int v) {
    return __uint_as_float(v & 0xffff0000u);
}

// gstart/gend init + zero bucket counters
__global__ void k_init_small(int* gstart, int* gend, int G, int* bcnt, int NBK) {
    int g = blockIdx.x * blockDim.x + threadIdx.x;
    if (g < G) { gstart[g] = 0x7fffffff; gend[g] = 0; }
    if (g < NBK) bcnt[g] = 0;
}

// sorted batch -> contiguous runs; boundary threads are unique writers
__global__ void k_init_nodes(const int* __restrict__ batch,
                             int* __restrict__ gstart, int* __restrict__ gend, int N) {
    int i = blockIdx.x * blockDim.x + threadIdx.x;
    if (i >= N) return;
    int b = batch[i];
    if (i == 0 || batch[i - 1] != b) gstart[b] = i;
    if (i == N - 1 || batch[i + 1] != b) gend[b] = i + 1;
}

// ---- Pass A1: per-bucket edge counts ---------------------------------------
__global__ __launch_bounds__(256) void k_binhist(const int* __restrict__ dst, int E,
                                                 int* __restrict__ bcnt, int NBK) {
    __shared__ int h[256];
    int tid = threadIdx.x;
    h[tid] = 0;
    __syncthreads();
    int base = blockIdx.x * CH;
    int nend = min(base + CH, E);
    for (int i = base + tid; i < nend; i += 256) atomicAdd(&h[dst[i] >> BK_SHIFT], 1);
    __syncthreads();
    if (tid < NBK && h[tid]) atomicAdd(&bcnt[tid], h[tid]);
}

// ---- Pass A2: scan bucket counts -> bbase[NBK+1], bfill cursors ------------
__global__ __launch_bounds__(256) void k_binscan(const int* __restrict__ bcnt,
                                                 int* __restrict__ bbase,
                                                 int* __restrict__ bfill, int NBK) {
    __shared__ int sc[256];
    int tid = threadIdx.x;
    int v = (tid < NBK) ? bcnt[tid] : 0;
    sc[tid] = v;
    __syncthreads();
    for (int d = 1; d < 256; d <<= 1) {
        int t = (tid >= d) ? sc[tid - d] : 0;
        __syncthreads();
        sc[tid] += t;
        __syncthreads();
    }
    int excl = sc[tid] - v;
    if (tid < NBK) { bbase[tid] = excl; bfill[tid] = excl; }
    if (tid == 255) bbase[NBK] = sc[255];  // total = E
}

// ---- Pass A3: counting-sort each 4096-edge chunk into bucket-major order ---
__global__ __launch_bounds__(256) void k_binscatter(const int* __restrict__ src,
                                                    const int* __restrict__ dst,
                                                    const float* __restrict__ ew,
                                                    int* __restrict__ bfill,
                                                    int2* __restrict__ binned, int E) {
    __shared__ int2 stage2[CH];          // 32 KB
    __shared__ unsigned char bkt2[CH];   // 4 KB
    __shared__ int hist[256], sc[256], lofs[256], cnt2[256], gbase[256];
    int tid = threadIdx.x;
    int base = blockIdx.x * CH;
    int n = min(CH, E - base);
    hist[tid] = 0;
    cnt2[tid] = 0;
    __syncthreads();
    int2 ev[CH / 256];
    int bk[CH / 256];
#pragma unroll
    for (int j = 0; j < CH / 256; ++j) {
        int i = base + tid + j * 256;
        bk[j] = -1;
        if (i < base + n) {
            int s = src[i], d = dst[i];
            float w = ew[i];
            int b = d >> BK_SHIFT;
            ev[j] = make_int2(s | ((d & (BK_NODES - 1)) << NODE_BITS), __float_as_int(w));
            bk[j] = b;
            atomicAdd(&hist[b], 1);
        }
    }
    __syncthreads();
    int hv = hist[tid];
    sc[tid] = hv;
    __syncthreads();
    for (int d = 1; d < 256; d <<= 1) {
        int t = (tid >= d) ? sc[tid - d] : 0;
        __syncthreads();
        sc[tid] += t;
        __syncthreads();
    }
    lofs[tid] = sc[tid] - hv;
    gbase[tid] = hv ? atomicAdd(&bfill[tid], hv) : 0;
    __syncthreads();
#pragma unroll
    for (int j = 0; j < CH / 256; ++j) {
        if (bk[j] >= 0) {
            int r = atomicAdd(&cnt2[bk[j]], 1);
            int p = lofs[bk[j]] + r;
            stage2[p] = ev[j];
            bkt2[p] = (unsigned char)bk[j];
        }
    }
    __syncthreads();
    for (int i = tid; i < n; i += 256) {
        int b = bkt2[i];
        binned[gbase[b] + (i - lofs[b])] = stage2[i];
    }
}

// ---- Pass B: per-bucket local CSR + rowptr + dinv --------------------------
__global__ __launch_bounds__(256) void k_csr(const int2* __restrict__ binned,
                                             const int* __restrict__ bbase,
                                             int2* __restrict__ cvb,
                                             int* __restrict__ rowptr,
                                             float* __restrict__ dinv, int N, int E) {
    __shared__ int lh[BK_NODES];
    __shared__ float ls[BK_NODES];
    __shared__ int lofs[BK_NODES];
    __shared__ int s2[256];
    int tid = threadIdx.x;
    int b = blockIdx.x;
    int nbase = b << BK_SHIFT;
    int nend = min(nbase + BK_NODES, N);
    int ebase = bbase[b], eend = bbase[b + 1];
    for (int i = tid; i < BK_NODES; i += 256) { lh[i] = 0; ls[i] = 0.f; }
    __syncthreads();
    for (int e = ebase + tid; e < eend; e += 256) {
        int2 v = binned[e];
        int local = (v.x >> NODE_BITS) & (BK_NODES - 1);
        atomicAdd(&lh[local], 1);
        atomicAdd(&ls[local], __int_as_float(v.y));
    }
    __syncthreads();
    // exclusive scan of lh[512] via pairwise + 256-scan
    int p0 = lh[2 * tid], p1 = lh[2 * tid + 1];
    int pv = p0 + p1;
    s2[tid] = pv;
    __syncthreads();
    for (int d = 1; d < 256; d <<= 1) {
        int t = (tid >= d) ? s2[tid - d] : 0;
        __syncthreads();
        s2[tid] += t;
        __syncthreads();
    }
    int e2 = s2[tid] - pv;  // exclusive over pairs
    lofs[2 * tid] = e2;
    lofs[2 * tid + 1] = e2 + p0;
    __syncthreads();
    for (int i = nbase + tid; i < nend; i += 256) {
        int local = i - nbase;
        rowptr[i] = ebase + lofs[local];
        dinv[i] = rsqrtf(1.0f + ls[local]);
    }
    if (b == 0 && tid == 0) rowptr[N] = E;
    __syncthreads();
    for (int e = ebase + tid; e < eend; e += 256) {
        int2 v = binned[e];
        int local = (v.x >> NODE_BITS) & (BK_NODES - 1);
        int r = atomicAdd(&lofs[local], 1);
        cvb[ebase + r] = make_int2(v.x & NODE_MASK, v.y);
    }
}

// W[k][n] f32 -> WT[n][k] bf16
__global__ __launch_bounds__(256) void k_wt(const float* __restrict__ W,
                                            unsigned short* __restrict__ WT) {
    int idx = blockIdx.x * 256 + threadIdx.x;
    int n = idx >> 7, k = idx & 127;
    WT[idx] = (unsigned short)f2bf(W[(size_t)k * 128 + n]);
}

// Layer 1: Y[M,128](bf16) = dinv[row] * (x_f32[M,128] @ W), cast fused.
__global__ __launch_bounds__(256) void k_gemm1(const float* __restrict__ X,
                                               const unsigned short* __restrict__ WT,
                                               const float* __restrict__ dinv,
                                               unsigned short* __restrict__ Y, int M) {
    int tid = threadIdx.x;
    int wid = tid >> 6, lane = tid & 63;
    int rowb = blockIdx.x * 64 + wid * 16;
    int r16 = lane & 15, kg = lane >> 4;
    int arow = min(rowb + r16, M - 1);  // clamp: garbage only affects unsaved pad rows
    const float* xr = X + (size_t)arow * 128 + kg * 8;
    bf16x8 a[4];
#pragma unroll
    for (int kc = 0; kc < 4; ++kc) {
        float4 u = *reinterpret_cast<const float4*>(xr + kc * 32);
        float4 v = *reinterpret_cast<const float4*>(xr + kc * 32 + 4);
        bfpack pk;
        pk.u = make_uint4(packbf2(u.x, u.y), packbf2(u.z, u.w),
                          packbf2(v.x, v.y), packbf2(v.z, v.w));
        a[kc] = pk.b;
    }
    float dv[4];
#pragma unroll
    for (int r = 0; r < 4; ++r) {
        int ro = rowb + kg * 4 + r;
        dv[r] = (ro < M) ? dinv[ro] : 0.f;
    }
    const bf16x8* Bp = reinterpret_cast<const bf16x8*>(WT + (size_t)r16 * 128 + kg * 8);
#pragma unroll
    for (int nt = 0; nt < 8; ++nt) {
        const bf16x8* B = Bp + (size_t)nt * 256;
        f32x4 acc = {0.f, 0.f, 0.f, 0.f};
        acc = __builtin_amdgcn_mfma_f32_16x16x32_bf16(a[0], B[0], acc, 0, 0, 0);
        acc = __builtin_amdgcn_mfma_f32_16x16x32_bf16(a[1], B[4], acc, 0, 0, 0);
        acc = __builtin_amdgcn_mfma_f32_16x16x32_bf16(a[2], B[8], acc, 0, 0, 0);
        acc = __builtin_amdgcn_mfma_f32_16x16x32_bf16(a[3], B[12], acc, 0, 0, 0);
        int colo = nt * 16 + r16;
#pragma unroll
        for (int r = 0; r < 4; ++r) {
            int ro = rowb + kg * 4 + r;
            if (ro < M) Y[(size_t)ro * 128 + colo] = (unsigned short)f2bf(acc[r] * dv[r]);
        }
    }
}

// Layer 2: Y[M,128](bf16) = dinv[row] * (Hb[M,128](bf16) @ W)
__global__ __launch_bounds__(256) void k_gemm(const unsigned short* __restrict__ Xb,
                                              const unsigned short* __restrict__ WT,
                                              const float* __restrict__ dinv,
                                              unsigned short* __restrict__ Y, int M) {
    int tid = threadIdx.x;
    int wid = tid >> 6, lane = tid & 63;
    int rowb = blockIdx.x * 64 + wid * 16;
    int r16 = lane & 15, kg = lane >> 4;
    const bf16x8* Ap = reinterpret_cast<const bf16x8*>(Xb + (size_t)(rowb + r16) * 128 + kg * 8);
    bf16x8 a0 = Ap[0], a1 = Ap[4], a2 = Ap[8], a3 = Ap[12];
    float dv[4];
#pragma unroll
    for (int r = 0; r < 4; ++r) {
        int ro = rowb + kg * 4 + r;
        dv[r] = (ro < M) ? dinv[ro] : 0.f;
    }
    const bf16x8* Bp = reinterpret_cast<const bf16x8*>(WT + (size_t)r16 * 128 + kg * 8);
#pragma unroll
    for (int nt = 0; nt < 8; ++nt) {
        const bf16x8* B = Bp + (size_t)nt * 256;
        f32x4 acc = {0.f, 0.f, 0.f, 0.f};
        acc = __builtin_amdgcn_mfma_f32_16x16x32_bf16(a0, B[0], acc, 0, 0, 0);
        acc = __builtin_amdgcn_mfma_f32_16x16x32_bf16(a1, B[4], acc, 0, 0, 0);
        acc = __builtin_amdgcn_mfma_f32_16x16x32_bf16(a2, B[8], acc, 0, 0, 0);
        acc = __builtin_amdgcn_mfma_f32_16x16x32_bf16(a3, B[12], acc, 0, 0, 0);
        int colo = nt * 16 + r16;
#pragma unroll
        for (int r = 0; r < 4; ++r) {
            int ro = rowb + kg * 4 + r;
            if (ro < M) Y[(size_t)ro * 128 + colo] = (unsigned short)f2bf(acc[r] * dv[r]);
        }
    }
}

// Out[d] = relu( dinv[d]*( sum_e ew_e*H'[s_e] + H'[d] ) + bias ), bf16 in/out
// FOUR gather streams per wave; edge records staged in wave-private LDS,
// per-j broadcast via uniform ds_read (no ds_bpermute).
__global__ __launch_bounds__(256) void k_agg(const unsigned int* __restrict__ Hb,
                                             const int* __restrict__ rowptr,
                                             const int2* __restrict__ cvb,
                                             const float* __restrict__ dinv,
                                             const float* __restrict__ bias,
                                             unsigned int* __restrict__ OutB, int N) {
    __shared__ int2 lcv[4][4][64];  // [wave][stream][slot], 8 KB
    int lane = threadIdx.x & 63;
    int wid = threadIdx.x >> 6;
    int grp = blockIdx.x * 4 + wid;
    int n0 = grp * 4;
    if (n0 >= N) return;
    int r0 = rowptr[n0];
    int r1 = rowptr[min(n0 + 1, N)];
    int r2 = rowptr[min(n0 + 2, N)];
    int r3 = rowptr[min(n0 + 3, N)];
    int r4 = rowptr[min(n0 + 4, N)];
    int c0 = r1 - r0, c1 = r2 - r1, c2 = r3 - r2, c3 = r4 - r3;
    bool v1n = n0 + 1 < N, v2n = n0 + 2 < N, v3n = n0 + 3 < N;
    unsigned int hv0 = Hb[(size_t)n0 * 64 + lane];
    unsigned int hv1 = v1n ? Hb[(size_t)(n0 + 1) * 64 + lane] : 0u;
    unsigned int hv2 = v2n ? Hb[(size_t)(n0 + 2) * 64 + lane] : 0u;
    unsigned int hv3 = v3n ? Hb[(size_t)(n0 + 3) * 64 + lane] : 0u;
    float a00 = bf_lo(hv0), a01 = bf_hi(hv0);
    float a10 = bf_lo(hv1), a11 = bf_hi(hv1);
    float a20 = bf_lo(hv2), a21 = bf_hi(hv2);
    float a30 = bf_lo(hv3), a31 = bf_hi(hv3);
    int nmax = max(max(c0, c1), max(c2, c3));
    for (int base = 0; base < nmax; base += 64) {
        int bl = base + lane;
        // stage this block's edge records (zeros where out of range)
        int2 t0 = (bl < c0) ? cvb[r0 + bl] : make_int2(0, 0);
        int2 t1 = (bl < c1) ? cvb[r1 + bl] : make_int2(0, 0);
        int2 t2 = (bl < c2) ? cvb[r2 + bl] : make_int2(0, 0);
        int2 t3 = (bl < c3) ? cvb[r3 + bl] : make_int2(0, 0);
        lcv[wid][0][lane] = t0;
        lcv[wid][1][lane] = t1;
        lcv[wid][2][lane] = t2;
        lcv[wid][3][lane] = t3;
        // wave-private LDS: in-order per-wave ds ops, no barrier needed
        int m = min(64, nmax - base);
        for (int j0 = 0; j0 < m; j0 += 8) {
#pragma unroll
            for (int jj = 0; jj < 8; ++jj) {
                int j = j0 + jj;
                if (j < m) {
                    int2 e0 = lcv[wid][0][j];
                    int2 e1 = lcv[wid][1][j];
                    int2 e2 = lcv[wid][2][j];
                    int2 e3 = lcv[wid][3][j];
                    unsigned int h0 = Hb[(size_t)e0.x * 64 + lane];
                    unsigned int h1 = Hb[(size_t)e1.x * 64 + lane];
                    unsigned int h2 = Hb[(size_t)e2.x * 64 + lane];
                    unsigned int h3 = Hb[(size_t)e3.x * 64 + lane];
                    float w0 = __int_as_float(e0.y);
                    float w1 = __int_as_float(e1.y);
                    float w2 = __int_as_float(e2.y);
                    float w3 = __int_as_float(e3.y);
                    a00 = fmaf(w0, bf_lo(h0), a00);
                    a01 = fmaf(w0, bf_hi(h0), a01);
                    a10 = fmaf(w1, bf_lo(h1), a10);
                    a11 = fmaf(w1, bf_hi(h1), a11);
                    a20 = fmaf(w2, bf_lo(h2), a20);
                    a21 = fmaf(w2, bf_hi(h2), a21);
                    a30 = fmaf(w3, bf_lo(h3), a30);
                    a31 = fmaf(w3, bf_hi(h3), a31);
                }
            }
        }
    }
    float2 bv = reinterpret_cast<const float2*>(bias)[lane];
    float d0 = dinv[n0];
    a00 = fmaxf(fmaf(a00, d0, bv.x), 0.f);
    a01 = fmaxf(fmaf(a01, d0, bv.y), 0.f);
    OutB[(size_t)n0 * 64 + lane] = packbf2(a00, a01);
    if (v1n) {
        float d1 = dinv[n0 + 1];
        a10 = fmaxf(fmaf(a10, d1, bv.x), 0.f);
        a11 = fmaxf(fmaf(a11, d1, bv.y), 0.f);
        OutB[(size_t)(n0 + 1) * 64 + lane] = packbf2(a10, a11);
    }
    if (v2n) {
        float d2 = dinv[n0 + 2];
        a20 = fmaxf(fmaf(a20, d2, bv.x), 0.f);
        a21 = fmaxf(fmaf(a21, d2, bv.y), 0.f);
        OutB[(size_t)(n0 + 2) * 64 + lane] = packbf2(a20, a21);
    }
    if (v3n) {
        float d3 = dinv[n0 + 3];
        a30 = fmaxf(fmaf(a30, d3, bv.x), 0.f);
        a31 = fmaxf(fmaf(a31, d3, bv.y), 0.f);
        OutB[(size_t)(n0 + 3) * 64 + lane] = packbf2(a30, a31);
    }
}

// fused mean-pool + head: out[g] = [pooled, relu(md@Wm+bm)] @ Wf + bf
__global__ __launch_bounds__(256) void k_poolhead(const unsigned int* __restrict__ H2u,
                                                  const int* __restrict__ gstart,
                                                  const int* __restrict__ gend,
                                                  const float* __restrict__ meta,
                                                  const float* __restrict__ Wm,
                                                  const float* __restrict__ bm,
                                                  const float* __restrict__ Wf,
                                                  const float* __restrict__ bf,
                                                  float* __restrict__ out, int G) {
    int g = blockIdx.x;
    int tid = threadIdx.x;
    int cu = tid & 63, q = tid >> 6;
    __shared__ float r0[256], r1[256];
    __shared__ float pooled[128];
    __shared__ float red[128];
    int b = gstart[g];
    int e = gend[g];
    int cntg = e - b;  // <=0 for empty graph (gstart=INT_MAX, gend=0)
    float s0 = 0.f, s1 = 0.f;
    for (int i = q; i < cntg; i += 4) {
        unsigned int v = H2u[(size_t)(b + i) * 64 + cu];
        s0 += bf_lo(v);
        s1 += bf_hi(v);
    }
    r0[tid] = s0; r1[tid] = s1;
    __syncthreads();
    if (tid < 64) {
        float t0 = r0[cu] + r0[cu + 64] + r0[cu + 128] + r0[cu + 192];
        float t1 = r1[cu] + r1[cu + 64] + r1[cu + 128] + r1[cu + 192];
        float inv = 1.f / fmaxf((float)cntg, 1.f);
        pooled[2 * cu] = t0 * inv;
        pooled[2 * cu + 1] = t1 * inv;
    }
    __syncthreads();
    if (tid < 128) {
        int c = tid;
        int idx = gstart[g] % G;  // INT_MAX for empty graph (segment_min identity)
        float m = bm[c];
#pragma unroll
        for (int k = 0; k < 30; ++k) m = fmaf(meta[idx * 30 + k], Wm[k * 128 + c], m);
        m = fmaxf(m, 0.f);
        red[c] = pooled[c] * Wf[c] + m * Wf[128 + c];
    }
    __syncthreads();
    for (int st = 64; st > 0; st >>= 1) {
        if (tid < st) red[tid] += red[tid + st];
        __syncthreads();
    }
    if (tid == 0) out[g] = red[0] + bf[0];
}

extern "C" void kernel_launch(void* const* d_in, const int* in_sizes, int n_in,
                              void* d_out, int out_size, void* d_ws, size_t ws_size,
                              hipStream_t stream) {
    const float* x     = (const float*)d_in[0];
    const int*   ei    = (const int*)d_in[1];
    const float* ew    = (const float*)d_in[2];
    const int*   batch = (const int*)d_in[3];
    const float* meta  = (const float*)d_in[4];
    const float* W1    = (const float*)d_in[5];
    const float* b1    = (const float*)d_in[6];
    const float* W2    = (const float*)d_in[7];
    const float* b2    = (const float*)d_in[8];
    const float* Wm    = (const float*)d_in[9];
    const float* bm    = (const float*)d_in[10];
    const float* Wf    = (const float*)d_in[11];
    const float* bf    = (const float*)d_in[12];

    int N = in_sizes[0] / 128;
    int E = in_sizes[2];
    int G = in_sizes[4] / 30;
    int Mpad = (N + 63) & ~63;
    int NBK = (N + BK_NODES - 1) >> BK_SHIFT;  // 196 for N=100000 (<=256)
    const int* srcp = ei;
    const int* dstp = ei + E;

    char* p = (char*)d_ws;
    auto alloc = [&](size_t bytes) -> void* {
        void* r = p;
        p += (bytes + 255) & ~(size_t)255;
        return r;
    };
    float* dinv   = (float*)alloc((size_t)N * 4);
    int*   rowptr = (int*)alloc((size_t)(N + 1) * 4);
    int2*  binned = (int2*)alloc((size_t)E * 8);
    int2*  cvb    = (int2*)alloc((size_t)E * 8);
    int*   bcnt   = (int*)alloc((size_t)NBK * 4);
    int*   bbase  = (int*)alloc((size_t)(NBK + 1) * 4);
    int*   bfillp = (int*)alloc((size_t)NBK * 4);
    unsigned short* H   = (unsigned short*)alloc((size_t)Mpad * 128 * 2);
    unsigned short* H2  = (unsigned short*)alloc((size_t)Mpad * 128 * 2);
    unsigned short* WT1 = (unsigned short*)alloc(128 * 128 * 2);
    unsigned short* WT2 = (unsigned short*)alloc(128 * 128 * 2);
    int*   gstart = (int*)alloc((size_t)G * 4);
    int*   gend   = (int*)alloc((size_t)G * 4);

    int EB = (E + CH - 1) / CH;
    k_init_small<<<(max(G, NBK) + 255) / 256, 256, 0, stream>>>(gstart, gend, G, bcnt, NBK);
    k_init_nodes<<<(N + 255) / 256, 256, 0, stream>>>(batch, gstart, gend, N);
    k_binhist<<<EB, 256, 0, stream>>>(dstp, E, bcnt, NBK);
    k_binscan<<<1, 256, 0, stream>>>(bcnt, bbase, bfillp, NBK);
    k_binscatter<<<EB, 256, 0, stream>>>(srcp, dstp, ew, bfillp, binned, E);
    k_csr<<<NBK, 256, 0, stream>>>(binned, bbase, cvb, rowptr, dinv, N, E);

    k_wt<<<64, 256, 0, stream>>>(W1, WT1);
    k_wt<<<64, 256, 0, stream>>>(W2, WT2);

    k_gemm1<<<Mpad / 64, 256, 0, stream>>>(x, WT1, dinv, H, N);
    k_agg<<<(N + 15) / 16, 256, 0, stream>>>((const unsigned int*)H, rowptr, cvb, dinv, b1,
                                             (unsigned int*)H2, N);
    k_gemm<<<Mpad / 64, 256, 0, stream>>>(H2, WT2, dinv, H, N);
    k_agg<<<(N + 15) / 16, 256, 0, stream>>>((const unsigned int*)H, rowptr, cvb, dinv, b2,
                                             (unsigned int*)H2, N);

    k_poolhead<<<G, 256, 0, stream>>>((const unsigned int*)H2, gstart, gend,
                                      meta, Wm, bm, Wf, bf, (float*)d_out, G);
}

// Round 11
// 299.123 us; speedup vs baseline: 2.5466x; 1.0026x over previous
//
#include <hip/hip_runtime.h>
#include <cstdint>

// ---------------------------------------------------------------------------
// GCN pipeline (bf16 MFMA GEMMs, binned CSR build):
//  binhist -> binscan -> binscatter -> k_csr -> GEMM1(fused cast, xW*dinv)
//  -> AGG1 (8 nodes/wave: 4 slots x 2 half-wave rows) -> GEMM2(*dinv) -> AGG2
//  -> fused pool+head.  Graph ranges via sorted-batch boundaries (no atomics).
// ---------------------------------------------------------------------------

#define BK_SHIFT 9
#define BK_NODES 512            // 1 << BK_SHIFT
#define CH 4096                 // edges per binscatter chunk
#define NODE_BITS 17            // N=100000 < 2^17
#define NODE_MASK ((1 << NODE_BITS) - 1)

typedef short bf16x8 __attribute__((ext_vector_type(8)));
typedef float f32x4 __attribute__((ext_vector_type(4)));

union bfpack {
    uint4 u;
    bf16x8 b;
};

// f32 -> bf16 round-to-nearest-even
static __device__ __forceinline__ unsigned int f2bf(float f) {
    unsigned int u = __float_as_uint(f);
    return (u + 0x7fffu + ((u >> 16) & 1u)) >> 16;
}
static __device__ __forceinline__ unsigned int packbf2(float a, float b) {
    return f2bf(a) | (f2bf(b) << 16);
}
static __device__ __forceinline__ float bf_lo(unsigned int v) {
    return __uint_as_float(v << 16);
}
static __device__ __forceinline__ float bf_hi(unsigned int v) {
    return __uint_as_float(v & 0xffff0000u);
}

// gstart/gend init + zero bucket counters
__global__ void k_init_small(int* gstart, int* gend, int G, int* bcnt, int NBK) {
    int g = blockIdx.x * blockDim.x + threadIdx.x;
    if (g < G) { gstart[g] = 0x7fffffff; gend[g] = 0; }
    if (g < NBK) bcnt[g] = 0;
}

// sorted batch -> contiguous runs; boundary threads are unique writers
__global__ void k_init_nodes(const int* __restrict__ batch,
                             int* __restrict__ gstart, int* __restrict__ gend, int N) {
    int i = blockIdx.x * blockDim.x + threadIdx.x;
    if (i >= N) return;
    int b = batch[i];
    if (i == 0 || batch[i - 1] != b) gstart[b] = i;
    if (i == N - 1 || batch[i + 1] != b) gend[b] = i + 1;
}

// ---- Pass A1: per-bucket edge counts ---------------------------------------
__global__ __launch_bounds__(256) void k_binhist(const int* __restrict__ dst, int E,
                                                 int* __restrict__ bcnt, int NBK) {
    __shared__ int h[256];
    int tid = threadIdx.x;
    h[tid] = 0;
    __syncthreads();
    int base = blockIdx.x * CH;
    int nend = min(base + CH, E);
    for (int i = base + tid; i < nend; i += 256) atomicAdd(&h[dst[i] >> BK_SHIFT], 1);
    __syncthreads();
    if (tid < NBK && h[tid]) atomicAdd(&bcnt[tid], h[tid]);
}

// ---- Pass A2: scan bucket counts -> bbase[NBK+1], bfill cursors ------------
__global__ __launch_bounds__(256) void k_binscan(const int* __restrict__ bcnt,
                                                 int* __restrict__ bbase,
                                                 int* __restrict__ bfill, int NBK) {
    __shared__ int sc[256];
    int tid = threadIdx.x;
    int v = (tid < NBK) ? bcnt[tid] : 0;
    sc[tid] = v;
    __syncthreads();
    for (int d = 1; d < 256; d <<= 1) {
        int t = (tid >= d) ? sc[tid - d] : 0;
        __syncthreads();
        sc[tid] += t;
        __syncthreads();
    }
    int excl = sc[tid] - v;
    if (tid < NBK) { bbase[tid] = excl; bfill[tid] = excl; }
    if (tid == 255) bbase[NBK] = sc[255];  // total = E
}

// ---- Pass A3: counting-sort each 4096-edge chunk into bucket-major order ---
__global__ __launch_bounds__(256) void k_binscatter(const int* __restrict__ src,
                                                    const int* __restrict__ dst,
                                                    const float* __restrict__ ew,
                                                    int* __restrict__ bfill,
                                                    int2* __restrict__ binned, int E) {
    __shared__ int2 stage2[CH];          // 32 KB
    __shared__ unsigned char bkt2[CH];   // 4 KB
    __shared__ int hist[256], sc[256], lofs[256], cnt2[256], gbase[256];
    int tid = threadIdx.x;
    int base = blockIdx.x * CH;
    int n = min(CH, E - base);
    hist[tid] = 0;
    cnt2[tid] = 0;
    __syncthreads();
    int2 ev[CH / 256];
    int bk[CH / 256];
#pragma unroll
    for (int j = 0; j < CH / 256; ++j) {
        int i = base + tid + j * 256;
        bk[j] = -1;
        if (i < base + n) {
            int s = src[i], d = dst[i];
            float w = ew[i];
            int b = d >> BK_SHIFT;
            ev[j] = make_int2(s | ((d & (BK_NODES - 1)) << NODE_BITS), __float_as_int(w));
            bk[j] = b;
            atomicAdd(&hist[b], 1);
        }
    }
    __syncthreads();
    int hv = hist[tid];
    sc[tid] = hv;
    __syncthreads();
    for (int d = 1; d < 256; d <<= 1) {
        int t = (tid >= d) ? sc[tid - d] : 0;
        __syncthreads();
        sc[tid] += t;
        __syncthreads();
    }
    lofs[tid] = sc[tid] - hv;
    gbase[tid] = hv ? atomicAdd(&bfill[tid], hv) : 0;
    __syncthreads();
#pragma unroll
    for (int j = 0; j < CH / 256; ++j) {
        if (bk[j] >= 0) {
            int r = atomicAdd(&cnt2[bk[j]], 1);
            int p = lofs[bk[j]] + r;
            stage2[p] = ev[j];
            bkt2[p] = (unsigned char)bk[j];
        }
    }
    __syncthreads();
    for (int i = tid; i < n; i += 256) {
        int b = bkt2[i];
        binned[gbase[b] + (i - lofs[b])] = stage2[i];
    }
}

// ---- Pass B: per-bucket local CSR + rowptr + dinv --------------------------
__global__ __launch_bounds__(256) void k_csr(const int2* __restrict__ binned,
                                             const int* __restrict__ bbase,
                                             int2* __restrict__ cvb,
                                             int* __restrict__ rowptr,
                                             float* __restrict__ dinv, int N, int E) {
    __shared__ int lh[BK_NODES];
    __shared__ float ls[BK_NODES];
    __shared__ int lofs[BK_NODES];
    __shared__ int s2[256];
    int tid = threadIdx.x;
    int b = blockIdx.x;
    int nbase = b << BK_SHIFT;
    int nend = min(nbase + BK_NODES, N);
    int ebase = bbase[b], eend = bbase[b + 1];
    for (int i = tid; i < BK_NODES; i += 256) { lh[i] = 0; ls[i] = 0.f; }
    __syncthreads();
    for (int e = ebase + tid; e < eend; e += 256) {
        int2 v = binned[e];
        int local = (v.x >> NODE_BITS) & (BK_NODES - 1);
        atomicAdd(&lh[local], 1);
        atomicAdd(&ls[local], __int_as_float(v.y));
    }
    __syncthreads();
    // exclusive scan of lh[512] via pairwise + 256-scan
    int p0 = lh[2 * tid], p1 = lh[2 * tid + 1];
    int pv = p0 + p1;
    s2[tid] = pv;
    __syncthreads();
    for (int d = 1; d < 256; d <<= 1) {
        int t = (tid >= d) ? s2[tid - d] : 0;
        __syncthreads();
        s2[tid] += t;
        __syncthreads();
    }
    int e2 = s2[tid] - pv;  // exclusive over pairs
    lofs[2 * tid] = e2;
    lofs[2 * tid + 1] = e2 + p0;
    __syncthreads();
    for (int i = nbase + tid; i < nend; i += 256) {
        int local = i - nbase;
        rowptr[i] = ebase + lofs[local];
        dinv[i] = rsqrtf(1.0f + ls[local]);
    }
    if (b == 0 && tid == 0) rowptr[N] = E;
    __syncthreads();
    for (int e = ebase + tid; e < eend; e += 256) {
        int2 v = binned[e];
        int local = (v.x >> NODE_BITS) & (BK_NODES - 1);
        int r = atomicAdd(&lofs[local], 1);
        cvb[ebase + r] = make_int2(v.x & NODE_MASK, v.y);
    }
}

// W[k][n] f32 -> WT[n][k] bf16
__global__ __launch_bounds__(256) void k_wt(const float* __restrict__ W,
                                            unsigned short* __restrict__ WT) {
    int idx = blockIdx.x * 256 + threadIdx.x;
    int n = idx >> 7, k = idx & 127;
    WT[idx] = (unsigned short)f2bf(W[(size_t)k * 128 + n]);
}

// Layer 1: Y[M,128](bf16) = dinv[row] * (x_f32[M,128] @ W), cast fused.
__global__ __launch_bounds__(256) void k_gemm1(const float* __restrict__ X,
                                               const unsigned short* __restrict__ WT,
                                               const float* __restrict__ dinv,
                                               unsigned short* __restrict__ Y, int M) {
    int tid = threadIdx.x;
    int wid = tid >> 6, lane = tid & 63;
    int rowb = blockIdx.x * 64 + wid * 16;
    int r16 = lane & 15, kg = lane >> 4;
    int arow = min(rowb + r16, M - 1);  // clamp: garbage only affects unsaved pad rows
    const float* xr = X + (size_t)arow * 128 + kg * 8;
    bf16x8 a[4];
#pragma unroll
    for (int kc = 0; kc < 4; ++kc) {
        float4 u = *reinterpret_cast<const float4*>(xr + kc * 32);
        float4 v = *reinterpret_cast<const float4*>(xr + kc * 32 + 4);
        bfpack pk;
        pk.u = make_uint4(packbf2(u.x, u.y), packbf2(u.z, u.w),
                          packbf2(v.x, v.y), packbf2(v.z, v.w));
        a[kc] = pk.b;
    }
    float dv[4];
#pragma unroll
    for (int r = 0; r < 4; ++r) {
        int ro = rowb + kg * 4 + r;
        dv[r] = (ro < M) ? dinv[ro] : 0.f;
    }
    const bf16x8* Bp = reinterpret_cast<const bf16x8*>(WT + (size_t)r16 * 128 + kg * 8);
#pragma unroll
    for (int nt = 0; nt < 8; ++nt) {
        const bf16x8* B = Bp + (size_t)nt * 256;
        f32x4 acc = {0.f, 0.f, 0.f, 0.f};
        acc = __builtin_amdgcn_mfma_f32_16x16x32_bf16(a[0], B[0], acc, 0, 0, 0);
        acc = __builtin_amdgcn_mfma_f32_16x16x32_bf16(a[1], B[4], acc, 0, 0, 0);
        acc = __builtin_amdgcn_mfma_f32_16x16x32_bf16(a[2], B[8], acc, 0, 0, 0);
        acc = __builtin_amdgcn_mfma_f32_16x16x32_bf16(a[3], B[12], acc, 0, 0, 0);
        int colo = nt * 16 + r16;
#pragma unroll
        for (int r = 0; r < 4; ++r) {
            int ro = rowb + kg * 4 + r;
            if (ro < M) Y[(size_t)ro * 128 + colo] = (unsigned short)f2bf(acc[r] * dv[r]);
        }
    }
}

// Layer 2: Y[M,128](bf16) = dinv[row] * (Hb[M,128](bf16) @ W)
__global__ __launch_bounds__(256) void k_gemm(const unsigned short* __restrict__ Xb,
                                              const unsigned short* __restrict__ WT,
                                              const float* __restrict__ dinv,
                                              unsigned short* __restrict__ Y, int M) {
    int tid = threadIdx.x;
    int wid = tid >> 6, lane = tid & 63;
    int rowb = blockIdx.x * 64 + wid * 16;
    int r16 = lane & 15, kg = lane >> 4;
    const bf16x8* Ap = reinterpret_cast<const bf16x8*>(Xb + (size_t)(rowb + r16) * 128 + kg * 8);
    bf16x8 a0 = Ap[0], a1 = Ap[4], a2 = Ap[8], a3 = Ap[12];
    float dv[4];
#pragma unroll
    for (int r = 0; r < 4; ++r) {
        int ro = rowb + kg * 4 + r;
        dv[r] = (ro < M) ? dinv[ro] : 0.f;
    }
    const bf16x8* Bp = reinterpret_cast<const bf16x8*>(WT + (size_t)r16 * 128 + kg * 8);
#pragma unroll
    for (int nt = 0; nt < 8; ++nt) {
        const bf16x8* B = Bp + (size_t)nt * 256;
        f32x4 acc = {0.f, 0.f, 0.f, 0.f};
        acc = __builtin_amdgcn_mfma_f32_16x16x32_bf16(a0, B[0], acc, 0, 0, 0);
        acc = __builtin_amdgcn_mfma_f32_16x16x32_bf16(a1, B[4], acc, 0, 0, 0);
        acc = __builtin_amdgcn_mfma_f32_16x16x32_bf16(a2, B[8], acc, 0, 0, 0);
        acc = __builtin_amdgcn_mfma_f32_16x16x32_bf16(a3, B[12], acc, 0, 0, 0);
        int colo = nt * 16 + r16;
#pragma unroll
        for (int r = 0; r < 4; ++r) {
            int ro = rowb + kg * 4 + r;
            if (ro < M) Y[(size_t)ro * 128 + colo] = (unsigned short)f2bf(acc[r] * dv[r]);
        }
    }
}

// Out[d] = relu( dinv[d]*( sum_e ew_e*H'[s_e] + H'[d] ) + bias ), bf16 in/out
// 8 nodes per wave: 4 slots x 2 half-wave rows (uint2/lane = 8B, 32 lanes/row).
// Each gather instruction fetches TWO 256B rows -> 2x bytes in flight.
__global__ __launch_bounds__(256) void k_agg(const uint2* __restrict__ Hb2,
                                             const int* __restrict__ rowptr,
                                             const int2* __restrict__ cvb,
                                             const float* __restrict__ dinv,
                                             const float* __restrict__ bias,
                                             uint2* __restrict__ OutB2, int N) {
    __shared__ int2 lcv[4][4][2][64];  // [wave][slot][half][slot64], 16 KB
    int tid = threadIdx.x;
    int lane = tid & 63, wid = tid >> 6;
    int half = lane >> 5, sl = lane & 31;
    int n0 = (blockIdx.x * 4 + wid) * 8;
    if (n0 >= N) return;
    // rowptr[n0 .. n0+8] via one lane-parallel load + shfl broadcast
    int rv = rowptr[min(n0 + min(lane, 8), N)];
    int rp[9];
#pragma unroll
    for (int k = 0; k < 9; ++k) rp[k] = __shfl(rv, k);
    int cnt[8];
    int nmax = 0;
#pragma unroll
    for (int k = 0; k < 8; ++k) {
        cnt[k] = rp[k + 1] - rp[k];
        nmax = max(nmax, cnt[k]);
    }
    // self terms; own node for slot s is n0 + 2*s + half (per-lane)
    float a[4][4];
#pragma unroll
    for (int s = 0; s < 4; ++s) {
        int ns = n0 + 2 * s + half;
        uint2 hv = (ns < N) ? Hb2[(size_t)ns * 32 + sl] : make_uint2(0u, 0u);
        a[s][0] = bf_lo(hv.x);
        a[s][1] = bf_hi(hv.x);
        a[s][2] = bf_lo(hv.y);
        a[s][3] = bf_hi(hv.y);
    }
    for (int base = 0; base < nmax; base += 64) {
        // stage 64-entry blocks of all 8 edge lists (coalesced, wave-private)
#pragma unroll
        for (int s = 0; s < 4; ++s) {
#pragma unroll
            for (int h = 0; h < 2; ++h) {
                int k = 2 * s + h;
                int2 t = (base + lane < cnt[k]) ? cvb[rp[k] + base + lane]
                                                : make_int2(0, 0);
                lcv[wid][s][h][lane] = t;
            }
        }
        int m = min(64, nmax - base);
        for (int j0 = 0; j0 < m; j0 += 8) {
#pragma unroll
            for (int jj = 0; jj < 8; ++jj) {
                int j = j0 + jj;
                if (j < m) {
                    int2 e0 = lcv[wid][0][half][j];
                    int2 e1 = lcv[wid][1][half][j];
                    int2 e2 = lcv[wid][2][half][j];
                    int2 e3 = lcv[wid][3][half][j];
                    uint2 h0 = Hb2[(size_t)e0.x * 32 + sl];
                    uint2 h1 = Hb2[(size_t)e1.x * 32 + sl];
                    uint2 h2 = Hb2[(size_t)e2.x * 32 + sl];
                    uint2 h3 = Hb2[(size_t)e3.x * 32 + sl];
                    float w0 = __int_as_float(e0.y);
                    float w1 = __int_as_float(e1.y);
                    float w2 = __int_as_float(e2.y);
                    float w3 = __int_as_float(e3.y);
                    a[0][0] = fmaf(w0, bf_lo(h0.x), a[0][0]);
                    a[0][1] = fmaf(w0, bf_hi(h0.x), a[0][1]);
                    a[0][2] = fmaf(w0, bf_lo(h0.y), a[0][2]);
                    a[0][3] = fmaf(w0, bf_hi(h0.y), a[0][3]);
                    a[1][0] = fmaf(w1, bf_lo(h1.x), a[1][0]);
                    a[1][1] = fmaf(w1, bf_hi(h1.x), a[1][1]);
                    a[1][2] = fmaf(w1, bf_lo(h1.y), a[1][2]);
                    a[1][3] = fmaf(w1, bf_hi(h1.y), a[1][3]);
                    a[2][0] = fmaf(w2, bf_lo(h2.x), a[2][0]);
                    a[2][1] = fmaf(w2, bf_hi(h2.x), a[2][1]);
                    a[2][2] = fmaf(w2, bf_lo(h2.y), a[2][2]);
                    a[2][3] = fmaf(w2, bf_hi(h2.y), a[2][3]);
                    a[3][0] = fmaf(w3, bf_lo(h3.x), a[3][0]);
                    a[3][1] = fmaf(w3, bf_hi(h3.x), a[3][1]);
                    a[3][2] = fmaf(w3, bf_lo(h3.y), a[3][2]);
                    a[3][3] = fmaf(w3, bf_hi(h3.y), a[3][3]);
                }
            }
        }
    }
    float4 bv = reinterpret_cast<const float4*>(bias)[sl];
#pragma unroll
    for (int s = 0; s < 4; ++s) {
        int ns = n0 + 2 * s + half;
        if (ns < N) {
            float d = dinv[ns];
            float o0 = fmaxf(fmaf(a[s][0], d, bv.x), 0.f);
            float o1 = fmaxf(fmaf(a[s][1], d, bv.y), 0.f);
            float o2 = fmaxf(fmaf(a[s][2], d, bv.z), 0.f);
            float o3 = fmaxf(fmaf(a[s][3], d, bv.w), 0.f);
            OutB2[(size_t)ns * 32 + sl] = make_uint2(packbf2(o0, o1), packbf2(o2, o3));
        }
    }
}

// fused mean-pool + head: out[g] = [pooled, relu(md@Wm+bm)] @ Wf + bf
__global__ __launch_bounds__(256) void k_poolhead(const unsigned int* __restrict__ H2u,
                                                  const int* __restrict__ gstart,
                                                  const int* __restrict__ gend,
                                                  const float* __restrict__ meta,
                                                  const float* __restrict__ Wm,
                                                  const float* __restrict__ bm,
                                                  const float* __restrict__ Wf,
                                                  const float* __restrict__ bf,
                                                  float* __restrict__ out, int G) {
    int g = blockIdx.x;
    int tid = threadIdx.x;
    int cu = tid & 63, q = tid >> 6;
    __shared__ float r0[256], r1[256];
    __shared__ float pooled[128];
    __shared__ float red[128];
    int b = gstart[g];
    int e = gend[g];
    int cntg = e - b;  // <=0 for empty graph (gstart=INT_MAX, gend=0)
    float s0 = 0.f, s1 = 0.f;
    for (int i = q; i < cntg; i += 4) {
        unsigned int v = H2u[(size_t)(b + i) * 64 + cu];
        s0 += bf_lo(v);
        s1 += bf_hi(v);
    }
    r0[tid] = s0; r1[tid] = s1;
    __syncthreads();
    if (tid < 64) {
        float t0 = r0[cu] + r0[cu + 64] + r0[cu + 128] + r0[cu + 192];
        float t1 = r1[cu] + r1[cu + 64] + r1[cu + 128] + r1[cu + 192];
        float inv = 1.f / fmaxf((float)cntg, 1.f);
        pooled[2 * cu] = t0 * inv;
        pooled[2 * cu + 1] = t1 * inv;
    }
    __syncthreads();
    if (tid < 128) {
        int c = tid;
        int idx = gstart[g] % G;  // INT_MAX for empty graph (segment_min identity)
        float m = bm[c];
#pragma unroll
        for (int k = 0; k < 30; ++k) m = fmaf(meta[idx * 30 + k], Wm[k * 128 + c], m);
        m = fmaxf(m, 0.f);
        red[c] = pooled[c] * Wf[c] + m * Wf[128 + c];
    }
    __syncthreads();
    for (int st = 64; st > 0; st >>= 1) {
        if (tid < st) red[tid] += red[tid + st];
        __syncthreads();
    }
    if (tid == 0) out[g] = red[0] + bf[0];
}

extern "C" void kernel_launch(void* const* d_in, const int* in_sizes, int n_in,
                              void* d_out, int out_size, void* d_ws, size_t ws_size,
                              hipStream_t stream) {
    const float* x     = (const float*)d_in[0];
    const int*   ei    = (const int*)d_in[1];
    const float* ew    = (const float*)d_in[2];
    const int*   batch = (const int*)d_in[3];
    const float* meta  = (const float*)d_in[4];
    const float* W1    = (const float*)d_in[5];
    const float* b1    = (const float*)d_in[6];
    const float* W2    = (const float*)d_in[7];
    const float* b2    = (const float*)d_in[8];
    const float* Wm    = (const float*)d_in[9];
    const float* bm    = (const float*)d_in[10];
    const float* Wf    = (const float*)d_in[11];
    const float* bf    = (const float*)d_in[12];

    int N = in_sizes[0] / 128;
    int E = in_sizes[2];
    int G = in_sizes[4] / 30;
    int Mpad = (N + 63) & ~63;
    int NBK = (N + BK_NODES - 1) >> BK_SHIFT;  // 196 for N=100000 (<=256)
    const int* srcp = ei;
    const int* dstp = ei + E;

    char* p = (char*)d_ws;
    auto alloc = [&](size_t bytes) -> void* {
        void* r = p;
        p += (bytes + 255) & ~(size_t)255;
        return r;
    };
    float* dinv   = (float*)alloc((size_t)N * 4);
    int*   rowptr = (int*)alloc((size_t)(N + 1) * 4);
    int2*  binned = (int2*)alloc((size_t)E * 8);
    int2*  cvb    = (int2*)alloc((size_t)E * 8);
    int*   bcnt   = (int*)alloc((size_t)NBK * 4);
    int*   bbase  = (int*)alloc((size_t)(NBK + 1) * 4);
    int*   bfillp = (int*)alloc((size_t)NBK * 4);
    unsigned short* H   = (unsigned short*)alloc((size_t)Mpad * 128 * 2);
    unsigned short* H2  = (unsigned short*)alloc((size_t)Mpad * 128 * 2);
    unsigned short* WT1 = (unsigned short*)alloc(128 * 128 * 2);
    unsigned short* WT2 = (unsigned short*)alloc(128 * 128 * 2);
    int*   gstart = (int*)alloc((size_t)G * 4);
    int*   gend   = (int*)alloc((size_t)G * 4);

    int EB = (E + CH - 1) / CH;
    k_init_small<<<(max(G, NBK) + 255) / 256, 256, 0, stream>>>(gstart, gend, G, bcnt, NBK);
    k_init_nodes<<<(N + 255) / 256, 256, 0, stream>>>(batch, gstart, gend, N);
    k_binhist<<<EB, 256, 0, stream>>>(dstp, E, bcnt, NBK);
    k_binscan<<<1, 256, 0, stream>>>(bcnt, bbase, bfillp, NBK);
    k_binscatter<<<EB, 256, 0, stream>>>(srcp, dstp, ew, bfillp, binned, E);
    k_csr<<<NBK, 256, 0, stream>>>(binned, bbase, cvb, rowptr, dinv, N, E);

    k_wt<<<64, 256, 0, stream>>>(W1, WT1);
    k_wt<<<64, 256, 0, stream>>>(W2, WT2);

    k_gemm1<<<Mpad / 64, 256, 0, stream>>>(x, WT1, dinv, H, N);
    k_agg<<<(N + 31) / 32, 256, 0, stream>>>((const uint2*)H, rowptr, cvb, dinv, b1,
                                             (uint2*)H2, N);
    k_gemm<<<Mpad / 64, 256, 0, stream>>>(H2, WT2, dinv, H, N);
    k_agg<<<(N + 31) / 32, 256, 0, stream>>>((const uint2*)H, rowptr, cvb, dinv, b2,
                                             (uint2*)H2, N);

    k_poolhead<<<G, 256, 0, stream>>>((const unsigned int*)H2, gstart, gend,
                                      meta, Wm, bm, Wf, bf, (float*)d_out, G);
}

// Round 12
// 290.861 us; speedup vs baseline: 2.6189x; 1.0284x over previous
//
#include <hip/hip_runtime.h>
#include <cstdint>

// ---------------------------------------------------------------------------
// GCN pipeline (bf16 MFMA GEMMs, binned CSR build):
//  binhist -> binscan -> binscatter -> k_csr -> GEMM1(fused cast, xW*dinv)
//  -> AGGEMM (agg layer1 + fused GEMM2, 8 nodes/wave gather + MFMA tail)
//  -> AGG2 -> fused pool+head.  Graph ranges via sorted-batch boundaries.
// ---------------------------------------------------------------------------

#define BK_SHIFT 9
#define BK_NODES 512            // 1 << BK_SHIFT
#define CH 4096                 // edges per binscatter chunk
#define NODE_BITS 17            // N=100000 < 2^17
#define NODE_MASK ((1 << NODE_BITS) - 1)

typedef short bf16x8 __attribute__((ext_vector_type(8)));
typedef float f32x4 __attribute__((ext_vector_type(4)));

union bfpack {
    uint4 u;
    bf16x8 b;
};

// f32 -> bf16 round-to-nearest-even
static __device__ __forceinline__ unsigned int f2bf(float f) {
    unsigned int u = __float_as_uint(f);
    return (u + 0x7fffu + ((u >> 16) & 1u)) >> 16;
}
static __device__ __forceinline__ unsigned int packbf2(float a, float b) {
    return f2bf(a) | (f2bf(b) << 16);
}
static __device__ __forceinline__ float bf_lo(unsigned int v) {
    return __uint_as_float(v << 16);
}
static __device__ __forceinline__ float bf_hi(unsigned int v) {
    return __uint_as_float(v & 0xffff0000u);
}

// gstart/gend init + zero bucket counters
__global__ void k_init_small(int* gstart, int* gend, int G, int* bcnt, int NBK) {
    int g = blockIdx.x * blockDim.x + threadIdx.x;
    if (g < G) { gstart[g] = 0x7fffffff; gend[g] = 0; }
    if (g < NBK) bcnt[g] = 0;
}

// sorted batch -> contiguous runs; boundary threads are unique writers
__global__ void k_init_nodes(const int* __restrict__ batch,
                             int* __restrict__ gstart, int* __restrict__ gend, int N) {
    int i = blockIdx.x * blockDim.x + threadIdx.x;
    if (i >= N) return;
    int b = batch[i];
    if (i == 0 || batch[i - 1] != b) gstart[b] = i;
    if (i == N - 1 || batch[i + 1] != b) gend[b] = i + 1;
}

// ---- Pass A1: per-bucket edge counts ---------------------------------------
__global__ __launch_bounds__(256) void k_binhist(const int* __restrict__ dst, int E,
                                                 int* __restrict__ bcnt, int NBK) {
    __shared__ int h[256];
    int tid = threadIdx.x;
    h[tid] = 0;
    __syncthreads();
    int base = blockIdx.x * CH;
    int nend = min(base + CH, E);
    for (int i = base + tid; i < nend; i += 256) atomicAdd(&h[dst[i] >> BK_SHIFT], 1);
    __syncthreads();
    if (tid < NBK && h[tid]) atomicAdd(&bcnt[tid], h[tid]);
}

// ---- Pass A2: scan bucket counts -> bbase[NBK+1], bfill cursors ------------
__global__ __launch_bounds__(256) void k_binscan(const int* __restrict__ bcnt,
                                                 int* __restrict__ bbase,
                                                 int* __restrict__ bfill, int NBK) {
    __shared__ int sc[256];
    int tid = threadIdx.x;
    int v = (tid < NBK) ? bcnt[tid] : 0;
    sc[tid] = v;
    __syncthreads();
    for (int d = 1; d < 256; d <<= 1) {
        int t = (tid >= d) ? sc[tid - d] : 0;
        __syncthreads();
        sc[tid] += t;
        __syncthreads();
    }
    int excl = sc[tid] - v;
    if (tid < NBK) { bbase[tid] = excl; bfill[tid] = excl; }
    if (tid == 255) bbase[NBK] = sc[255];  // total = E
}

// ---- Pass A3: counting-sort each 4096-edge chunk into bucket-major order ---
__global__ __launch_bounds__(256) void k_binscatter(const int* __restrict__ src,
                                                    const int* __restrict__ dst,
                                                    const float* __restrict__ ew,
                                                    int* __restrict__ bfill,
                                                    int2* __restrict__ binned, int E) {
    __shared__ int2 stage2[CH];          // 32 KB
    __shared__ unsigned char bkt2[CH];   // 4 KB
    __shared__ int hist[256], sc[256], lofs[256], cnt2[256], gbase[256];
    int tid = threadIdx.x;
    int base = blockIdx.x * CH;
    int n = min(CH, E - base);
    hist[tid] = 0;
    cnt2[tid] = 0;
    __syncthreads();
    int2 ev[CH / 256];
    int bk[CH / 256];
#pragma unroll
    for (int j = 0; j < CH / 256; ++j) {
        int i = base + tid + j * 256;
        bk[j] = -1;
        if (i < base + n) {
            int s = src[i], d = dst[i];
            float w = ew[i];
            int b = d >> BK_SHIFT;
            ev[j] = make_int2(s | ((d & (BK_NODES - 1)) << NODE_BITS), __float_as_int(w));
            bk[j] = b;
            atomicAdd(&hist[b], 1);
        }
    }
    __syncthreads();
    int hv = hist[tid];
    sc[tid] = hv;
    __syncthreads();
    for (int d = 1; d < 256; d <<= 1) {
        int t = (tid >= d) ? sc[tid - d] : 0;
        __syncthreads();
        sc[tid] += t;
        __syncthreads();
    }
    lofs[tid] = sc[tid] - hv;
    gbase[tid] = hv ? atomicAdd(&bfill[tid], hv) : 0;
    __syncthreads();
#pragma unroll
    for (int j = 0; j < CH / 256; ++j) {
        if (bk[j] >= 0) {
            int r = atomicAdd(&cnt2[bk[j]], 1);
            int p = lofs[bk[j]] + r;
            stage2[p] = ev[j];
            bkt2[p] = (unsigned char)bk[j];
        }
    }
    __syncthreads();
    for (int i = tid; i < n; i += 256) {
        int b = bkt2[i];
        binned[gbase[b] + (i - lofs[b])] = stage2[i];
    }
}

// ---- Pass B: per-bucket local CSR + rowptr + dinv --------------------------
__global__ __launch_bounds__(256) void k_csr(const int2* __restrict__ binned,
                                             const int* __restrict__ bbase,
                                             int2* __restrict__ cvb,
                                             int* __restrict__ rowptr,
                                             float* __restrict__ dinv, int N, int E) {
    __shared__ int lh[BK_NODES];
    __shared__ float ls[BK_NODES];
    __shared__ int lofs[BK_NODES];
    __shared__ int s2[256];
    int tid = threadIdx.x;
    int b = blockIdx.x;
    int nbase = b << BK_SHIFT;
    int nend = min(nbase + BK_NODES, N);
    int ebase = bbase[b], eend = bbase[b + 1];
    for (int i = tid; i < BK_NODES; i += 256) { lh[i] = 0; ls[i] = 0.f; }
    __syncthreads();
    for (int e = ebase + tid; e < eend; e += 256) {
        int2 v = binned[e];
        int local = (v.x >> NODE_BITS) & (BK_NODES - 1);
        atomicAdd(&lh[local], 1);
        atomicAdd(&ls[local], __int_as_float(v.y));
    }
    __syncthreads();
    // exclusive scan of lh[512] via pairwise + 256-scan
    int p0 = lh[2 * tid], p1 = lh[2 * tid + 1];
    int pv = p0 + p1;
    s2[tid] = pv;
    __syncthreads();
    for (int d = 1; d < 256; d <<= 1) {
        int t = (tid >= d) ? s2[tid - d] : 0;
        __syncthreads();
        s2[tid] += t;
        __syncthreads();
    }
    int e2 = s2[tid] - pv;  // exclusive over pairs
    lofs[2 * tid] = e2;
    lofs[2 * tid + 1] = e2 + p0;
    __syncthreads();
    for (int i = nbase + tid; i < nend; i += 256) {
        int local = i - nbase;
        rowptr[i] = ebase + lofs[local];
        dinv[i] = rsqrtf(1.0f + ls[local]);
    }
    if (b == 0 && tid == 0) rowptr[N] = E;
    __syncthreads();
    for (int e = ebase + tid; e < eend; e += 256) {
        int2 v = binned[e];
        int local = (v.x >> NODE_BITS) & (BK_NODES - 1);
        int r = atomicAdd(&lofs[local], 1);
        cvb[ebase + r] = make_int2(v.x & NODE_MASK, v.y);
    }
}

// both W -> WT transposes in one launch (grid 128)
__global__ __launch_bounds__(256) void k_wtboth(const float* __restrict__ W1,
                                                const float* __restrict__ W2,
                                                unsigned short* __restrict__ WT1,
                                                unsigned short* __restrict__ WT2) {
    int idx = blockIdx.x * 256 + threadIdx.x;
    const float* W = (idx < 16384) ? W1 : W2;
    unsigned short* WT = (idx < 16384) ? WT1 : WT2;
    int i = idx & 16383;
    int n = i >> 7, k = i & 127;
    WT[i] = (unsigned short)f2bf(W[(size_t)k * 128 + n]);
}

// Layer 1: Y[M,128](bf16) = dinv[row] * (x_f32[M,128] @ W), cast fused.
__global__ __launch_bounds__(256) void k_gemm1(const float* __restrict__ X,
                                               const unsigned short* __restrict__ WT,
                                               const float* __restrict__ dinv,
                                               unsigned short* __restrict__ Y, int M) {
    int tid = threadIdx.x;
    int wid = tid >> 6, lane = tid & 63;
    int rowb = blockIdx.x * 64 + wid * 16;
    int r16 = lane & 15, kg = lane >> 4;
    int arow = min(rowb + r16, M - 1);  // clamp: garbage only affects unsaved pad rows
    const float* xr = X + (size_t)arow * 128 + kg * 8;
    bf16x8 a[4];
#pragma unroll
    for (int kc = 0; kc < 4; ++kc) {
        float4 u = *reinterpret_cast<const float4*>(xr + kc * 32);
        float4 v = *reinterpret_cast<const float4*>(xr + kc * 32 + 4);
        bfpack pk;
        pk.u = make_uint4(packbf2(u.x, u.y), packbf2(u.z, u.w),
                          packbf2(v.x, v.y), packbf2(v.z, v.w));
        a[kc] = pk.b;
    }
    float dv[4];
#pragma unroll
    for (int r = 0; r < 4; ++r) {
        int ro = rowb + kg * 4 + r;
        dv[r] = (ro < M) ? dinv[ro] : 0.f;
    }
    const bf16x8* Bp = reinterpret_cast<const bf16x8*>(WT + (size_t)r16 * 128 + kg * 8);
#pragma unroll
    for (int nt = 0; nt < 8; ++nt) {
        const bf16x8* B = Bp + (size_t)nt * 256;
        f32x4 acc = {0.f, 0.f, 0.f, 0.f};
        acc = __builtin_amdgcn_mfma_f32_16x16x32_bf16(a[0], B[0], acc, 0, 0, 0);
        acc = __builtin_amdgcn_mfma_f32_16x16x32_bf16(a[1], B[4], acc, 0, 0, 0);
        acc = __builtin_amdgcn_mfma_f32_16x16x32_bf16(a[2], B[8], acc, 0, 0, 0);
        acc = __builtin_amdgcn_mfma_f32_16x16x32_bf16(a[3], B[12], acc, 0, 0, 0);
        int colo = nt * 16 + r16;
#pragma unroll
        for (int r = 0; r < 4; ++r) {
            int ro = rowb + kg * 4 + r;
            if (ro < M) Y[(size_t)ro * 128 + colo] = (unsigned short)f2bf(acc[r] * dv[r]);
        }
    }
}

// AGG layer1 + fused GEMM2.
// Gather phase (8 nodes/wave, half-wave rows) computes relu(dinv*agg + b1)
// rows; stage 32 rows/block in LDS; MFMA phase computes dinv * (rows @ W2).
__global__ __launch_bounds__(256) void k_aggemm(const uint2* __restrict__ Hb2,
                                                const int* __restrict__ rowptr,
                                                const int2* __restrict__ cvb,
                                                const float* __restrict__ dinv,
                                                const float* __restrict__ bias,
                                                const unsigned short* __restrict__ WT2,
                                                unsigned short* __restrict__ Y, int N) {
    __shared__ int2 lcv[4][4][2][64];  // 16 KB gather staging
    __shared__ uint2 hst[32][33];      // 8.25 KB relu'd rows (padded stride)
    int tid = threadIdx.x;
    int lane = tid & 63, wid = tid >> 6;
    int half = lane >> 5, sl = lane & 31;
    int blockbase = blockIdx.x * 32;
    int n0 = blockbase + wid * 8;
    bool active = (n0 < N);
    float a[4][4];
#pragma unroll
    for (int s = 0; s < 4; ++s)
#pragma unroll
        for (int q = 0; q < 4; ++q) a[s][q] = 0.f;
    if (active) {
        int rv = rowptr[min(n0 + min(lane, 8), N)];
        int rp[9];
#pragma unroll
        for (int k = 0; k < 9; ++k) rp[k] = __shfl(rv, k);
        int cnt[8];
        int nmax = 0;
#pragma unroll
        for (int k = 0; k < 8; ++k) {
            cnt[k] = rp[k + 1] - rp[k];
            nmax = max(nmax, cnt[k]);
        }
#pragma unroll
        for (int s = 0; s < 4; ++s) {
            int ns = n0 + 2 * s + half;
            uint2 hv = (ns < N) ? Hb2[(size_t)ns * 32 + sl] : make_uint2(0u, 0u);
            a[s][0] = bf_lo(hv.x);
            a[s][1] = bf_hi(hv.x);
            a[s][2] = bf_lo(hv.y);
            a[s][3] = bf_hi(hv.y);
        }
        for (int base = 0; base < nmax; base += 64) {
#pragma unroll
            for (int s = 0; s < 4; ++s) {
#pragma unroll
                for (int h = 0; h < 2; ++h) {
                    int k = 2 * s + h;
                    int2 t = (base + lane < cnt[k]) ? cvb[rp[k] + base + lane]
                                                    : make_int2(0, 0);
                    lcv[wid][s][h][lane] = t;
                }
            }
            int m = min(64, nmax - base);
            for (int j0 = 0; j0 < m; j0 += 8) {
#pragma unroll
                for (int jj = 0; jj < 8; ++jj) {
                    int j = j0 + jj;
                    if (j < m) {
                        int2 e0 = lcv[wid][0][half][j];
                        int2 e1 = lcv[wid][1][half][j];
                        int2 e2 = lcv[wid][2][half][j];
                        int2 e3 = lcv[wid][3][half][j];
                        uint2 h0 = Hb2[(size_t)e0.x * 32 + sl];
                        uint2 h1 = Hb2[(size_t)e1.x * 32 + sl];
                        uint2 h2 = Hb2[(size_t)e2.x * 32 + sl];
                        uint2 h3 = Hb2[(size_t)e3.x * 32 + sl];
                        float w0 = __int_as_float(e0.y);
                        float w1 = __int_as_float(e1.y);
                        float w2 = __int_as_float(e2.y);
                        float w3 = __int_as_float(e3.y);
                        a[0][0] = fmaf(w0, bf_lo(h0.x), a[0][0]);
                        a[0][1] = fmaf(w0, bf_hi(h0.x), a[0][1]);
                        a[0][2] = fmaf(w0, bf_lo(h0.y), a[0][2]);
                        a[0][3] = fmaf(w0, bf_hi(h0.y), a[0][3]);
                        a[1][0] = fmaf(w1, bf_lo(h1.x), a[1][0]);
                        a[1][1] = fmaf(w1, bf_hi(h1.x), a[1][1]);
                        a[1][2] = fmaf(w1, bf_lo(h1.y), a[1][2]);
                        a[1][3] = fmaf(w1, bf_hi(h1.y), a[1][3]);
                        a[2][0] = fmaf(w2, bf_lo(h2.x), a[2][0]);
                        a[2][1] = fmaf(w2, bf_hi(h2.x), a[2][1]);
                        a[2][2] = fmaf(w2, bf_lo(h2.y), a[2][2]);
                        a[2][3] = fmaf(w2, bf_hi(h2.y), a[2][3]);
                        a[3][0] = fmaf(w3, bf_lo(h3.x), a[3][0]);
                        a[3][1] = fmaf(w3, bf_hi(h3.x), a[3][1]);
                        a[3][2] = fmaf(w3, bf_lo(h3.y), a[3][2]);
                        a[3][3] = fmaf(w3, bf_hi(h3.y), a[3][3]);
                    }
                }
            }
        }
    }
    // bias + relu -> stage rows into LDS (pad rows = 0)
    float4 bv = reinterpret_cast<const float4*>(bias)[sl];
#pragma unroll
    for (int s = 0; s < 4; ++s) {
        int ns = n0 + 2 * s + half;
        uint2 o = make_uint2(0u, 0u);
        if (active && ns < N) {
            float d = dinv[ns];
            float o0 = fmaxf(fmaf(a[s][0], d, bv.x), 0.f);
            float o1 = fmaxf(fmaf(a[s][1], d, bv.y), 0.f);
            float o2 = fmaxf(fmaf(a[s][2], d, bv.z), 0.f);
            float o3 = fmaxf(fmaf(a[s][3], d, bv.w), 0.f);
            o = make_uint2(packbf2(o0, o1), packbf2(o2, o3));
        }
        hst[wid * 8 + 2 * s + half][sl] = o;
    }
    __syncthreads();
    // ---- MFMA phase: 32x128 @ 128x128; wave -> 16-row x 64-col tile ----
    int r16 = lane & 15, kg = lane >> 4;
    int trow = wid >> 1;
    int ntb = (wid & 1) * 4;
    int arow = trow * 16 + r16;
    bf16x8 afr[4];
#pragma unroll
    for (int kc = 0; kc < 4; ++kc) {
        uint2 lo = hst[arow][kc * 8 + kg * 2];
        uint2 hi = hst[arow][kc * 8 + kg * 2 + 1];
        bfpack pk;
        pk.u = make_uint4(lo.x, lo.y, hi.x, hi.y);
        afr[kc] = pk.b;
    }
    float dv[4];
#pragma unroll
    for (int r = 0; r < 4; ++r) {
        int ro = blockbase + trow * 16 + kg * 4 + r;
        dv[r] = (ro < N) ? dinv[ro] : 0.f;
    }
    const bf16x8* Bp = reinterpret_cast<const bf16x8*>(WT2 + (size_t)r16 * 128 + kg * 8);
#pragma unroll
    for (int nt = 0; nt < 4; ++nt) {
        const bf16x8* B = Bp + (size_t)(ntb + nt) * 256;
        f32x4 acc = {0.f, 0.f, 0.f, 0.f};
        acc = __builtin_amdgcn_mfma_f32_16x16x32_bf16(afr[0], B[0], acc, 0, 0, 0);
        acc = __builtin_amdgcn_mfma_f32_16x16x32_bf16(afr[1], B[4], acc, 0, 0, 0);
        acc = __builtin_amdgcn_mfma_f32_16x16x32_bf16(afr[2], B[8], acc, 0, 0, 0);
        acc = __builtin_amdgcn_mfma_f32_16x16x32_bf16(afr[3], B[12], acc, 0, 0, 0);
        int colo = (ntb + nt) * 16 + r16;
#pragma unroll
        for (int r = 0; r < 4; ++r) {
            int ro = blockbase + trow * 16 + kg * 4 + r;
            if (ro < N) Y[(size_t)ro * 128 + colo] = (unsigned short)f2bf(acc[r] * dv[r]);
        }
    }
}

// AGG layer 2: Out = relu( dinv*( sum ew*H'[s] + H'[d] ) + b2 ), bf16 in/out
__global__ __launch_bounds__(256) void k_agg(const uint2* __restrict__ Hb2,
                                             const int* __restrict__ rowptr,
                                             const int2* __restrict__ cvb,
                                             const float* __restrict__ dinv,
                                             const float* __restrict__ bias,
                                             uint2* __restrict__ OutB2, int N) {
    __shared__ int2 lcv[4][4][2][64];  // 16 KB
    int tid = threadIdx.x;
    int lane = tid & 63, wid = tid >> 6;
    int half = lane >> 5, sl = lane & 31;
    int n0 = (blockIdx.x * 4 + wid) * 8;
    if (n0 >= N) return;
    int rv = rowptr[min(n0 + min(lane, 8), N)];
    int rp[9];
#pragma unroll
    for (int k = 0; k < 9; ++k) rp[k] = __shfl(rv, k);
    int cnt[8];
    int nmax = 0;
#pragma unroll
    for (int k = 0; k < 8; ++k) {
        cnt[k] = rp[k + 1] - rp[k];
        nmax = max(nmax, cnt[k]);
    }
    float a[4][4];
#pragma unroll
    for (int s = 0; s < 4; ++s) {
        int ns = n0 + 2 * s + half;
        uint2 hv = (ns < N) ? Hb2[(size_t)ns * 32 + sl] : make_uint2(0u, 0u);
        a[s][0] = bf_lo(hv.x);
        a[s][1] = bf_hi(hv.x);
        a[s][2] = bf_lo(hv.y);
        a[s][3] = bf_hi(hv.y);
    }
    for (int base = 0; base < nmax; base += 64) {
#pragma unroll
        for (int s = 0; s < 4; ++s) {
#pragma unroll
            for (int h = 0; h < 2; ++h) {
                int k = 2 * s + h;
                int2 t = (base + lane < cnt[k]) ? cvb[rp[k] + base + lane]
                                                : make_int2(0, 0);
                lcv[wid][s][h][lane] = t;
            }
        }
        int m = min(64, nmax - base);
        for (int j0 = 0; j0 < m; j0 += 8) {
#pragma unroll
            for (int jj = 0; jj < 8; ++jj) {
                int j = j0 + jj;
                if (j < m) {
                    int2 e0 = lcv[wid][0][half][j];
                    int2 e1 = lcv[wid][1][half][j];
                    int2 e2 = lcv[wid][2][half][j];
                    int2 e3 = lcv[wid][3][half][j];
                    uint2 h0 = Hb2[(size_t)e0.x * 32 + sl];
                    uint2 h1 = Hb2[(size_t)e1.x * 32 + sl];
                    uint2 h2 = Hb2[(size_t)e2.x * 32 + sl];
                    uint2 h3 = Hb2[(size_t)e3.x * 32 + sl];
                    float w0 = __int_as_float(e0.y);
                    float w1 = __int_as_float(e1.y);
                    float w2 = __int_as_float(e2.y);
                    float w3 = __int_as_float(e3.y);
                    a[0][0] = fmaf(w0, bf_lo(h0.x), a[0][0]);
                    a[0][1] = fmaf(w0, bf_hi(h0.x), a[0][1]);
                    a[0][2] = fmaf(w0, bf_lo(h0.y), a[0][2]);
                    a[0][3] = fmaf(w0, bf_hi(h0.y), a[0][3]);
                    a[1][0] = fmaf(w1, bf_lo(h1.x), a[1][0]);
                    a[1][1] = fmaf(w1, bf_hi(h1.x), a[1][1]);
                    a[1][2] = fmaf(w1, bf_lo(h1.y), a[1][2]);
                    a[1][3] = fmaf(w1, bf_hi(h1.y), a[1][3]);
                    a[2][0] = fmaf(w2, bf_lo(h2.x), a[2][0]);
                    a[2][1] = fmaf(w2, bf_hi(h2.x), a[2][1]);
                    a[2][2] = fmaf(w2, bf_lo(h2.y), a[2][2]);
                    a[2][3] = fmaf(w2, bf_hi(h2.y), a[2][3]);
                    a[3][0] = fmaf(w3, bf_lo(h3.x), a[3][0]);
                    a[3][1] = fmaf(w3, bf_hi(h3.x), a[3][1]);
                    a[3][2] = fmaf(w3, bf_lo(h3.y), a[3][2]);
                    a[3][3] = fmaf(w3, bf_hi(h3.y), a[3][3]);
                }
            }
        }
    }
    float4 bv = reinterpret_cast<const float4*>(bias)[sl];
#pragma unroll
    for (int s = 0; s < 4; ++s) {
        int ns = n0 + 2 * s + half;
        if (ns < N) {
            float d = dinv[ns];
            float o0 = fmaxf(fmaf(a[s][0], d, bv.x), 0.f);
            float o1 = fmaxf(fmaf(a[s][1], d, bv.y), 0.f);
            float o2 = fmaxf(fmaf(a[s][2], d, bv.z), 0.f);
            float o3 = fmaxf(fmaf(a[s][3], d, bv.w), 0.f);
            OutB2[(size_t)ns * 32 + sl] = make_uint2(packbf2(o0, o1), packbf2(o2, o3));
        }
    }
}

// fused mean-pool + head: out[g] = [pooled, relu(md@Wm+bm)] @ Wf + bf
__global__ __launch_bounds__(256) void k_poolhead(const unsigned int* __restrict__ H2u,
                                                  const int* __restrict__ gstart,
                                                  const int* __restrict__ gend,
                                                  const float* __restrict__ meta,
                                                  const float* __restrict__ Wm,
                                                  const float* __restrict__ bm,
                                                  const float* __restrict__ Wf,
                                                  const float* __restrict__ bf,
                                                  float* __restrict__ out, int G) {
    int g = blockIdx.x;
    int tid = threadIdx.x;
    int cu = tid & 63, q = tid >> 6;
    __shared__ float r0[256], r1[256];
    __shared__ float pooled[128];
    __shared__ float red[128];
    int b = gstart[g];
    int e = gend[g];
    int cntg = e - b;  // <=0 for empty graph (gstart=INT_MAX, gend=0)
    float s0 = 0.f, s1 = 0.f;
    for (int i = q; i < cntg; i += 4) {
        unsigned int v = H2u[(size_t)(b + i) * 64 + cu];
        s0 += bf_lo(v);
        s1 += bf_hi(v);
    }
    r0[tid] = s0; r1[tid] = s1;
    __syncthreads();
    if (tid < 64) {
        float t0 = r0[cu] + r0[cu + 64] + r0[cu + 128] + r0[cu + 192];
        float t1 = r1[cu] + r1[cu + 64] + r1[cu + 128] + r1[cu + 192];
        float inv = 1.f / fmaxf((float)cntg, 1.f);
        pooled[2 * cu] = t0 * inv;
        pooled[2 * cu + 1] = t1 * inv;
    }
    __syncthreads();
    if (tid < 128) {
        int c = tid;
        int idx = gstart[g] % G;  // INT_MAX for empty graph (segment_min identity)
        float m = bm[c];
#pragma unroll
        for (int k = 0; k < 30; ++k) m = fmaf(meta[idx * 30 + k], Wm[k * 128 + c], m);
        m = fmaxf(m, 0.f);
        red[c] = pooled[c] * Wf[c] + m * Wf[128 + c];
    }
    __syncthreads();
    for (int st = 64; st > 0; st >>= 1) {
        if (tid < st) red[tid] += red[tid + st];
        __syncthreads();
    }
    if (tid == 0) out[g] = red[0] + bf[0];
}

extern "C" void kernel_launch(void* const* d_in, const int* in_sizes, int n_in,
                              void* d_out, int out_size, void* d_ws, size_t ws_size,
                              hipStream_t stream) {
    const float* x     = (const float*)d_in[0];
    const int*   ei    = (const int*)d_in[1];
    const float* ew    = (const float*)d_in[2];
    const int*   batch = (const int*)d_in[3];
    const float* meta  = (const float*)d_in[4];
    const float* W1    = (const float*)d_in[5];
    const float* b1    = (const float*)d_in[6];
    const float* W2    = (const float*)d_in[7];
    const float* b2    = (const float*)d_in[8];
    const float* Wm    = (const float*)d_in[9];
    const float* bm    = (const float*)d_in[10];
    const float* Wf    = (const float*)d_in[11];
    const float* bf    = (const float*)d_in[12];

    int N = in_sizes[0] / 128;
    int E = in_sizes[2];
    int G = in_sizes[4] / 30;
    int Mpad = (N + 63) & ~63;
    int NBK = (N + BK_NODES - 1) >> BK_SHIFT;  // 196 for N=100000 (<=256)
    const int* srcp = ei;
    const int* dstp = ei + E;

    char* p = (char*)d_ws;
    auto alloc = [&](size_t bytes) -> void* {
        void* r = p;
        p += (bytes + 255) & ~(size_t)255;
        return r;
    };
    float* dinv   = (float*)alloc((size_t)N * 4);
    int*   rowptr = (int*)alloc((size_t)(N + 1) * 4);
    int2*  binned = (int2*)alloc((size_t)E * 8);
    int2*  cvb    = (int2*)alloc((size_t)E * 8);
    int*   bcnt   = (int*)alloc((size_t)NBK * 4);
    int*   bbase  = (int*)alloc((size_t)(NBK + 1) * 4);
    int*   bfillp = (int*)alloc((size_t)NBK * 4);
    unsigned short* H   = (unsigned short*)alloc((size_t)Mpad * 128 * 2);
    unsigned short* H2  = (unsigned short*)alloc((size_t)Mpad * 128 * 2);
    unsigned short* WT1 = (unsigned short*)alloc(128 * 128 * 2);
    unsigned short* WT2 = (unsigned short*)alloc(128 * 128 * 2);
    int*   gstart = (int*)alloc((size_t)G * 4);
    int*   gend   = (int*)alloc((size_t)G * 4);

    int EB = (E + CH - 1) / CH;
    k_init_small<<<(max(G, NBK) + 255) / 256, 256, 0, stream>>>(gstart, gend, G, bcnt, NBK);
    k_init_nodes<<<(N + 255) / 256, 256, 0, stream>>>(batch, gstart, gend, N);
    k_binhist<<<EB, 256, 0, stream>>>(dstp, E, bcnt, NBK);
    k_binscan<<<1, 256, 0, stream>>>(bcnt, bbase, bfillp, NBK);
    k_binscatter<<<EB, 256, 0, stream>>>(srcp, dstp, ew, bfillp, binned, E);
    k_csr<<<NBK, 256, 0, stream>>>(binned, bbase, cvb, rowptr, dinv, N, E);

    k_wtboth<<<128, 256, 0, stream>>>(W1, W2, WT1, WT2);

    k_gemm1<<<Mpad / 64, 256, 0, stream>>>(x, WT1, dinv, H, N);
    int NB32 = (N + 31) / 32;
    k_aggemm<<<NB32, 256, 0, stream>>>((const uint2*)H, rowptr, cvb, dinv, b1, WT2,
                                       H2, N);
    k_agg<<<NB32, 256, 0, stream>>>((const uint2*)H2, rowptr, cvb, dinv, b2,
                                    (uint2*)H, N);

    k_poolhead<<<G, 256, 0, stream>>>((const unsigned int*)H, gstart, gend,
                                      meta, Wm, bm, Wf, bf, (float*)d_out, G);
}